// Round 11
// baseline (2234.365 us; speedup 1.0000x reference)
//
#include <hip/hip_runtime.h>
#include <hip/hip_bf16.h>
#include <stdint.h>

typedef __attribute__((ext_vector_type(8))) short bf16x8;   // 8 bf16 in 4 VGPRs (MFMA A/B operand)
typedef __attribute__((ext_vector_type(4))) float f32x4;    // MFMA C/D operand
typedef __attribute__((ext_vector_type(4))) unsigned int u32x4; // native 16B vec

// ---------------- model constants ----------------
static constexpr int BB = 32, SS = 256, DD = 384;
static constexpr int TDEC = 400;
static constexpr int NMELC = 80;

// d_out offsets (floats), return order: mel, dec_mask, dur_pred, log_dur_pred, dec_lens
static constexpr size_t OFF_MEL    = 0;
static constexpr size_t OFF_DMASK  = (size_t)BB * TDEC * NMELC;   // 1,024,000
static constexpr size_t OFF_DUR    = OFF_DMASK + (size_t)BB * TDEC;
static constexpr size_t OFF_LOGDUR = OFF_DUR + (size_t)BB * SS;
static constexpr size_t OFF_DLEN   = OFF_LOGDUR + (size_t)BB * SS;

// async global->LDS, 16B per lane (dest must be wave-uniform base + lane*16)
__device__ __forceinline__ void gld16(void* lds, const void* g) {
  __builtin_amdgcn_global_load_lds(
      (const __attribute__((address_space(1))) void*)g,
      (__attribute__((address_space(3))) void*)lds, 16, 0, 0);
}

// =================================================================
// Weight conversion
// =================================================================

// src: [L][R][C] f32  ->  dst: [L][Cpad][R] bf16 (transposed; zeros for c >= C)
__global__ __launch_bounds__(256)
void transpose_cvt(const float* __restrict__ src, __hip_bfloat16* __restrict__ dst,
                   int R, int C, int Cpad)
{
  __shared__ float tile[32][33];
  int l = blockIdx.z;
  src += (size_t)l * R * C;
  dst += (size_t)l * Cpad * R;
  int r0 = blockIdx.x * 32, c0 = blockIdx.y * 32;
  int tx = threadIdx.x, ty = threadIdx.y;
  for (int i = ty; i < 32; i += 8) {
    int c = c0 + tx;
    tile[i][tx] = (c < C) ? src[(size_t)(r0 + i) * C + c] : 0.f;
  }
  __syncthreads();
  for (int i = ty; i < 32; i += 8) {
    dst[(size_t)(c0 + i) * R + (r0 + tx)] = __float2bfloat16(tile[tx][i]);
  }
}

// src: [L][Cout][Cin][3] f32  ->  dst: [L][3][Cout][Cin] bf16
__global__ __launch_bounds__(256)
void conv_cvt(const float* __restrict__ src, __hip_bfloat16* __restrict__ dst,
              int Cout, int Cin, long long total)
{
  long long i = (long long)blockIdx.x * 256 + threadIdx.x;
  if (i >= total) return;
  int ci = (int)(i % Cin);
  long long t1 = i / Cin;
  int co = (int)(t1 % Cout);
  long long t2 = t1 / Cout;
  int tap = (int)(t2 % 3);
  int l = (int)(t2 / 3);
  dst[i] = __float2bfloat16(src[(((size_t)l * Cout + co) * Cin + ci) * 3 + tap]);
}

// =================================================================
// Positional embedding / embedding
// =================================================================

__global__ __launch_bounds__(256)
void pe_kernel(float* __restrict__ pe, int T)
{
  int i = blockIdx.x * 256 + threadIdx.x;
  if (i >= T * 192) return;
  int t = i / 192, j = i % 192;
  float inv = expf(-(float)j * (9.210340371976184f / 192.f));
  float s = (float)t * inv;
  pe[(size_t)t * 384 + j]       = sinf(s);
  pe[(size_t)t * 384 + 192 + j] = cosf(s);
}

__global__ __launch_bounds__(128)
void embed_kernel(const int* __restrict__ inputs, const float* __restrict__ emb,
                  const float* __restrict__ pe, float* __restrict__ maskf,
                  __hip_bfloat16* __restrict__ xb)
{
  int blk = blockIdx.x; int b = blk / SS, t = blk % SS;
  int tok = inputs[b * SS + t];
  float mk = (tok != 0) ? 1.f : 0.f;
  if (threadIdx.x == 0) maskf[b * SS + t] = mk;
  size_t prow = ((size_t)b * (SS + 2) + 1 + t) * 384;
  for (int c = threadIdx.x; c < 384; c += 128) {
    float v = emb[(size_t)tok * 384 + c] + pe[(size_t)t * 384 + c] * mk;
    xb[prow + c] = __float2bfloat16(v);
  }
}

__global__ __launch_bounds__(256)
void zero_guards(__hip_bfloat16* __restrict__ buf, int T, int C)
{
  int b = blockIdx.x >> 1, which = blockIdx.x & 1;
  size_t row = ((size_t)b * (T + 2) + (which ? (T + 1) : 0)) * (size_t)C;
  for (int c = threadIdx.x; c < C; c += 256) buf[row + c] = __float2bfloat16(0.f);
}

// =================================================================
// GEMM: C[M,N] = act( sum_tap A[m + tap - NTAPS/2, :] @ B_tap + bias )
// A: bf16, padded rows (B, T+2, K), guard rows zero. B: bf16 [NTAPS][Npad][K].
// TM x TN tile, 4 waves 2x2; wave (TM/2)x(TN/2); 16x16x32 fragments.
// BK=32, depth-DEPTH pipeline (DEPTH+1 buffers), counted vmcnt, R8 tail.
// LDS chunk swizzle (conflicts~0).
// Block->tile map: per-XCD contiguous logical chunk (n-fast, bijective m204).
// Epilogue: bf16 C staged in LDS -> coalesced 16B row stores.
// TN=64 variant exists to enlarge grids for small-N GEMMs (occupancy fill).
// =================================================================
template<int TM, int TN, int DEPTH, int NTAPS, int KV, bool RELU, bool OUTF32, bool CPAD>
__global__ __launch_bounds__(256)
void gemm_tn(const __hip_bfloat16* __restrict__ A,
             const __hip_bfloat16* __restrict__ Bw,
             const float* __restrict__ bias,
             void* __restrict__ Cout_,
             int N, int ldc, int T, int Npad)
{
  constexpr int KS = KV >> 5;          // 32-K steps per tap
  constexpr int NSTEP = NTAPS * KS;
  constexpr int DEP = (DEPTH < NSTEP) ? DEPTH : NSTEP;
  constexpr int NBUF = DEP + 1;
  constexpr int ABYTES = TM * 64;      // A bytes per buffer
  constexpr int BBYTES = TN * 64;      // B bytes per buffer
  constexpr int BUFB = ABYTES + BBYTES;
  constexpr int MI_N = TM / 32;        // m-fragments per wave
  constexpr int NI_N = TN / 32;        // n-fragments per wave
  constexpr int OPS = (TM == 128 ? 2 : 1) + (TN == 128 ? 2 : 1);  // gld16 per STAGE
  __shared__ __align__(16) char SH[NBUF * BUFB];

  const int tid = threadIdx.x;
  const int lane = tid & 63;
  const int w = tid >> 6;
  const int wm = w >> 1, wn = w & 1;

  // ---- per-XCD contiguous chunk mapping (bijective, m204; n-fast) ----
  const int GN = gridDim.y;
  const int NB = gridDim.x * GN;
  const int f = blockIdx.y * gridDim.x + blockIdx.x;
  const int qq = NB >> 3, rr8 = NB & 7;
  const int xcd = f & 7, pos = f >> 3;
  const int st = (xcd < rr8) ? xcd * (qq + 1) : rr8 * (qq + 1) + (xcd - rr8) * qq;
  const int L = st + pos;
  const int m0 = (L / GN) * TM;
  const int n0 = (L % GN) * TN;

  const int ar = tid >> 2;
  const int q = tid & 3;
  const int qsw = q ^ ((ar >> 1) & 3);         // pre-swizzled source chunk
  const int g0 = m0 + ar, g1 = g0 + 64;
  const char* sA0 = (const char*)A + (((size_t)(g0 + 2 * (g0 / T) + 1 - NTAPS / 2)) * KV + qsw * 8) * 2;
  const char* sA1 = (const char*)A + (((size_t)(g1 + 2 * (g1 / T) + 1 - NTAPS / 2)) * KV + qsw * 8) * 2;
  const char* sB0 = (const char*)Bw + ((size_t)(n0 + ar) * KV + qsw * 8) * 2;
  const char* sB1 = (const char*)Bw + ((size_t)(n0 + ar + 64) * KV + qsw * 8) * 2;

  const int woff = ar * 64 + q * 16;   // LDS byte offset (linear, tid*16)
  int ks_s = 0;

  auto STAGE = [&](int buf) {
    char* base = SH + buf * BUFB;
    gld16(base + woff, sA0);
    if (TM == 128) gld16(base + 4096 + woff, sA1);
    gld16(base + ABYTES + woff, sB0);
    if (TN == 128) gld16(base + ABYTES + 4096 + woff, sB1);
  };
  auto ADV = [&]() {
    sA0 += 64; sA1 += 64; sB0 += 64; sB1 += 64;
    if (++ks_s == KS) {
      ks_s = 0;
      const size_t badj = ((size_t)Npad - 1) * KV * 2;
      sB0 += badj; sB1 += badj;
    }
  };

  f32x4 zero = {0.f, 0.f, 0.f, 0.f};
  f32x4 acc[MI_N][NI_N];
#pragma unroll
  for (int i = 0; i < MI_N; i++)
#pragma unroll
    for (int j = 0; j < NI_N; j++) acc[i][j] = zero;

  const int rl = lane & 15;
  const int hi4 = lane >> 4;
  const int kb2 = (hi4 ^ ((rl >> 1) & 3)) * 16;   // swizzled read slot (bytes)

  // ---- prologue: fill DEP buffers ----
#pragma unroll
  for (int i = 0; i < DEP; ++i) { STAGE(i); ADV(); }
  if constexpr (DEP == NSTEP) {
    asm volatile("s_waitcnt vmcnt(0)" ::: "memory");
  } else {
    asm volatile("s_waitcnt vmcnt(%0)" :: "i"((DEP - 1) * OPS) : "memory");
  }
  __builtin_amdgcn_s_barrier();
  __builtin_amdgcn_sched_barrier(0);

  int cur = 0;
  for (int s = 0; s < NSTEP; ++s) {
    if (s + DEP < NSTEP) {
      int nb = cur + DEP; if (nb >= NBUF) nb -= NBUF;
      STAGE(nb); ADV();
    }
    const char* Ab = SH + cur * BUFB;
    const char* Bb = Ab + ABYTES;
    bf16x8 af[MI_N], bfr[NI_N];
#pragma unroll
    for (int mi = 0; mi < MI_N; mi++)
      af[mi] = *(const bf16x8*)(Ab + (wm * (TM / 2) + mi * 16 + rl) * 64 + kb2);
#pragma unroll
    for (int ni = 0; ni < NI_N; ni++)
      bfr[ni] = *(const bf16x8*)(Bb + (wn * (TN / 2) + ni * 16 + rl) * 64 + kb2);
#pragma unroll
    for (int mi = 0; mi < MI_N; mi++)
#pragma unroll
      for (int ni = 0; ni < NI_N; ni++)
        acc[mi][ni] = __builtin_amdgcn_mfma_f32_16x16x32_bf16(af[mi], bfr[ni], acc[mi][ni], 0, 0, 0);
    if (s + 1 < NSTEP) {
      if (s + DEP < NSTEP) {
        asm volatile("s_waitcnt vmcnt(%0)" :: "i"((DEP - 1) * OPS) : "memory");
      } else {
        asm volatile("s_waitcnt vmcnt(0)" ::: "memory");  // tail drain
      }
      __builtin_amdgcn_s_barrier();
      __builtin_amdgcn_sched_barrier(0);
    }
    cur = cur + 1; if (cur >= NBUF) cur -= NBUF;
  }

  // epilogue. C/D layout col=lane&15, row=(lane>>4)*4+j  [m89-verified]
  const int rj = hi4 * 4;
  if (!OUTF32) {
    // stage bf16 C-tile in LDS, then coalesced 16B row stores
    __syncthreads();                 // all waves done with K-loop LDS
    ushort* S = (ushort*)SH;         // [TM][TN] bf16
#pragma unroll
    for (int mi = 0; mi < MI_N; mi++) {
#pragma unroll
      for (int ni = 0; ni < NI_N; ni++) {
        int lc = wn * (TN / 2) + ni * 16 + rl;
        float bv = bias ? bias[n0 + lc] : 0.f;
#pragma unroll
        for (int j = 0; j < 4; j++) {
          float v = acc[mi][ni][j] + bv;
          if (RELU) v = fmaxf(v, 0.f);
          __hip_bfloat16 hb = __float2bfloat16(v);
          S[(wm * (TM / 2) + mi * 16 + rj + j) * TN + lc] = *(ushort*)&hb;
        }
      }
    }
    __syncthreads();
    constexpr int TPR = TN / 8;       // threads per row (16B each)
    constexpr int RPP = 256 / TPR;    // rows per pass
    const int tr = tid / TPR;
    const int tc = (tid % TPR) * 8;
#pragma unroll
    for (int pass = 0; pass < TM / RPP; ++pass) {
      int lr = pass * RPP + tr;
      int gcol = n0 + tc;
      if (gcol < N) {
        int r = m0 + lr;
        size_t orow = CPAD ? ((size_t)r + 2 * (r / T) + 1) : (size_t)r;
        *(u32x4*)((__hip_bfloat16*)Cout_ + orow * ldc + gcol) = *(const u32x4*)&S[lr * TN + tc];
      }
    }
  } else {
#pragma unroll
    for (int mi = 0; mi < MI_N; mi++) {
#pragma unroll
      for (int ni = 0; ni < NI_N; ni++) {
        int col = n0 + wn * (TN / 2) + ni * 16 + rl;
        if (col < N) {
          float bv = bias ? bias[col] : 0.f;
#pragma unroll
          for (int j = 0; j < 4; j++) {
            int r = m0 + wm * (TM / 2) + mi * 16 + rj + j;
            float v = acc[mi][ni][j] + bv;
            if (RELU) v = fmaxf(v, 0.f);
            size_t orow = CPAD ? ((size_t)r + 2 * (r / T) + 1) : (size_t)r;
            ((float*)Cout_)[orow * ldc + col] = v;
          }
        }
      }
    }
  }
}

// =================================================================
// Fused flash attention: 1 head, d=64. Block = (b, 64-query tile), 4 waves.
// =================================================================
__global__ __launch_bounds__(256)
void fattn_kernel(const __hip_bfloat16* __restrict__ qkv, const float* __restrict__ maskf,
                  __hip_bfloat16* __restrict__ vec, int T, int NT)
{
  __shared__ __align__(16) ushort VT[64][456];   // V^T: [d][key]
  __shared__ __align__(16) ushort Pl[4][16][72]; // per-wave P tile
  __shared__ float MS[448];                      // 0=ok, -1e9=masked, -1e38=pad

  const int tid = threadIdx.x;
  const int b = blockIdx.y;
  const int TP = T + 2;
  const int KTOT = NT * 64;
  const char* bptr = (const char*)qkv + ((size_t)b * TP + 1) * 384;

  for (int k = tid; k < KTOT; k += 256)
    MS[k] = (k < T) ? ((maskf[b * T + k] > 0.f) ? 0.f : -1e9f) : -1e38f;
  for (int i = tid; i < KTOT * 8; i += 256) {
    int k = i >> 3, seg = i & 7;
    int kr = (k < T) ? k : T - 1;
    uint4 u = *(const uint4*)(bptr + (size_t)kr * 384 + 256 + seg * 16);
    const ushort* e = (const ushort*)&u;
#pragma unroll
    for (int j = 0; j < 8; ++j) VT[seg * 8 + j][k] = e[j];
  }
  __syncthreads();

  const int w = tid >> 6, lane = tid & 63;
  const int lo = lane & 15, hi = lane >> 4;
  const int q0 = blockIdx.x * 64 + w * 16;
  const int qc = min(q0 + lo, T - 1);

  bf16x8 afr[2];
#pragma unroll
  for (int ks = 0; ks < 2; ++ks)
    afr[ks] = *(const bf16x8*)(bptr + (size_t)qc * 384 + ks * 64 + hi * 16);

  f32x4 Oacc[4];
  f32x4 z = {0.f, 0.f, 0.f, 0.f};
#pragma unroll
  for (int df = 0; df < 4; ++df) Oacc[df] = z;
  float mrun[4], lrun[4];
#pragma unroll
  for (int j = 0; j < 4; ++j) { mrun[j] = -3e38f; lrun[j] = 0.f; }

  for (int kt = 0; kt < NT; ++kt) {
    const int kb = kt * 64;
    f32x4 S[4];
#pragma unroll
    for (int f = 0; f < 4; ++f) S[f] = z;
#pragma unroll
    for (int ks = 0; ks < 2; ++ks) {
#pragma unroll
      for (int f = 0; f < 4; ++f) {
        int krc = min(kb + f * 16 + lo, T - 1);
        bf16x8 bfr = *(const bf16x8*)(bptr + (size_t)krc * 384 + 128 + ks * 64 + hi * 16);
        S[f] = __builtin_amdgcn_mfma_f32_16x16x32_bf16(afr[ks], bfr, S[f], 0, 0, 0);
      }
    }
    float sv[4][4];
#pragma unroll
    for (int f = 0; f < 4; ++f) {
      float msel = MS[kb + f * 16 + lo];
#pragma unroll
      for (int j = 0; j < 4; ++j) {
        float x = S[f][j] * 0.125f;
        sv[f][j] = (msel == 0.f) ? x : msel;
      }
    }
    float scale[4];
#pragma unroll
    for (int j = 0; j < 4; ++j) {
      float m4 = fmaxf(fmaxf(sv[0][j], sv[1][j]), fmaxf(sv[2][j], sv[3][j]));
#pragma unroll
      for (int msk = 1; msk < 16; msk <<= 1) m4 = fmaxf(m4, __shfl_xor(m4, msk));
      float mnew = fmaxf(mrun[j], m4);
      scale[j] = __expf(mrun[j] - mnew);
      mrun[j] = mnew;
    }
    float pv[4][4], ps[4] = {0.f, 0.f, 0.f, 0.f};
#pragma unroll
    for (int f = 0; f < 4; ++f)
#pragma unroll
      for (int j = 0; j < 4; ++j) {
        float p = __expf(sv[f][j] - mrun[j]);
        pv[f][j] = p; ps[j] += p;
      }
#pragma unroll
    for (int j = 0; j < 4; ++j) {
#pragma unroll
      for (int msk = 1; msk < 16; msk <<= 1) ps[j] += __shfl_xor(ps[j], msk);
      lrun[j] = lrun[j] * scale[j] + ps[j];
#pragma unroll
      for (int df = 0; df < 4; ++df) Oacc[df][j] *= scale[j];
    }
#pragma unroll
    for (int f = 0; f < 4; ++f)
#pragma unroll
      for (int j = 0; j < 4; ++j) {
        __hip_bfloat16 hb = __float2bfloat16(pv[f][j]);
        Pl[w][hi * 4 + j][f * 16 + lo] = *(ushort*)&hb;
      }
#pragma unroll
    for (int ks = 0; ks < 2; ++ks) {
      bf16x8 pa = *(const bf16x8*)((const char*)&Pl[w][lo][0] + ks * 64 + hi * 16);
#pragma unroll
      for (int df = 0; df < 4; ++df) {
        bf16x8 vfr = *(const bf16x8*)((const char*)&VT[df * 16 + lo][0] + kb * 2 + ks * 64 + hi * 16);
        Oacc[df] = __builtin_amdgcn_mfma_f32_16x16x32_bf16(pa, vfr, Oacc[df], 0, 0, 0);
      }
    }
  }

  float inv[4];
#pragma unroll
  for (int j = 0; j < 4; ++j) inv[j] = 1.f / lrun[j];
#pragma unroll
  for (int df = 0; df < 4; ++df)
#pragma unroll
    for (int j = 0; j < 4; ++j) {
      int qq = q0 + hi * 4 + j;
      if (qq < T) {
        __hip_bfloat16 hb = __float2bfloat16(Oacc[df][j] * inv[j]);
        *(ushort*)((char*)vec + ((size_t)b * TP + 1 + qq) * 128 + (df * 16 + lo) * 2) = *(ushort*)&hb;
      }
    }
}

// =================================================================
// LayerNorm (bf16 residual stream): out = LN(xin [+ resin]) * g + b [* mask]
// 4 rows per 256-thr block, one wave per row; uint(2xbf16) coalesced loads;
// shfl_xor wave reduce; packed uint stores. Padded rows (T+2, C).
// =================================================================
template<int C, bool HASRES, bool HASMASK>
__global__ __launch_bounds__(256)
void ln_kernel(const __hip_bfloat16* __restrict__ xin, const __hip_bfloat16* __restrict__ resin,
               const float* __restrict__ g, const float* __restrict__ bb,
               const float* __restrict__ maskf,
               __hip_bfloat16* __restrict__ outb, int T)
{
  constexpr int NU = C / 128;              // uint chunks per lane
  const int row = blockIdx.x * 4 + (threadIdx.x >> 6);
  const int lane = threadIdx.x & 63;
  const int b = row / T, t = row - b * T;
  const size_t prow = ((size_t)b * (T + 2) + 1 + t) * C;
  const uint* xu = (const uint*)(xin + prow);
  const uint* ru = (const uint*)(resin + prow);
  float v[2 * NU];
  float s1 = 0.f, s2 = 0.f;
#pragma unroll
  for (int k = 0; k < NU; ++k) {
    uint ux = xu[lane + 64 * k];
    uint xl = ux << 16, xh = ux & 0xffff0000u;
    float lo = *(float*)&xl, hi = *(float*)&xh;
    if (HASRES) {
      uint ur = ru[lane + 64 * k];
      uint rl2 = ur << 16, rh = ur & 0xffff0000u;
      lo += *(float*)&rl2; hi += *(float*)&rh;
    }
    v[2 * k] = lo; v[2 * k + 1] = hi;
    s1 += lo + hi; s2 += lo * lo + hi * hi;
  }
#pragma unroll
  for (int o = 32; o > 0; o >>= 1) { s1 += __shfl_xor(s1, o); s2 += __shfl_xor(s2, o); }
  float mu = s1 / C;
  float var = s2 / C - mu * mu;
  float rstd = rsqrtf(fmaxf(var, 0.f) + 1e-5f);
  float mk = HASMASK ? maskf[row] : 1.f;
  uint* ou = (uint*)(outb + prow);
#pragma unroll
  for (int k = 0; k < NU; ++k) {
    int c = (lane + 64 * k) * 2;
    float2 gv = *(const float2*)(g + c);
    float2 bv = *(const float2*)(bb + c);
    float lo = ((v[2 * k]     - mu) * rstd * gv.x + bv.x) * mk;
    float hi = ((v[2 * k + 1] - mu) * rstd * gv.y + bv.y) * mk;
    __hip_bfloat16 hl = __float2bfloat16(lo), hh = __float2bfloat16(hi);
    ou[lane + 64 * k] = (uint)(*(ushort*)&hl) | ((uint)(*(ushort*)&hh) << 16);
  }
}

// =================================================================
// Duration predictor FC + exp/clip
// =================================================================
__global__ __launch_bounds__(64)
void dpfc_kernel(const __hip_bfloat16* __restrict__ dp2, const float* __restrict__ fcw,
                 const float* __restrict__ fcb, const float* __restrict__ maskf,
                 float* __restrict__ logdur, float* __restrict__ durpred)
{
  int blk = blockIdx.x; int b = blk / SS, t = blk % SS;
  size_t prow = ((size_t)b * (SS + 2) + 1 + t) * 256;
  int lane = threadIdx.x;
  float a = 0.f;
  for (int c = lane; c < 256; c += 64) a += __bfloat162float(dp2[prow + c]) * fcw[c];
  for (int o = 32; o > 0; o >>= 1) a += __shfl_down(a, o);
  if (lane == 0) {
    float ld = (a + fcb[0]) * maskf[b * SS + t];
    logdur[b * SS + t] = ld;
    durpred[b * SS + t] = fminf(fmaxf(expf(ld) - 1.f, 0.f), 75.f);
  }
}

// =================================================================
// Length regulator
// =================================================================
__global__ __launch_bounds__(512)
void regulator_kernel(const float* __restrict__ dur, float* __restrict__ dmaskf,
                      int* __restrict__ idxbuf, float* __restrict__ out_dmask,
                      float* __restrict__ out_dlen)
{
  int b = blockIdx.x, tid = threadIdx.x;
  __shared__ int cum[256];
  __shared__ int len_s;
  if (tid < 256) cum[tid] = (int)rintf(dur[b * 256 + tid] / 0.0265f);
  __syncthreads();
  if (tid == 0) {
    int acc = 0;
    for (int i = 0; i < 256; i++) { acc += cum[i]; cum[i] = acc; }
    int len = acc < 400 ? acc : 400;
    len_s = len;
    out_dlen[b] = (float)len;
  }
  __syncthreads();
  if (tid < 400) {
    int p = tid;
    int lo = 0, hi = 256;
    while (lo < hi) { int mid = (lo + hi) >> 1; if (cum[mid] <= p) lo = mid + 1; else hi = mid; }
    int idx = lo < 255 ? lo : 255;
    idxbuf[b * 400 + p] = idx;
    float mk = (p < len_s) ? 1.f : 0.f;
    dmaskf[b * 400 + p] = mk;
    out_dmask[b * 400 + p] = mk;
  }
}

__global__ __launch_bounds__(128)
void build_y_kernel(const __hip_bfloat16* __restrict__ encb, const int* __restrict__ idxbuf,
                    const float* __restrict__ dmaskf, const float* __restrict__ pe,
                    __hip_bfloat16* __restrict__ yb)
{
  int blk = blockIdx.x; int b = blk / 400, p = blk % 400;
  float mk = dmaskf[b * 400 + p];
  int idx = idxbuf[b * 400 + p];
  size_t orowp = ((size_t)b * 402 + 1 + p) * 384;
  size_t srow = ((size_t)b * 258 + 1 + idx) * 384;
  for (int c = threadIdx.x; c < 384; c += 128) {
    float v = (mk > 0.f) ? (__bfloat162float(encb[srow + c]) + pe[(size_t)p * 384 + c]) : 40.f;
    yb[orowp + c] = __float2bfloat16(v);
  }
}

// =================================================================
// Orchestration
// =================================================================
extern "C" void kernel_launch(void* const* d_in, const int* in_sizes, int n_in,
                              void* d_out, int out_size, void* d_ws, size_t ws_size,
                              hipStream_t stream)
{
  (void)in_sizes; (void)n_in; (void)out_size; (void)ws_size;
  float* outF = (float*)d_out;

  const int*   inputs  = (const int*)d_in[0];
  const float* dur_tgt = (const float*)d_in[1];
  const float* emb     = (const float*)d_in[2];
  const float* e_qkv_w = (const float*)d_in[3];
  const float* e_qkv_b = (const float*)d_in[4];
  const float* e_o_w   = (const float*)d_in[5];
  const float* e_ln1g  = (const float*)d_in[6];
  const float* e_ln1b  = (const float*)d_in[7];
  const float* e_c1w   = (const float*)d_in[8];
  const float* e_c1b   = (const float*)d_in[9];
  const float* e_c2w   = (const float*)d_in[10];
  const float* e_c2b   = (const float*)d_in[11];
  const float* e_ln2g  = (const float*)d_in[12];
  const float* e_ln2b  = (const float*)d_in[13];
  const float* dc_qkv_w = (const float*)d_in[14];
  const float* dc_qkv_b = (const float*)d_in[15];
  const float* dc_o_w   = (const float*)d_in[16];
  const float* dc_ln1g  = (const float*)d_in[17];
  const float* dc_ln1b  = (const float*)d_in[18];
  const float* dc_c1w   = (const float*)d_in[19];
  const float* dc_c1b   = (const float*)d_in[20];
  const float* dc_c2w   = (const float*)d_in[21];
  const float* dc_c2b   = (const float*)d_in[22];
  const float* dc_ln2g  = (const float*)d_in[23];
  const float* dc_ln2b  = (const float*)d_in[24];
  const float* dp_c1w = (const float*)d_in[25];
  const float* dp_c1b = (const float*)d_in[26];
  const float* dp_ln1g = (const float*)d_in[27];
  const float* dp_ln1b = (const float*)d_in[28];
  const float* dp_c2w = (const float*)d_in[29];
  const float* dp_c2b = (const float*)d_in[30];
  const float* dp_ln2g = (const float*)d_in[31];
  const float* dp_ln2b = (const float*)d_in[32];
  const float* dp_fcw = (const float*)d_in[33];
  const float* dp_fcb = (const float*)d_in[34];
  const float* proj_w = (const float*)d_in[35];
  const float* proj_b = (const float*)d_in[36];

  char* ws = (char*)d_ws;
  size_t off = 0;
  auto alloc = [&](size_t bytes) -> char* {
    char* p = ws + off;
    off += (bytes + 255) & ~(size_t)255;
    return p;
  };

  __hip_bfloat16* qkvwt_e = (__hip_bfloat16*)alloc((size_t)6 * 256 * 384 * 2);
  __hip_bfloat16* qkvwt_d = (__hip_bfloat16*)alloc((size_t)6 * 256 * 384 * 2);
  __hip_bfloat16* owt_e   = (__hip_bfloat16*)alloc((size_t)6 * 384 * 64 * 2);
  __hip_bfloat16* owt_d   = (__hip_bfloat16*)alloc((size_t)6 * 384 * 64 * 2);
  __hip_bfloat16* c1wt_e  = (__hip_bfloat16*)alloc((size_t)6 * 3 * 1536 * 384 * 2);
  __hip_bfloat16* c1wt_d  = (__hip_bfloat16*)alloc((size_t)6 * 3 * 1536 * 384 * 2);
  __hip_bfloat16* c2wt_e  = (__hip_bfloat16*)alloc((size_t)6 * 3 * 384 * 1536 * 2);
  __hip_bfloat16* c2wt_d  = (__hip_bfloat16*)alloc((size_t)6 * 3 * 384 * 1536 * 2);
  __hip_bfloat16* dpc1wt  = (__hip_bfloat16*)alloc((size_t)3 * 256 * 384 * 2);
  __hip_bfloat16* dpc2wt  = (__hip_bfloat16*)alloc((size_t)3 * 256 * 256 * 2);
  __hip_bfloat16* projwt  = (__hip_bfloat16*)alloc((size_t)128 * 384 * 2);
  float* pe_e   = (float*)alloc((size_t)256 * 384 * 4);
  float* pe_d   = (float*)alloc((size_t)400 * 384 * 4);
  float* maskf_e = (float*)alloc((size_t)32 * 256 * 4);
  float* maskf_d = (float*)alloc((size_t)32 * 400 * 4);
  int*   idxbuf  = (int*)alloc((size_t)32 * 400 * 4);
  __hip_bfloat16* h_enc_bf = (__hip_bfloat16*)alloc((size_t)32 * 258 * 384 * 2);
  __hip_bfloat16* h_dec_bf = (__hip_bfloat16*)alloc((size_t)32 * 402 * 384 * 2);
  __hip_bfloat16* qkvbuf = (__hip_bfloat16*)alloc((size_t)32 * 402 * 192 * 2);
  __hip_bfloat16* vecbuf = (__hip_bfloat16*)alloc((size_t)32 * 402 * 64 * 2);
  __hip_bfloat16* tmp384 = (__hip_bfloat16*)alloc((size_t)32 * 402 * 384 * 2);
  __hip_bfloat16* cbuf   = (__hip_bfloat16*)alloc((size_t)32 * 402 * 1536 * 2);
  __hip_bfloat16* dp1b   = (__hip_bfloat16*)alloc((size_t)32 * 258 * 256 * 2);
  __hip_bfloat16* dp2b   = (__hip_bfloat16*)alloc((size_t)32 * 258 * 256 * 2);

  // ---- weight conversion ----
  transpose_cvt<<<dim3(12, 8, 6), dim3(32, 8), 0, stream>>>(e_qkv_w, qkvwt_e, 384, 192, 256);
  transpose_cvt<<<dim3(12, 8, 6), dim3(32, 8), 0, stream>>>(dc_qkv_w, qkvwt_d, 384, 192, 256);
  transpose_cvt<<<dim3(2, 12, 6), dim3(32, 8), 0, stream>>>(e_o_w, owt_e, 64, 384, 384);
  transpose_cvt<<<dim3(2, 12, 6), dim3(32, 8), 0, stream>>>(dc_o_w, owt_d, 64, 384, 384);
  transpose_cvt<<<dim3(12, 4, 1), dim3(32, 8), 0, stream>>>(proj_w, projwt, 384, 80, 128);
  {
    long long tot = 6LL * 3 * 1536 * 384;
    int blocks = (int)((tot + 255) / 256);
    conv_cvt<<<blocks, 256, 0, stream>>>(e_c1w, c1wt_e, 1536, 384, tot);
    conv_cvt<<<blocks, 256, 0, stream>>>(dc_c1w, c1wt_d, 1536, 384, tot);
    conv_cvt<<<blocks, 256, 0, stream>>>(e_c2w, c2wt_e, 384, 1536, tot);
    conv_cvt<<<blocks, 256, 0, stream>>>(dc_c2w, c2wt_d, 384, 1536, tot);
  }
  { long long tot = 3LL * 256 * 384; conv_cvt<<<(int)((tot + 255) / 256), 256, 0, stream>>>(dp_c1w, dpc1wt, 256, 384, tot); }
  { long long tot = 3LL * 256 * 256; conv_cvt<<<(int)((tot + 255) / 256), 256, 0, stream>>>(dp_c2w, dpc2wt, 256, 256, tot); }

  pe_kernel<<<(256 * 192 + 255) / 256, 256, 0, stream>>>(pe_e, 256);
  pe_kernel<<<(400 * 192 + 255) / 256, 256, 0, stream>>>(pe_d, 400);

  embed_kernel<<<32 * 256, 128, 0, stream>>>(inputs, emb, pe_e, maskf_e, h_enc_bf);
  zero_guards<<<64, 256, 0, stream>>>(h_enc_bf, 256, 384);
  zero_guards<<<64, 256, 0, stream>>>(cbuf, 256, 1536);

  // ---- encoder ----
  for (int l = 0; l < 6; ++l) {
    gemm_tn<64, 64, 2, 1, 384, false, false, true><<<dim3(128, 3), 256, 0, stream>>>(
        h_enc_bf, qkvwt_e + (size_t)l * 256 * 384, e_qkv_b + l * 192, qkvbuf,
        192, 192, 256, 256);
    fattn_kernel<<<dim3(4, 32), 256, 0, stream>>>(qkvbuf, maskf_e, vecbuf, 256, 4);
    gemm_tn<64, 64, 2, 1, 64, false, false, true><<<dim3(128, 6), 256, 0, stream>>>(
        vecbuf, owt_e + (size_t)l * 384 * 64, nullptr, tmp384,
        384, 384, 256, 384);
    ln_kernel<384, true, true><<<2048, 256, 0, stream>>>(
        tmp384, h_enc_bf, e_ln1g + l * 384, e_ln1b + l * 384, maskf_e, h_enc_bf, 256);
    gemm_tn<128, 128, 2, 3, 384, true, false, true><<<dim3(64, 12), 256, 0, stream>>>(
        h_enc_bf, c1wt_e + (size_t)l * 3 * 1536 * 384, e_c1b + l * 1536, cbuf,
        1536, 1536, 256, 1536);
    gemm_tn<64, 64, 2, 3, 1536, false, false, true><<<dim3(128, 6), 256, 0, stream>>>(
        cbuf, c2wt_e + (size_t)l * 3 * 384 * 1536, e_c2b + l * 384, tmp384,
        384, 384, 256, 384);
    ln_kernel<384, true, true><<<2048, 256, 0, stream>>>(
        tmp384, h_enc_bf, e_ln2g + l * 384, e_ln2b + l * 384, maskf_e, h_enc_bf, 256);
  }

  // ---- duration predictor ----
  zero_guards<<<64, 256, 0, stream>>>(dp1b, 256, 256);
  gemm_tn<64, 64, 2, 3, 384, true, false, true><<<dim3(128, 4), 256, 0, stream>>>(
      h_enc_bf, dpc1wt, dp_c1b, dp1b, 256, 256, 256, 256);
  ln_kernel<256, false, false><<<2048, 256, 0, stream>>>(
      dp1b, nullptr, dp_ln1g, dp_ln1b, nullptr, dp1b, 256);
  gemm_tn<64, 64, 2, 3, 256, true, false, true><<<dim3(128, 4), 256, 0, stream>>>(
      dp1b, dpc2wt, dp_c2b, dp2b, 256, 256, 256, 256);
  ln_kernel<256, false, false><<<2048, 256, 0, stream>>>(
      dp2b, nullptr, dp_ln2g, dp_ln2b, nullptr, dp2b, 256);
  dpfc_kernel<<<32 * 256, 64, 0, stream>>>(
      dp2b, dp_fcw, dp_fcb, maskf_e, outF + OFF_LOGDUR, outF + OFF_DUR);

  // ---- length regulator ----
  regulator_kernel<<<32, 512, 0, stream>>>(dur_tgt, maskf_d, idxbuf,
                                           outF + OFF_DMASK, outF + OFF_DLEN);
  zero_guards<<<64, 256, 0, stream>>>(h_dec_bf, 400, 384);
  zero_guards<<<64, 256, 0, stream>>>(cbuf, 400, 1536);
  build_y_kernel<<<32 * 400, 128, 0, stream>>>(h_enc_bf, idxbuf, maskf_d, pe_d, h_dec_bf);

  // ---- decoder ----
  for (int l = 0; l < 6; ++l) {
    gemm_tn<64, 64, 2, 1, 384, false, false, true><<<dim3(200, 3), 256, 0, stream>>>(
        h_dec_bf, qkvwt_d + (size_t)l * 256 * 384, dc_qkv_b + l * 192, qkvbuf,
        192, 192, 400, 256);
    fattn_kernel<<<dim3(7, 32), 256, 0, stream>>>(qkvbuf, maskf_d, vecbuf, 400, 7);
    gemm_tn<64, 64, 2, 1, 64, false, false, true><<<dim3(200, 6), 256, 0, stream>>>(
        vecbuf, owt_d + (size_t)l * 384 * 64, nullptr, tmp384,
        384, 384, 400, 384);
    ln_kernel<384, true, true><<<3200, 256, 0, stream>>>(
        tmp384, h_dec_bf, dc_ln1g + l * 384, dc_ln1b + l * 384, maskf_d, h_dec_bf, 400);
    gemm_tn<128, 128, 2, 3, 384, true, false, true><<<dim3(100, 12), 256, 0, stream>>>(
        h_dec_bf, c1wt_d + (size_t)l * 3 * 1536 * 384, dc_c1b + l * 1536, cbuf,
        1536, 1536, 400, 1536);
    gemm_tn<64, 64, 2, 3, 1536, false, false, true><<<dim3(200, 6), 256, 0, stream>>>(
        cbuf, c2wt_d + (size_t)l * 3 * 384 * 1536, dc_c2b + l * 384, tmp384,
        384, 384, 400, 384);
    ln_kernel<384, true, true><<<3200, 256, 0, stream>>>(
        tmp384, h_dec_bf, dc_ln2g + l * 384, dc_ln2b + l * 384, maskf_d, h_dec_bf, 400);
  }

  // ---- mel projection ----
  gemm_tn<64, 64, 2, 1, 384, false, true, false><<<dim3(200, 2), 256, 0, stream>>>(
      h_dec_bf, projwt, proj_b, outF + OFF_MEL, 80, 80, 400, 128);
}

// Round 12
// 2151.533 us; speedup vs baseline: 1.0385x; 1.0385x over previous
//
#include <hip/hip_runtime.h>
#include <hip/hip_bf16.h>
#include <stdint.h>

typedef __attribute__((ext_vector_type(8))) short bf16x8;   // 8 bf16 in 4 VGPRs (MFMA A/B operand)
typedef __attribute__((ext_vector_type(4))) float f32x4;    // MFMA C/D operand
typedef __attribute__((ext_vector_type(4))) unsigned int u32x4; // native 16B vec

// ---------------- model constants ----------------
static constexpr int BB = 32, SS = 256, DD = 384;
static constexpr int TDEC = 400;
static constexpr int NMELC = 80;

// d_out offsets (floats), return order: mel, dec_mask, dur_pred, log_dur_pred, dec_lens
static constexpr size_t OFF_MEL    = 0;
static constexpr size_t OFF_DMASK  = (size_t)BB * TDEC * NMELC;   // 1,024,000
static constexpr size_t OFF_DUR    = OFF_DMASK + (size_t)BB * TDEC;
static constexpr size_t OFF_LOGDUR = OFF_DUR + (size_t)BB * SS;
static constexpr size_t OFF_DLEN   = OFF_LOGDUR + (size_t)BB * SS;

// async global->LDS, 16B per lane (dest must be wave-uniform base + lane*16)
__device__ __forceinline__ void gld16(void* lds, const void* g) {
  __builtin_amdgcn_global_load_lds(
      (const __attribute__((address_space(1))) void*)g,
      (__attribute__((address_space(3))) void*)lds, 16, 0, 0);
}

// =================================================================
// Weight conversion
// =================================================================

// src: [L][R][C] f32  ->  dst: [L][Cpad][R] bf16 (transposed; zeros for c >= C)
__global__ __launch_bounds__(256)
void transpose_cvt(const float* __restrict__ src, __hip_bfloat16* __restrict__ dst,
                   int R, int C, int Cpad)
{
  __shared__ float tile[32][33];
  int l = blockIdx.z;
  src += (size_t)l * R * C;
  dst += (size_t)l * Cpad * R;
  int r0 = blockIdx.x * 32, c0 = blockIdx.y * 32;
  int tx = threadIdx.x, ty = threadIdx.y;
  for (int i = ty; i < 32; i += 8) {
    int c = c0 + tx;
    tile[i][tx] = (c < C) ? src[(size_t)(r0 + i) * C + c] : 0.f;
  }
  __syncthreads();
  for (int i = ty; i < 32; i += 8) {
    dst[(size_t)(c0 + i) * R + (r0 + tx)] = __float2bfloat16(tile[tx][i]);
  }
}

// src: [L][Cout][Cin][3] f32  ->  dst: [L][3][Cout][Cin] bf16
__global__ __launch_bounds__(256)
void conv_cvt(const float* __restrict__ src, __hip_bfloat16* __restrict__ dst,
              int Cout, int Cin, long long total)
{
  long long i = (long long)blockIdx.x * 256 + threadIdx.x;
  if (i >= total) return;
  int ci = (int)(i % Cin);
  long long t1 = i / Cin;
  int co = (int)(t1 % Cout);
  long long t2 = t1 / Cout;
  int tap = (int)(t2 % 3);
  int l = (int)(t2 / 3);
  dst[i] = __float2bfloat16(src[(((size_t)l * Cout + co) * Cin + ci) * 3 + tap]);
}

// =================================================================
// Positional embedding / embedding
// =================================================================

__global__ __launch_bounds__(256)
void pe_kernel(float* __restrict__ pe, int T)
{
  int i = blockIdx.x * 256 + threadIdx.x;
  if (i >= T * 192) return;
  int t = i / 192, j = i % 192;
  float inv = expf(-(float)j * (9.210340371976184f / 192.f));
  float s = (float)t * inv;
  pe[(size_t)t * 384 + j]       = sinf(s);
  pe[(size_t)t * 384 + 192 + j] = cosf(s);
}

__global__ __launch_bounds__(128)
void embed_kernel(const int* __restrict__ inputs, const float* __restrict__ emb,
                  const float* __restrict__ pe, float* __restrict__ maskf,
                  __hip_bfloat16* __restrict__ xb)
{
  int blk = blockIdx.x; int b = blk / SS, t = blk % SS;
  int tok = inputs[b * SS + t];
  float mk = (tok != 0) ? 1.f : 0.f;
  if (threadIdx.x == 0) maskf[b * SS + t] = mk;
  size_t prow = ((size_t)b * (SS + 2) + 1 + t) * 384;
  for (int c = threadIdx.x; c < 384; c += 128) {
    float v = emb[(size_t)tok * 384 + c] + pe[(size_t)t * 384 + c] * mk;
    xb[prow + c] = __float2bfloat16(v);
  }
}

__global__ __launch_bounds__(256)
void zero_guards(__hip_bfloat16* __restrict__ buf, int T, int C)
{
  int b = blockIdx.x >> 1, which = blockIdx.x & 1;
  size_t row = ((size_t)b * (T + 2) + (which ? (T + 1) : 0)) * (size_t)C;
  for (int c = threadIdx.x; c < C; c += 256) buf[row + c] = __float2bfloat16(0.f);
}

// =================================================================
// GEMM: C[M,N] = act( sum_tap A[m + tap - NTAPS/2, :] @ B_tap + bias )
// A: bf16, padded rows (B, T+2, K), guard rows zero. B: bf16 [NTAPS][Npad][K].
// TM x TN tile, 4 waves 2x2; wave (TM/2)x(TN/2); 16x16x32 fragments.
// BK=32, depth-DEPTH pipeline (DEPTH+1 buffers), counted vmcnt, R8 tail.
// STEP ORDER: ks-outer, TAP-INNER (s = ks*NTAPS + tap) — taps' A-reads
// overlap (rows m-1..m+TM) within one step window -> A fetched ~once
// through L1/L2 instead of NTAPS times (tap-outer evicted between passes).
// LDS chunk swizzle (conflicts~0).
// Block->tile map: per-XCD contiguous logical chunk (n-fast, bijective m204).
// Epilogue: bf16 C staged in LDS -> coalesced 16B row stores.
// =================================================================
template<int TM, int TN, int DEPTH, int NTAPS, int KV, bool RELU, bool OUTF32, bool CPAD>
__global__ __launch_bounds__(256)
void gemm_tn(const __hip_bfloat16* __restrict__ A,
             const __hip_bfloat16* __restrict__ Bw,
             const float* __restrict__ bias,
             void* __restrict__ Cout_,
             int N, int ldc, int T, int Npad)
{
  constexpr int KS = KV >> 5;          // 32-K steps per tap
  constexpr int NSTEP = NTAPS * KS;
  constexpr int DEP = (DEPTH < NSTEP) ? DEPTH : NSTEP;
  constexpr int NBUF = DEP + 1;
  constexpr int ABYTES = TM * 64;      // A bytes per buffer
  constexpr int BBYTES = TN * 64;      // B bytes per buffer
  constexpr int BUFB = ABYTES + BBYTES;
  constexpr int MI_N = TM / 32;        // m-fragments per wave
  constexpr int NI_N = TN / 32;        // n-fragments per wave
  constexpr int OPS = (TM == 128 ? 2 : 1) + (TN == 128 ? 2 : 1);  // gld16 per STAGE
  __shared__ __align__(16) char SH[NBUF * BUFB];

  const int tid = threadIdx.x;
  const int lane = tid & 63;
  const int w = tid >> 6;
  const int wm = w >> 1, wn = w & 1;

  // ---- per-XCD contiguous chunk mapping (bijective, m204; n-fast) ----
  const int GN = gridDim.y;
  const int NB = gridDim.x * GN;
  const int f = blockIdx.y * gridDim.x + blockIdx.x;
  const int qq = NB >> 3, rr8 = NB & 7;
  const int xcd = f & 7, pos = f >> 3;
  const int st = (xcd < rr8) ? xcd * (qq + 1) : rr8 * (qq + 1) + (xcd - rr8) * qq;
  const int L = st + pos;
  const int m0 = (L / GN) * TM;
  const int n0 = (L % GN) * TN;

  const int ar = tid >> 2;
  const int q = tid & 3;
  const int qsw = q ^ ((ar >> 1) & 3);         // pre-swizzled source chunk
  const int g0 = m0 + ar, g1 = g0 + 64;
  const char* sA0 = (const char*)A + (((size_t)(g0 + 2 * (g0 / T) + 1 - NTAPS / 2)) * KV + qsw * 8) * 2;
  const char* sA1 = (const char*)A + (((size_t)(g1 + 2 * (g1 / T) + 1 - NTAPS / 2)) * KV + qsw * 8) * 2;
  const char* sB0 = (const char*)Bw + ((size_t)(n0 + ar) * KV + qsw * 8) * 2;
  const char* sB1 = (const char*)Bw + ((size_t)(n0 + ar + 64) * KV + qsw * 8) * 2;

  const int woff = ar * 64 + q * 16;   // LDS byte offset (linear, tid*16)
  int tap_s = 0;

  const size_t AROW = (size_t)KV * 2;             // one A row (== tap shift)
  const size_t BPAN = (size_t)Npad * KV * 2;      // one B tap panel

  auto STAGE = [&](int buf) {
    char* base = SH + buf * BUFB;
    gld16(base + woff, sA0);
    if (TM == 128) gld16(base + 4096 + woff, sA1);
    gld16(base + ABYTES + woff, sB0);
    if (TN == 128) gld16(base + ABYTES + 4096 + woff, sB1);
  };
  auto ADV = [&]() {
    // tap-inner: next tap = +1 A row, +1 B panel; wrap -> next 32-K chunk
    sA0 += AROW; sA1 += AROW; sB0 += BPAN; sB1 += BPAN;
    if (++tap_s == NTAPS) {
      tap_s = 0;
      sA0 -= NTAPS * AROW - 64; sA1 -= NTAPS * AROW - 64;
      sB0 -= NTAPS * BPAN - 64; sB1 -= NTAPS * BPAN - 64;
    }
  };

  f32x4 zero = {0.f, 0.f, 0.f, 0.f};
  f32x4 acc[MI_N][NI_N];
#pragma unroll
  for (int i = 0; i < MI_N; i++)
#pragma unroll
    for (int j = 0; j < NI_N; j++) acc[i][j] = zero;

  const int rl = lane & 15;
  const int hi4 = lane >> 4;
  const int kb2 = (hi4 ^ ((rl >> 1) & 3)) * 16;   // swizzled read slot (bytes)

  // ---- prologue: fill DEP buffers ----
#pragma unroll
  for (int i = 0; i < DEP; ++i) { STAGE(i); ADV(); }
  if constexpr (DEP == NSTEP) {
    asm volatile("s_waitcnt vmcnt(0)" ::: "memory");
  } else {
    asm volatile("s_waitcnt vmcnt(%0)" :: "i"((DEP - 1) * OPS) : "memory");
  }
  __builtin_amdgcn_s_barrier();
  __builtin_amdgcn_sched_barrier(0);

  int cur = 0;
  for (int s = 0; s < NSTEP; ++s) {
    if (s + DEP < NSTEP) {
      int nb = cur + DEP; if (nb >= NBUF) nb -= NBUF;
      STAGE(nb); ADV();
    }
    const char* Ab = SH + cur * BUFB;
    const char* Bb = Ab + ABYTES;
    bf16x8 af[MI_N], bfr[NI_N];
#pragma unroll
    for (int mi = 0; mi < MI_N; mi++)
      af[mi] = *(const bf16x8*)(Ab + (wm * (TM / 2) + mi * 16 + rl) * 64 + kb2);
#pragma unroll
    for (int ni = 0; ni < NI_N; ni++)
      bfr[ni] = *(const bf16x8*)(Bb + (wn * (TN / 2) + ni * 16 + rl) * 64 + kb2);
#pragma unroll
    for (int mi = 0; mi < MI_N; mi++)
#pragma unroll
      for (int ni = 0; ni < NI_N; ni++)
        acc[mi][ni] = __builtin_amdgcn_mfma_f32_16x16x32_bf16(af[mi], bfr[ni], acc[mi][ni], 0, 0, 0);
    if (s + 1 < NSTEP) {
      if (s + DEP < NSTEP) {
        asm volatile("s_waitcnt vmcnt(%0)" :: "i"((DEP - 1) * OPS) : "memory");
      } else {
        asm volatile("s_waitcnt vmcnt(0)" ::: "memory");  // tail drain
      }
      __builtin_amdgcn_s_barrier();
      __builtin_amdgcn_sched_barrier(0);
    }
    cur = cur + 1; if (cur >= NBUF) cur -= NBUF;
  }

  // epilogue. C/D layout col=lane&15, row=(lane>>4)*4+j  [m89-verified]
  const int rj = hi4 * 4;
  if (!OUTF32) {
    // stage bf16 C-tile in LDS, then coalesced 16B row stores
    __syncthreads();                 // all waves done with K-loop LDS
    ushort* S = (ushort*)SH;         // [TM][TN] bf16
#pragma unroll
    for (int mi = 0; mi < MI_N; mi++) {
#pragma unroll
      for (int ni = 0; ni < NI_N; ni++) {
        int lc = wn * (TN / 2) + ni * 16 + rl;
        float bv = bias ? bias[n0 + lc] : 0.f;
#pragma unroll
        for (int j = 0; j < 4; j++) {
          float v = acc[mi][ni][j] + bv;
          if (RELU) v = fmaxf(v, 0.f);
          __hip_bfloat16 hb = __float2bfloat16(v);
          S[(wm * (TM / 2) + mi * 16 + rj + j) * TN + lc] = *(ushort*)&hb;
        }
      }
    }
    __syncthreads();
    constexpr int TPR = TN / 8;       // threads per row (16B each)
    constexpr int RPP = 256 / TPR;    // rows per pass
    const int tr = tid / TPR;
    const int tc = (tid % TPR) * 8;
#pragma unroll
    for (int pass = 0; pass < TM / RPP; ++pass) {
      int lr = pass * RPP + tr;
      int gcol = n0 + tc;
      if (gcol < N) {
        int r = m0 + lr;
        size_t orow = CPAD ? ((size_t)r + 2 * (r / T) + 1) : (size_t)r;
        *(u32x4*)((__hip_bfloat16*)Cout_ + orow * ldc + gcol) = *(const u32x4*)&S[lr * TN + tc];
      }
    }
  } else {
#pragma unroll
    for (int mi = 0; mi < MI_N; mi++) {
#pragma unroll
      for (int ni = 0; ni < NI_N; ni++) {
        int col = n0 + wn * (TN / 2) + ni * 16 + rl;
        if (col < N) {
          float bv = bias ? bias[col] : 0.f;
#pragma unroll
          for (int j = 0; j < 4; j++) {
            int r = m0 + wm * (TM / 2) + mi * 16 + rj + j;
            float v = acc[mi][ni][j] + bv;
            if (RELU) v = fmaxf(v, 0.f);
            size_t orow = CPAD ? ((size_t)r + 2 * (r / T) + 1) : (size_t)r;
            ((float*)Cout_)[orow * ldc + col] = v;
          }
        }
      }
    }
  }
}

// =================================================================
// Fused flash attention: 1 head, d=64. Block = (b, 64-query tile), 4 waves.
// =================================================================
__global__ __launch_bounds__(256)
void fattn_kernel(const __hip_bfloat16* __restrict__ qkv, const float* __restrict__ maskf,
                  __hip_bfloat16* __restrict__ vec, int T, int NT)
{
  __shared__ __align__(16) ushort VT[64][456];   // V^T: [d][key]
  __shared__ __align__(16) ushort Pl[4][16][72]; // per-wave P tile
  __shared__ float MS[448];                      // 0=ok, -1e9=masked, -1e38=pad

  const int tid = threadIdx.x;
  const int b = blockIdx.y;
  const int TP = T + 2;
  const int KTOT = NT * 64;
  const char* bptr = (const char*)qkv + ((size_t)b * TP + 1) * 384;

  for (int k = tid; k < KTOT; k += 256)
    MS[k] = (k < T) ? ((maskf[b * T + k] > 0.f) ? 0.f : -1e9f) : -1e38f;
  for (int i = tid; i < KTOT * 8; i += 256) {
    int k = i >> 3, seg = i & 7;
    int kr = (k < T) ? k : T - 1;
    uint4 u = *(const uint4*)(bptr + (size_t)kr * 384 + 256 + seg * 16);
    const ushort* e = (const ushort*)&u;
#pragma unroll
    for (int j = 0; j < 8; ++j) VT[seg * 8 + j][k] = e[j];
  }
  __syncthreads();

  const int w = tid >> 6, lane = tid & 63;
  const int lo = lane & 15, hi = lane >> 4;
  const int q0 = blockIdx.x * 64 + w * 16;
  const int qc = min(q0 + lo, T - 1);

  bf16x8 afr[2];
#pragma unroll
  for (int ks = 0; ks < 2; ++ks)
    afr[ks] = *(const bf16x8*)(bptr + (size_t)qc * 384 + ks * 64 + hi * 16);

  f32x4 Oacc[4];
  f32x4 z = {0.f, 0.f, 0.f, 0.f};
#pragma unroll
  for (int df = 0; df < 4; ++df) Oacc[df] = z;
  float mrun[4], lrun[4];
#pragma unroll
  for (int j = 0; j < 4; ++j) { mrun[j] = -3e38f; lrun[j] = 0.f; }

  for (int kt = 0; kt < NT; ++kt) {
    const int kb = kt * 64;
    f32x4 S[4];
#pragma unroll
    for (int f = 0; f < 4; ++f) S[f] = z;
#pragma unroll
    for (int ks = 0; ks < 2; ++ks) {
#pragma unroll
      for (int f = 0; f < 4; ++f) {
        int krc = min(kb + f * 16 + lo, T - 1);
        bf16x8 bfr = *(const bf16x8*)(bptr + (size_t)krc * 384 + 128 + ks * 64 + hi * 16);
        S[f] = __builtin_amdgcn_mfma_f32_16x16x32_bf16(afr[ks], bfr, S[f], 0, 0, 0);
      }
    }
    float sv[4][4];
#pragma unroll
    for (int f = 0; f < 4; ++f) {
      float msel = MS[kb + f * 16 + lo];
#pragma unroll
      for (int j = 0; j < 4; ++j) {
        float x = S[f][j] * 0.125f;
        sv[f][j] = (msel == 0.f) ? x : msel;
      }
    }
    float scale[4];
#pragma unroll
    for (int j = 0; j < 4; ++j) {
      float m4 = fmaxf(fmaxf(sv[0][j], sv[1][j]), fmaxf(sv[2][j], sv[3][j]));
#pragma unroll
      for (int msk = 1; msk < 16; msk <<= 1) m4 = fmaxf(m4, __shfl_xor(m4, msk));
      float mnew = fmaxf(mrun[j], m4);
      scale[j] = __expf(mrun[j] - mnew);
      mrun[j] = mnew;
    }
    float pv[4][4], ps[4] = {0.f, 0.f, 0.f, 0.f};
#pragma unroll
    for (int f = 0; f < 4; ++f)
#pragma unroll
      for (int j = 0; j < 4; ++j) {
        float p = __expf(sv[f][j] - mrun[j]);
        pv[f][j] = p; ps[j] += p;
      }
#pragma unroll
    for (int j = 0; j < 4; ++j) {
#pragma unroll
      for (int msk = 1; msk < 16; msk <<= 1) ps[j] += __shfl_xor(ps[j], msk);
      lrun[j] = lrun[j] * scale[j] + ps[j];
#pragma unroll
      for (int df = 0; df < 4; ++df) Oacc[df][j] *= scale[j];
    }
#pragma unroll
    for (int f = 0; f < 4; ++f)
#pragma unroll
      for (int j = 0; j < 4; ++j) {
        __hip_bfloat16 hb = __float2bfloat16(pv[f][j]);
        Pl[w][hi * 4 + j][f * 16 + lo] = *(ushort*)&hb;
      }
#pragma unroll
    for (int ks = 0; ks < 2; ++ks) {
      bf16x8 pa = *(const bf16x8*)((const char*)&Pl[w][lo][0] + ks * 64 + hi * 16);
#pragma unroll
      for (int df = 0; df < 4; ++df) {
        bf16x8 vfr = *(const bf16x8*)((const char*)&VT[df * 16 + lo][0] + kb * 2 + ks * 64 + hi * 16);
        Oacc[df] = __builtin_amdgcn_mfma_f32_16x16x32_bf16(pa, vfr, Oacc[df], 0, 0, 0);
      }
    }
  }

  float inv[4];
#pragma unroll
  for (int j = 0; j < 4; ++j) inv[j] = 1.f / lrun[j];
#pragma unroll
  for (int df = 0; df < 4; ++df)
#pragma unroll
    for (int j = 0; j < 4; ++j) {
      int qq = q0 + hi * 4 + j;
      if (qq < T) {
        __hip_bfloat16 hb = __float2bfloat16(Oacc[df][j] * inv[j]);
        *(ushort*)((char*)vec + ((size_t)b * TP + 1 + qq) * 128 + (df * 16 + lo) * 2) = *(ushort*)&hb;
      }
    }
}

// =================================================================
// LayerNorm (bf16 residual stream): out = LN(xin [+ resin]) * g + b [* mask]
// =================================================================
template<int C, bool HASRES, bool HASMASK>
__global__ __launch_bounds__(256)
void ln_kernel(const __hip_bfloat16* __restrict__ xin, const __hip_bfloat16* __restrict__ resin,
               const float* __restrict__ g, const float* __restrict__ bb,
               const float* __restrict__ maskf,
               __hip_bfloat16* __restrict__ outb, int T)
{
  constexpr int NU = C / 128;              // uint chunks per lane
  const int row = blockIdx.x * 4 + (threadIdx.x >> 6);
  const int lane = threadIdx.x & 63;
  const int b = row / T, t = row - b * T;
  const size_t prow = ((size_t)b * (T + 2) + 1 + t) * C;
  const uint* xu = (const uint*)(xin + prow);
  const uint* ru = (const uint*)(resin + prow);
  float v[2 * NU];
  float s1 = 0.f, s2 = 0.f;
#pragma unroll
  for (int k = 0; k < NU; ++k) {
    uint ux = xu[lane + 64 * k];
    uint xl = ux << 16, xh = ux & 0xffff0000u;
    float lo = *(float*)&xl, hi = *(float*)&xh;
    if (HASRES) {
      uint ur = ru[lane + 64 * k];
      uint rl2 = ur << 16, rh = ur & 0xffff0000u;
      lo += *(float*)&rl2; hi += *(float*)&rh;
    }
    v[2 * k] = lo; v[2 * k + 1] = hi;
    s1 += lo + hi; s2 += lo * lo + hi * hi;
  }
#pragma unroll
  for (int o = 32; o > 0; o >>= 1) { s1 += __shfl_xor(s1, o); s2 += __shfl_xor(s2, o); }
  float mu = s1 / C;
  float var = s2 / C - mu * mu;
  float rstd = rsqrtf(fmaxf(var, 0.f) + 1e-5f);
  float mk = HASMASK ? maskf[row] : 1.f;
  uint* ou = (uint*)(outb + prow);
#pragma unroll
  for (int k = 0; k < NU; ++k) {
    int c = (lane + 64 * k) * 2;
    float2 gv = *(const float2*)(g + c);
    float2 bv = *(const float2*)(bb + c);
    float lo = ((v[2 * k]     - mu) * rstd * gv.x + bv.x) * mk;
    float hi = ((v[2 * k + 1] - mu) * rstd * gv.y + bv.y) * mk;
    __hip_bfloat16 hl = __float2bfloat16(lo), hh = __float2bfloat16(hi);
    ou[lane + 64 * k] = (uint)(*(ushort*)&hl) | ((uint)(*(ushort*)&hh) << 16);
  }
}

// =================================================================
// Duration predictor FC + exp/clip
// =================================================================
__global__ __launch_bounds__(64)
void dpfc_kernel(const __hip_bfloat16* __restrict__ dp2, const float* __restrict__ fcw,
                 const float* __restrict__ fcb, const float* __restrict__ maskf,
                 float* __restrict__ logdur, float* __restrict__ durpred)
{
  int blk = blockIdx.x; int b = blk / SS, t = blk % SS;
  size_t prow = ((size_t)b * (SS + 2) + 1 + t) * 256;
  int lane = threadIdx.x;
  float a = 0.f;
  for (int c = lane; c < 256; c += 64) a += __bfloat162float(dp2[prow + c]) * fcw[c];
  for (int o = 32; o > 0; o >>= 1) a += __shfl_down(a, o);
  if (lane == 0) {
    float ld = (a + fcb[0]) * maskf[b * SS + t];
    logdur[b * SS + t] = ld;
    durpred[b * SS + t] = fminf(fmaxf(expf(ld) - 1.f, 0.f), 75.f);
  }
}

// =================================================================
// Length regulator
// =================================================================
__global__ __launch_bounds__(512)
void regulator_kernel(const float* __restrict__ dur, float* __restrict__ dmaskf,
                      int* __restrict__ idxbuf, float* __restrict__ out_dmask,
                      float* __restrict__ out_dlen)
{
  int b = blockIdx.x, tid = threadIdx.x;
  __shared__ int cum[256];
  __shared__ int len_s;
  if (tid < 256) cum[tid] = (int)rintf(dur[b * 256 + tid] / 0.0265f);
  __syncthreads();
  if (tid == 0) {
    int acc = 0;
    for (int i = 0; i < 256; i++) { acc += cum[i]; cum[i] = acc; }
    int len = acc < 400 ? acc : 400;
    len_s = len;
    out_dlen[b] = (float)len;
  }
  __syncthreads();
  if (tid < 400) {
    int p = tid;
    int lo = 0, hi = 256;
    while (lo < hi) { int mid = (lo + hi) >> 1; if (cum[mid] <= p) lo = mid + 1; else hi = mid; }
    int idx = lo < 255 ? lo : 255;
    idxbuf[b * 400 + p] = idx;
    float mk = (p < len_s) ? 1.f : 0.f;
    dmaskf[b * 400 + p] = mk;
    out_dmask[b * 400 + p] = mk;
  }
}

__global__ __launch_bounds__(128)
void build_y_kernel(const __hip_bfloat16* __restrict__ encb, const int* __restrict__ idxbuf,
                    const float* __restrict__ dmaskf, const float* __restrict__ pe,
                    __hip_bfloat16* __restrict__ yb)
{
  int blk = blockIdx.x; int b = blk / 400, p = blk % 400;
  float mk = dmaskf[b * 400 + p];
  int idx = idxbuf[b * 400 + p];
  size_t orowp = ((size_t)b * 402 + 1 + p) * 384;
  size_t srow = ((size_t)b * 258 + 1 + idx) * 384;
  for (int c = threadIdx.x; c < 384; c += 128) {
    float v = (mk > 0.f) ? (__bfloat162float(encb[srow + c]) + pe[(size_t)p * 384 + c]) : 40.f;
    yb[orowp + c] = __float2bfloat16(v);
  }
}

// =================================================================
// Orchestration
// =================================================================
extern "C" void kernel_launch(void* const* d_in, const int* in_sizes, int n_in,
                              void* d_out, int out_size, void* d_ws, size_t ws_size,
                              hipStream_t stream)
{
  (void)in_sizes; (void)n_in; (void)out_size; (void)ws_size;
  float* outF = (float*)d_out;

  const int*   inputs  = (const int*)d_in[0];
  const float* dur_tgt = (const float*)d_in[1];
  const float* emb     = (const float*)d_in[2];
  const float* e_qkv_w = (const float*)d_in[3];
  const float* e_qkv_b = (const float*)d_in[4];
  const float* e_o_w   = (const float*)d_in[5];
  const float* e_ln1g  = (const float*)d_in[6];
  const float* e_ln1b  = (const float*)d_in[7];
  const float* e_c1w   = (const float*)d_in[8];
  const float* e_c1b   = (const float*)d_in[9];
  const float* e_c2w   = (const float*)d_in[10];
  const float* e_c2b   = (const float*)d_in[11];
  const float* e_ln2g  = (const float*)d_in[12];
  const float* e_ln2b  = (const float*)d_in[13];
  const float* dc_qkv_w = (const float*)d_in[14];
  const float* dc_qkv_b = (const float*)d_in[15];
  const float* dc_o_w   = (const float*)d_in[16];
  const float* dc_ln1g  = (const float*)d_in[17];
  const float* dc_ln1b  = (const float*)d_in[18];
  const float* dc_c1w   = (const float*)d_in[19];
  const float* dc_c1b   = (const float*)d_in[20];
  const float* dc_c2w   = (const float*)d_in[21];
  const float* dc_c2b   = (const float*)d_in[22];
  const float* dc_ln2g  = (const float*)d_in[23];
  const float* dc_ln2b  = (const float*)d_in[24];
  const float* dp_c1w = (const float*)d_in[25];
  const float* dp_c1b = (const float*)d_in[26];
  const float* dp_ln1g = (const float*)d_in[27];
  const float* dp_ln1b = (const float*)d_in[28];
  const float* dp_c2w = (const float*)d_in[29];
  const float* dp_c2b = (const float*)d_in[30];
  const float* dp_ln2g = (const float*)d_in[31];
  const float* dp_ln2b = (const float*)d_in[32];
  const float* dp_fcw = (const float*)d_in[33];
  const float* dp_fcb = (const float*)d_in[34];
  const float* proj_w = (const float*)d_in[35];
  const float* proj_b = (const float*)d_in[36];

  char* ws = (char*)d_ws;
  size_t off = 0;
  auto alloc = [&](size_t bytes) -> char* {
    char* p = ws + off;
    off += (bytes + 255) & ~(size_t)255;
    return p;
  };

  __hip_bfloat16* qkvwt_e = (__hip_bfloat16*)alloc((size_t)6 * 256 * 384 * 2);
  __hip_bfloat16* qkvwt_d = (__hip_bfloat16*)alloc((size_t)6 * 256 * 384 * 2);
  __hip_bfloat16* owt_e   = (__hip_bfloat16*)alloc((size_t)6 * 384 * 64 * 2);
  __hip_bfloat16* owt_d   = (__hip_bfloat16*)alloc((size_t)6 * 384 * 64 * 2);
  __hip_bfloat16* c1wt_e  = (__hip_bfloat16*)alloc((size_t)6 * 3 * 1536 * 384 * 2);
  __hip_bfloat16* c1wt_d  = (__hip_bfloat16*)alloc((size_t)6 * 3 * 1536 * 384 * 2);
  __hip_bfloat16* c2wt_e  = (__hip_bfloat16*)alloc((size_t)6 * 3 * 384 * 1536 * 2);
  __hip_bfloat16* c2wt_d  = (__hip_bfloat16*)alloc((size_t)6 * 3 * 384 * 1536 * 2);
  __hip_bfloat16* dpc1wt  = (__hip_bfloat16*)alloc((size_t)3 * 256 * 384 * 2);
  __hip_bfloat16* dpc2wt  = (__hip_bfloat16*)alloc((size_t)3 * 256 * 256 * 2);
  __hip_bfloat16* projwt  = (__hip_bfloat16*)alloc((size_t)128 * 384 * 2);
  float* pe_e   = (float*)alloc((size_t)256 * 384 * 4);
  float* pe_d   = (float*)alloc((size_t)400 * 384 * 4);
  float* maskf_e = (float*)alloc((size_t)32 * 256 * 4);
  float* maskf_d = (float*)alloc((size_t)32 * 400 * 4);
  int*   idxbuf  = (int*)alloc((size_t)32 * 400 * 4);
  __hip_bfloat16* h_enc_bf = (__hip_bfloat16*)alloc((size_t)32 * 258 * 384 * 2);
  __hip_bfloat16* h_dec_bf = (__hip_bfloat16*)alloc((size_t)32 * 402 * 384 * 2);
  __hip_bfloat16* qkvbuf = (__hip_bfloat16*)alloc((size_t)32 * 402 * 192 * 2);
  __hip_bfloat16* vecbuf = (__hip_bfloat16*)alloc((size_t)32 * 402 * 64 * 2);
  __hip_bfloat16* tmp384 = (__hip_bfloat16*)alloc((size_t)32 * 402 * 384 * 2);
  __hip_bfloat16* cbuf   = (__hip_bfloat16*)alloc((size_t)32 * 402 * 1536 * 2);
  __hip_bfloat16* dp1b   = (__hip_bfloat16*)alloc((size_t)32 * 258 * 256 * 2);
  __hip_bfloat16* dp2b   = (__hip_bfloat16*)alloc((size_t)32 * 258 * 256 * 2);

  // ---- weight conversion ----
  transpose_cvt<<<dim3(12, 8, 6), dim3(32, 8), 0, stream>>>(e_qkv_w, qkvwt_e, 384, 192, 256);
  transpose_cvt<<<dim3(12, 8, 6), dim3(32, 8), 0, stream>>>(dc_qkv_w, qkvwt_d, 384, 192, 256);
  transpose_cvt<<<dim3(2, 12, 6), dim3(32, 8), 0, stream>>>(e_o_w, owt_e, 64, 384, 384);
  transpose_cvt<<<dim3(2, 12, 6), dim3(32, 8), 0, stream>>>(dc_o_w, owt_d, 64, 384, 384);
  transpose_cvt<<<dim3(12, 4, 1), dim3(32, 8), 0, stream>>>(proj_w, projwt, 384, 80, 128);
  {
    long long tot = 6LL * 3 * 1536 * 384;
    int blocks = (int)((tot + 255) / 256);
    conv_cvt<<<blocks, 256, 0, stream>>>(e_c1w, c1wt_e, 1536, 384, tot);
    conv_cvt<<<blocks, 256, 0, stream>>>(dc_c1w, c1wt_d, 1536, 384, tot);
    conv_cvt<<<blocks, 256, 0, stream>>>(e_c2w, c2wt_e, 384, 1536, tot);
    conv_cvt<<<blocks, 256, 0, stream>>>(dc_c2w, c2wt_d, 384, 1536, tot);
  }
  { long long tot = 3LL * 256 * 384; conv_cvt<<<(int)((tot + 255) / 256), 256, 0, stream>>>(dp_c1w, dpc1wt, 256, 384, tot); }
  { long long tot = 3LL * 256 * 256; conv_cvt<<<(int)((tot + 255) / 256), 256, 0, stream>>>(dp_c2w, dpc2wt, 256, 256, tot); }

  pe_kernel<<<(256 * 192 + 255) / 256, 256, 0, stream>>>(pe_e, 256);
  pe_kernel<<<(400 * 192 + 255) / 256, 256, 0, stream>>>(pe_d, 400);

  embed_kernel<<<32 * 256, 128, 0, stream>>>(inputs, emb, pe_e, maskf_e, h_enc_bf);
  zero_guards<<<64, 256, 0, stream>>>(h_enc_bf, 256, 384);
  zero_guards<<<64, 256, 0, stream>>>(cbuf, 256, 1536);

  // ---- encoder ----
  for (int l = 0; l < 6; ++l) {
    gemm_tn<64, 128, 2, 1, 384, false, false, true><<<dim3(128, 2), 256, 0, stream>>>(
        h_enc_bf, qkvwt_e + (size_t)l * 256 * 384, e_qkv_b + l * 192, qkvbuf,
        192, 192, 256, 256);
    fattn_kernel<<<dim3(4, 32), 256, 0, stream>>>(qkvbuf, maskf_e, vecbuf, 256, 4);
    gemm_tn<64, 128, 2, 1, 64, false, false, true><<<dim3(128, 3), 256, 0, stream>>>(
        vecbuf, owt_e + (size_t)l * 384 * 64, nullptr, tmp384,
        384, 384, 256, 384);
    ln_kernel<384, true, true><<<2048, 256, 0, stream>>>(
        tmp384, h_enc_bf, e_ln1g + l * 384, e_ln1b + l * 384, maskf_e, h_enc_bf, 256);
    gemm_tn<128, 128, 2, 3, 384, true, false, true><<<dim3(64, 12), 256, 0, stream>>>(
        h_enc_bf, c1wt_e + (size_t)l * 3 * 1536 * 384, e_c1b + l * 1536, cbuf,
        1536, 1536, 256, 1536);
    gemm_tn<64, 128, 2, 3, 1536, false, false, true><<<dim3(128, 3), 256, 0, stream>>>(
        cbuf, c2wt_e + (size_t)l * 3 * 384 * 1536, e_c2b + l * 384, tmp384,
        384, 384, 256, 384);
    ln_kernel<384, true, true><<<2048, 256, 0, stream>>>(
        tmp384, h_enc_bf, e_ln2g + l * 384, e_ln2b + l * 384, maskf_e, h_enc_bf, 256);
  }

  // ---- duration predictor ----
  zero_guards<<<64, 256, 0, stream>>>(dp1b, 256, 256);
  gemm_tn<64, 128, 2, 3, 384, true, false, true><<<dim3(128, 2), 256, 0, stream>>>(
      h_enc_bf, dpc1wt, dp_c1b, dp1b, 256, 256, 256, 256);
  ln_kernel<256, false, false><<<2048, 256, 0, stream>>>(
      dp1b, nullptr, dp_ln1g, dp_ln1b, nullptr, dp1b, 256);
  gemm_tn<64, 128, 2, 3, 256, true, false, true><<<dim3(128, 2), 256, 0, stream>>>(
      dp1b, dpc2wt, dp_c2b, dp2b, 256, 256, 256, 256);
  ln_kernel<256, false, false><<<2048, 256, 0, stream>>>(
      dp2b, nullptr, dp_ln2g, dp_ln2b, nullptr, dp2b, 256);
  dpfc_kernel<<<32 * 256, 64, 0, stream>>>(
      dp2b, dp_fcw, dp_fcb, maskf_e, outF + OFF_LOGDUR, outF + OFF_DUR);

  // ---- length regulator ----
  regulator_kernel<<<32, 512, 0, stream>>>(dur_tgt, maskf_d, idxbuf,
                                           outF + OFF_DMASK, outF + OFF_DLEN);
  zero_guards<<<64, 256, 0, stream>>>(h_dec_bf, 400, 384);
  zero_guards<<<64, 256, 0, stream>>>(cbuf, 400, 1536);
  build_y_kernel<<<32 * 400, 128, 0, stream>>>(h_enc_bf, idxbuf, maskf_d, pe_d, h_dec_bf);

  // ---- decoder ----
  for (int l = 0; l < 6; ++l) {
    gemm_tn<64, 128, 2, 1, 384, false, false, true><<<dim3(200, 2), 256, 0, stream>>>(
        h_dec_bf, qkvwt_d + (size_t)l * 256 * 384, dc_qkv_b + l * 192, qkvbuf,
        192, 192, 400, 256);
    fattn_kernel<<<dim3(7, 32), 256, 0, stream>>>(qkvbuf, maskf_d, vecbuf, 400, 7);
    gemm_tn<64, 128, 2, 1, 64, false, false, true><<<dim3(200, 3), 256, 0, stream>>>(
        vecbuf, owt_d + (size_t)l * 384 * 64, nullptr, tmp384,
        384, 384, 400, 384);
    ln_kernel<384, true, true><<<3200, 256, 0, stream>>>(
        tmp384, h_dec_bf, dc_ln1g + l * 384, dc_ln1b + l * 384, maskf_d, h_dec_bf, 400);
    gemm_tn<128, 128, 2, 3, 384, true, false, true><<<dim3(100, 12), 256, 0, stream>>>(
        h_dec_bf, c1wt_d + (size_t)l * 3 * 1536 * 384, dc_c1b + l * 1536, cbuf,
        1536, 1536, 400, 1536);
    gemm_tn<64, 128, 2, 3, 1536, false, false, true><<<dim3(200, 3), 256, 0, stream>>>(
        cbuf, c2wt_d + (size_t)l * 3 * 384 * 1536, dc_c2b + l * 384, tmp384,
        384, 384, 400, 384);
    ln_kernel<384, true, true><<<3200, 256, 0, stream>>>(
        tmp384, h_dec_bf, dc_ln2g + l * 384, dc_ln2b + l * 384, maskf_d, h_dec_bf, 400);
  }

  // ---- mel projection ----
  gemm_tn<64, 128, 2, 1, 384, false, true, false><<<dim3(200, 1), 256, 0, stream>>>(
      h_dec_bf, projwt, proj_b, outF + OFF_MEL, 80, 80, 400, 128);
}

// Round 13
// 2149.595 us; speedup vs baseline: 1.0394x; 1.0009x over previous
//
#include <hip/hip_runtime.h>
#include <hip/hip_bf16.h>
#include <stdint.h>

typedef __attribute__((ext_vector_type(8))) short bf16x8;   // 8 bf16 in 4 VGPRs (MFMA A/B operand)
typedef __attribute__((ext_vector_type(4))) float f32x4;    // MFMA C/D operand
typedef __attribute__((ext_vector_type(4))) unsigned int u32x4; // native 16B vec

// ---------------- model constants ----------------
static constexpr int BB = 32, SS = 256, DD = 384;
static constexpr int TDEC = 400;
static constexpr int NMELC = 80;

// d_out offsets (floats), return order: mel, dec_mask, dur_pred, log_dur_pred, dec_lens
static constexpr size_t OFF_MEL    = 0;
static constexpr size_t OFF_DMASK  = (size_t)BB * TDEC * NMELC;   // 1,024,000
static constexpr size_t OFF_DUR    = OFF_DMASK + (size_t)BB * TDEC;
static constexpr size_t OFF_LOGDUR = OFF_DUR + (size_t)BB * SS;
static constexpr size_t OFF_DLEN   = OFF_LOGDUR + (size_t)BB * SS;

// async global->LDS, 16B per lane (dest must be wave-uniform base + lane*16)
__device__ __forceinline__ void gld16(void* lds, const void* g) {
  __builtin_amdgcn_global_load_lds(
      (const __attribute__((address_space(1))) void*)g,
      (__attribute__((address_space(3))) void*)lds, 16, 0, 0);
}

// =================================================================
// Weight conversion
// =================================================================

// src: [L][R][C] f32  ->  dst: [L][Cpad][R] bf16 (transposed; zeros for c >= C)
__global__ __launch_bounds__(256)
void transpose_cvt(const float* __restrict__ src, __hip_bfloat16* __restrict__ dst,
                   int R, int C, int Cpad)
{
  __shared__ float tile[32][33];
  int l = blockIdx.z;
  src += (size_t)l * R * C;
  dst += (size_t)l * Cpad * R;
  int r0 = blockIdx.x * 32, c0 = blockIdx.y * 32;
  int tx = threadIdx.x, ty = threadIdx.y;
  for (int i = ty; i < 32; i += 8) {
    int c = c0 + tx;
    tile[i][tx] = (c < C) ? src[(size_t)(r0 + i) * C + c] : 0.f;
  }
  __syncthreads();
  for (int i = ty; i < 32; i += 8) {
    dst[(size_t)(c0 + i) * R + (r0 + tx)] = __float2bfloat16(tile[tx][i]);
  }
}

// src: [L][Cout][Cin][3] f32  ->  dst: [L][3][Cout][Cin] bf16
__global__ __launch_bounds__(256)
void conv_cvt(const float* __restrict__ src, __hip_bfloat16* __restrict__ dst,
              int Cout, int Cin, long long total)
{
  long long i = (long long)blockIdx.x * 256 + threadIdx.x;
  if (i >= total) return;
  int ci = (int)(i % Cin);
  long long t1 = i / Cin;
  int co = (int)(t1 % Cout);
  long long t2 = t1 / Cout;
  int tap = (int)(t2 % 3);
  int l = (int)(t2 / 3);
  dst[i] = __float2bfloat16(src[(((size_t)l * Cout + co) * Cin + ci) * 3 + tap]);
}

// =================================================================
// Positional embedding / embedding
// =================================================================

__global__ __launch_bounds__(256)
void pe_kernel(float* __restrict__ pe, int T)
{
  int i = blockIdx.x * 256 + threadIdx.x;
  if (i >= T * 192) return;
  int t = i / 192, j = i % 192;
  float inv = expf(-(float)j * (9.210340371976184f / 192.f));
  float s = (float)t * inv;
  pe[(size_t)t * 384 + j]       = sinf(s);
  pe[(size_t)t * 384 + 192 + j] = cosf(s);
}

__global__ __launch_bounds__(128)
void embed_kernel(const int* __restrict__ inputs, const float* __restrict__ emb,
                  const float* __restrict__ pe, float* __restrict__ maskf,
                  __hip_bfloat16* __restrict__ xb)
{
  int blk = blockIdx.x; int b = blk / SS, t = blk % SS;
  int tok = inputs[b * SS + t];
  float mk = (tok != 0) ? 1.f : 0.f;
  if (threadIdx.x == 0) maskf[b * SS + t] = mk;
  size_t prow = ((size_t)b * (SS + 2) + 1 + t) * 384;
  for (int c = threadIdx.x; c < 384; c += 128) {
    float v = emb[(size_t)tok * 384 + c] + pe[(size_t)t * 384 + c] * mk;
    xb[prow + c] = __float2bfloat16(v);
  }
}

__global__ __launch_bounds__(256)
void zero_guards(__hip_bfloat16* __restrict__ buf, int T, int C)
{
  int b = blockIdx.x >> 1, which = blockIdx.x & 1;
  size_t row = ((size_t)b * (T + 2) + (which ? (T + 1) : 0)) * (size_t)C;
  for (int c = threadIdx.x; c < C; c += 256) buf[row + c] = __float2bfloat16(0.f);
}

// =================================================================
// GEMM: C[M,N] = act( sum_tap A[m + tap - NTAPS/2, :] @ B_tap + bias )
// A: bf16, padded rows (B, T+2, K), guard rows zero. B: bf16 [NTAPS][Npad][K].
// TM x TN tile, 4 waves 2x2; wave (TM/2)x(TN/2); 16x16x32 fragments.
// BK=32, depth-DEPTH pipeline (DEPTH+1 buffers), counted vmcnt, R8 tail.
// STEP ORDER: ks-outer, TAP-INNER (A fetched ~once; R12-verified FETCH drop).
// LDS chunk swizzle (conflicts~0).
// Block->tile map: per-XCD contiguous logical chunk (n-fast, bijective m204).
// Epilogue: bf16 C staged in LDS -> coalesced 16B row stores.
// DEPTH=3 for TM=64 path: grid-limited occupancy means NBUF=4 (49KB) is free;
// lookahead 2 steps (~1400cy) covers HBM miss latency (~900cy, m126).
// =================================================================
template<int TM, int TN, int DEPTH, int NTAPS, int KV, bool RELU, bool OUTF32, bool CPAD>
__global__ __launch_bounds__(256)
void gemm_tn(const __hip_bfloat16* __restrict__ A,
             const __hip_bfloat16* __restrict__ Bw,
             const float* __restrict__ bias,
             void* __restrict__ Cout_,
             int N, int ldc, int T, int Npad)
{
  constexpr int KS = KV >> 5;          // 32-K steps per tap
  constexpr int NSTEP = NTAPS * KS;
  constexpr int DEP = (DEPTH < NSTEP) ? DEPTH : NSTEP;
  constexpr int NBUF = DEP + 1;
  constexpr int ABYTES = TM * 64;      // A bytes per buffer
  constexpr int BBYTES = TN * 64;      // B bytes per buffer
  constexpr int BUFB = ABYTES + BBYTES;
  constexpr int MI_N = TM / 32;        // m-fragments per wave
  constexpr int NI_N = TN / 32;        // n-fragments per wave
  constexpr int OPS = (TM == 128 ? 2 : 1) + (TN == 128 ? 2 : 1);  // gld16 per STAGE
  __shared__ __align__(16) char SH[NBUF * BUFB];

  const int tid = threadIdx.x;
  const int lane = tid & 63;
  const int w = tid >> 6;
  const int wm = w >> 1, wn = w & 1;

  // ---- per-XCD contiguous chunk mapping (bijective, m204; n-fast) ----
  const int GN = gridDim.y;
  const int NB = gridDim.x * GN;
  const int f = blockIdx.y * gridDim.x + blockIdx.x;
  const int qq = NB >> 3, rr8 = NB & 7;
  const int xcd = f & 7, pos = f >> 3;
  const int st = (xcd < rr8) ? xcd * (qq + 1) : rr8 * (qq + 1) + (xcd - rr8) * qq;
  const int L = st + pos;
  const int m0 = (L / GN) * TM;
  const int n0 = (L % GN) * TN;

  const int ar = tid >> 2;
  const int q = tid & 3;
  const int qsw = q ^ ((ar >> 1) & 3);         // pre-swizzled source chunk
  const int g0 = m0 + ar, g1 = g0 + 64;
  const char* sA0 = (const char*)A + (((size_t)(g0 + 2 * (g0 / T) + 1 - NTAPS / 2)) * KV + qsw * 8) * 2;
  const char* sA1 = (const char*)A + (((size_t)(g1 + 2 * (g1 / T) + 1 - NTAPS / 2)) * KV + qsw * 8) * 2;
  const char* sB0 = (const char*)Bw + ((size_t)(n0 + ar) * KV + qsw * 8) * 2;
  const char* sB1 = (const char*)Bw + ((size_t)(n0 + ar + 64) * KV + qsw * 8) * 2;

  const int woff = ar * 64 + q * 16;   // LDS byte offset (linear, tid*16)
  int tap_s = 0;

  const size_t AROW = (size_t)KV * 2;             // one A row (== tap shift)
  const size_t BPAN = (size_t)Npad * KV * 2;      // one B tap panel

  auto STAGE = [&](int buf) {
    char* base = SH + buf * BUFB;
    gld16(base + woff, sA0);
    if (TM == 128) gld16(base + 4096 + woff, sA1);
    gld16(base + ABYTES + woff, sB0);
    if (TN == 128) gld16(base + ABYTES + 4096 + woff, sB1);
  };
  auto ADV = [&]() {
    // tap-inner: next tap = +1 A row, +1 B panel; wrap -> next 32-K chunk
    sA0 += AROW; sA1 += AROW; sB0 += BPAN; sB1 += BPAN;
    if (++tap_s == NTAPS) {
      tap_s = 0;
      sA0 -= NTAPS * AROW - 64; sA1 -= NTAPS * AROW - 64;
      sB0 -= NTAPS * BPAN - 64; sB1 -= NTAPS * BPAN - 64;
    }
  };

  f32x4 zero = {0.f, 0.f, 0.f, 0.f};
  f32x4 acc[MI_N][NI_N];
#pragma unroll
  for (int i = 0; i < MI_N; i++)
#pragma unroll
    for (int j = 0; j < NI_N; j++) acc[i][j] = zero;

  const int rl = lane & 15;
  const int hi4 = lane >> 4;
  const int kb2 = (hi4 ^ ((rl >> 1) & 3)) * 16;   // swizzled read slot (bytes)

  // ---- prologue: fill DEP buffers ----
#pragma unroll
  for (int i = 0; i < DEP; ++i) { STAGE(i); ADV(); }
  if constexpr (DEP == NSTEP) {
    asm volatile("s_waitcnt vmcnt(0)" ::: "memory");
  } else {
    asm volatile("s_waitcnt vmcnt(%0)" :: "i"((DEP - 1) * OPS) : "memory");
  }
  __builtin_amdgcn_s_barrier();
  __builtin_amdgcn_sched_barrier(0);

  int cur = 0;
  for (int s = 0; s < NSTEP; ++s) {
    if (s + DEP < NSTEP) {
      int nb = cur + DEP; if (nb >= NBUF) nb -= NBUF;
      STAGE(nb); ADV();
    }
    const char* Ab = SH + cur * BUFB;
    const char* Bb = Ab + ABYTES;
    bf16x8 af[MI_N], bfr[NI_N];
#pragma unroll
    for (int mi = 0; mi < MI_N; mi++)
      af[mi] = *(const bf16x8*)(Ab + (wm * (TM / 2) + mi * 16 + rl) * 64 + kb2);
#pragma unroll
    for (int ni = 0; ni < NI_N; ni++)
      bfr[ni] = *(const bf16x8*)(Bb + (wn * (TN / 2) + ni * 16 + rl) * 64 + kb2);
#pragma unroll
    for (int mi = 0; mi < MI_N; mi++)
#pragma unroll
      for (int ni = 0; ni < NI_N; ni++)
        acc[mi][ni] = __builtin_amdgcn_mfma_f32_16x16x32_bf16(af[mi], bfr[ni], acc[mi][ni], 0, 0, 0);
    if (s + 1 < NSTEP) {
      if (s + DEP < NSTEP) {
        asm volatile("s_waitcnt vmcnt(%0)" :: "i"((DEP - 1) * OPS) : "memory");
      } else {
        asm volatile("s_waitcnt vmcnt(0)" ::: "memory");  // tail drain
      }
      __builtin_amdgcn_s_barrier();
      __builtin_amdgcn_sched_barrier(0);
    }
    cur = cur + 1; if (cur >= NBUF) cur -= NBUF;
  }

  // epilogue. C/D layout col=lane&15, row=(lane>>4)*4+j  [m89-verified]
  const int rj = hi4 * 4;
  if (!OUTF32) {
    // stage bf16 C-tile in LDS, then coalesced 16B row stores
    __syncthreads();                 // all waves done with K-loop LDS
    ushort* S = (ushort*)SH;         // [TM][TN] bf16
#pragma unroll
    for (int mi = 0; mi < MI_N; mi++) {
#pragma unroll
      for (int ni = 0; ni < NI_N; ni++) {
        int lc = wn * (TN / 2) + ni * 16 + rl;
        float bv = bias ? bias[n0 + lc] : 0.f;
#pragma unroll
        for (int j = 0; j < 4; j++) {
          float v = acc[mi][ni][j] + bv;
          if (RELU) v = fmaxf(v, 0.f);
          __hip_bfloat16 hb = __float2bfloat16(v);
          S[(wm * (TM / 2) + mi * 16 + rj + j) * TN + lc] = *(ushort*)&hb;
        }
      }
    }
    __syncthreads();
    constexpr int TPR = TN / 8;       // threads per row (16B each)
    constexpr int RPP = 256 / TPR;    // rows per pass
    const int tr = tid / TPR;
    const int tc = (tid % TPR) * 8;
#pragma unroll
    for (int pass = 0; pass < TM / RPP; ++pass) {
      int lr = pass * RPP + tr;
      int gcol = n0 + tc;
      if (gcol < N) {
        int r = m0 + lr;
        size_t orow = CPAD ? ((size_t)r + 2 * (r / T) + 1) : (size_t)r;
        *(u32x4*)((__hip_bfloat16*)Cout_ + orow * ldc + gcol) = *(const u32x4*)&S[lr * TN + tc];
      }
    }
  } else {
#pragma unroll
    for (int mi = 0; mi < MI_N; mi++) {
#pragma unroll
      for (int ni = 0; ni < NI_N; ni++) {
        int col = n0 + wn * (TN / 2) + ni * 16 + rl;
        if (col < N) {
          float bv = bias ? bias[col] : 0.f;
#pragma unroll
          for (int j = 0; j < 4; j++) {
            int r = m0 + wm * (TM / 2) + mi * 16 + rj + j;
            float v = acc[mi][ni][j] + bv;
            if (RELU) v = fmaxf(v, 0.f);
            size_t orow = CPAD ? ((size_t)r + 2 * (r / T) + 1) : (size_t)r;
            ((float*)Cout_)[orow * ldc + col] = v;
          }
        }
      }
    }
  }
}

// =================================================================
// Fused flash attention: 1 head, d=64. Block = (b, 64-query tile), 4 waves.
// =================================================================
__global__ __launch_bounds__(256)
void fattn_kernel(const __hip_bfloat16* __restrict__ qkv, const float* __restrict__ maskf,
                  __hip_bfloat16* __restrict__ vec, int T, int NT)
{
  __shared__ __align__(16) ushort VT[64][456];   // V^T: [d][key]
  __shared__ __align__(16) ushort Pl[4][16][72]; // per-wave P tile
  __shared__ float MS[448];                      // 0=ok, -1e9=masked, -1e38=pad

  const int tid = threadIdx.x;
  const int b = blockIdx.y;
  const int TP = T + 2;
  const int KTOT = NT * 64;
  const char* bptr = (const char*)qkv + ((size_t)b * TP + 1) * 384;

  for (int k = tid; k < KTOT; k += 256)
    MS[k] = (k < T) ? ((maskf[b * T + k] > 0.f) ? 0.f : -1e9f) : -1e38f;
  for (int i = tid; i < KTOT * 8; i += 256) {
    int k = i >> 3, seg = i & 7;
    int kr = (k < T) ? k : T - 1;
    uint4 u = *(const uint4*)(bptr + (size_t)kr * 384 + 256 + seg * 16);
    const ushort* e = (const ushort*)&u;
#pragma unroll
    for (int j = 0; j < 8; ++j) VT[seg * 8 + j][k] = e[j];
  }
  __syncthreads();

  const int w = tid >> 6, lane = tid & 63;
  const int lo = lane & 15, hi = lane >> 4;
  const int q0 = blockIdx.x * 64 + w * 16;
  const int qc = min(q0 + lo, T - 1);

  bf16x8 afr[2];
#pragma unroll
  for (int ks = 0; ks < 2; ++ks)
    afr[ks] = *(const bf16x8*)(bptr + (size_t)qc * 384 + ks * 64 + hi * 16);

  f32x4 Oacc[4];
  f32x4 z = {0.f, 0.f, 0.f, 0.f};
#pragma unroll
  for (int df = 0; df < 4; ++df) Oacc[df] = z;
  float mrun[4], lrun[4];
#pragma unroll
  for (int j = 0; j < 4; ++j) { mrun[j] = -3e38f; lrun[j] = 0.f; }

  for (int kt = 0; kt < NT; ++kt) {
    const int kb = kt * 64;
    f32x4 S[4];
#pragma unroll
    for (int f = 0; f < 4; ++f) S[f] = z;
#pragma unroll
    for (int ks = 0; ks < 2; ++ks) {
#pragma unroll
      for (int f = 0; f < 4; ++f) {
        int krc = min(kb + f * 16 + lo, T - 1);
        bf16x8 bfr = *(const bf16x8*)(bptr + (size_t)krc * 384 + 128 + ks * 64 + hi * 16);
        S[f] = __builtin_amdgcn_mfma_f32_16x16x32_bf16(afr[ks], bfr, S[f], 0, 0, 0);
      }
    }
    float sv[4][4];
#pragma unroll
    for (int f = 0; f < 4; ++f) {
      float msel = MS[kb + f * 16 + lo];
#pragma unroll
      for (int j = 0; j < 4; ++j) {
        float x = S[f][j] * 0.125f;
        sv[f][j] = (msel == 0.f) ? x : msel;
      }
    }
    float scale[4];
#pragma unroll
    for (int j = 0; j < 4; ++j) {
      float m4 = fmaxf(fmaxf(sv[0][j], sv[1][j]), fmaxf(sv[2][j], sv[3][j]));
#pragma unroll
      for (int msk = 1; msk < 16; msk <<= 1) m4 = fmaxf(m4, __shfl_xor(m4, msk));
      float mnew = fmaxf(mrun[j], m4);
      scale[j] = __expf(mrun[j] - mnew);
      mrun[j] = mnew;
    }
    float pv[4][4], ps[4] = {0.f, 0.f, 0.f, 0.f};
#pragma unroll
    for (int f = 0; f < 4; ++f)
#pragma unroll
      for (int j = 0; j < 4; ++j) {
        float p = __expf(sv[f][j] - mrun[j]);
        pv[f][j] = p; ps[j] += p;
      }
#pragma unroll
    for (int j = 0; j < 4; ++j) {
#pragma unroll
      for (int msk = 1; msk < 16; msk <<= 1) ps[j] += __shfl_xor(ps[j], msk);
      lrun[j] = lrun[j] * scale[j] + ps[j];
#pragma unroll
      for (int df = 0; df < 4; ++df) Oacc[df][j] *= scale[j];
    }
#pragma unroll
    for (int f = 0; f < 4; ++f)
#pragma unroll
      for (int j = 0; j < 4; ++j) {
        __hip_bfloat16 hb = __float2bfloat16(pv[f][j]);
        Pl[w][hi * 4 + j][f * 16 + lo] = *(ushort*)&hb;
      }
#pragma unroll
    for (int ks = 0; ks < 2; ++ks) {
      bf16x8 pa = *(const bf16x8*)((const char*)&Pl[w][lo][0] + ks * 64 + hi * 16);
#pragma unroll
      for (int df = 0; df < 4; ++df) {
        bf16x8 vfr = *(const bf16x8*)((const char*)&VT[df * 16 + lo][0] + kb * 2 + ks * 64 + hi * 16);
        Oacc[df] = __builtin_amdgcn_mfma_f32_16x16x32_bf16(pa, vfr, Oacc[df], 0, 0, 0);
      }
    }
  }

  float inv[4];
#pragma unroll
  for (int j = 0; j < 4; ++j) inv[j] = 1.f / lrun[j];
#pragma unroll
  for (int df = 0; df < 4; ++df)
#pragma unroll
    for (int j = 0; j < 4; ++j) {
      int qq = q0 + hi * 4 + j;
      if (qq < T) {
        __hip_bfloat16 hb = __float2bfloat16(Oacc[df][j] * inv[j]);
        *(ushort*)((char*)vec + ((size_t)b * TP + 1 + qq) * 128 + (df * 16 + lo) * 2) = *(ushort*)&hb;
      }
    }
}

// =================================================================
// LayerNorm (bf16 residual stream): out = LN(xin [+ resin]) * g + b [* mask]
// =================================================================
template<int C, bool HASRES, bool HASMASK>
__global__ __launch_bounds__(256)
void ln_kernel(const __hip_bfloat16* __restrict__ xin, const __hip_bfloat16* __restrict__ resin,
               const float* __restrict__ g, const float* __restrict__ bb,
               const float* __restrict__ maskf,
               __hip_bfloat16* __restrict__ outb, int T)
{
  constexpr int NU = C / 128;              // uint chunks per lane
  const int row = blockIdx.x * 4 + (threadIdx.x >> 6);
  const int lane = threadIdx.x & 63;
  const int b = row / T, t = row - b * T;
  const size_t prow = ((size_t)b * (T + 2) + 1 + t) * C;
  const uint* xu = (const uint*)(xin + prow);
  const uint* ru = (const uint*)(resin + prow);
  float v[2 * NU];
  float s1 = 0.f, s2 = 0.f;
#pragma unroll
  for (int k = 0; k < NU; ++k) {
    uint ux = xu[lane + 64 * k];
    uint xl = ux << 16, xh = ux & 0xffff0000u;
    float lo = *(float*)&xl, hi = *(float*)&xh;
    if (HASRES) {
      uint ur = ru[lane + 64 * k];
      uint rl2 = ur << 16, rh = ur & 0xffff0000u;
      lo += *(float*)&rl2; hi += *(float*)&rh;
    }
    v[2 * k] = lo; v[2 * k + 1] = hi;
    s1 += lo + hi; s2 += lo * lo + hi * hi;
  }
#pragma unroll
  for (int o = 32; o > 0; o >>= 1) { s1 += __shfl_xor(s1, o); s2 += __shfl_xor(s2, o); }
  float mu = s1 / C;
  float var = s2 / C - mu * mu;
  float rstd = rsqrtf(fmaxf(var, 0.f) + 1e-5f);
  float mk = HASMASK ? maskf[row] : 1.f;
  uint* ou = (uint*)(outb + prow);
#pragma unroll
  for (int k = 0; k < NU; ++k) {
    int c = (lane + 64 * k) * 2;
    float2 gv = *(const float2*)(g + c);
    float2 bv = *(const float2*)(bb + c);
    float lo = ((v[2 * k]     - mu) * rstd * gv.x + bv.x) * mk;
    float hi = ((v[2 * k + 1] - mu) * rstd * gv.y + bv.y) * mk;
    __hip_bfloat16 hl = __float2bfloat16(lo), hh = __float2bfloat16(hi);
    ou[lane + 64 * k] = (uint)(*(ushort*)&hl) | ((uint)(*(ushort*)&hh) << 16);
  }
}

// =================================================================
// Duration predictor FC + exp/clip
// =================================================================
__global__ __launch_bounds__(64)
void dpfc_kernel(const __hip_bfloat16* __restrict__ dp2, const float* __restrict__ fcw,
                 const float* __restrict__ fcb, const float* __restrict__ maskf,
                 float* __restrict__ logdur, float* __restrict__ durpred)
{
  int blk = blockIdx.x; int b = blk / SS, t = blk % SS;
  size_t prow = ((size_t)b * (SS + 2) + 1 + t) * 256;
  int lane = threadIdx.x;
  float a = 0.f;
  for (int c = lane; c < 256; c += 64) a += __bfloat162float(dp2[prow + c]) * fcw[c];
  for (int o = 32; o > 0; o >>= 1) a += __shfl_down(a, o);
  if (lane == 0) {
    float ld = (a + fcb[0]) * maskf[b * SS + t];
    logdur[b * SS + t] = ld;
    durpred[b * SS + t] = fminf(fmaxf(expf(ld) - 1.f, 0.f), 75.f);
  }
}

// =================================================================
// Length regulator
// =================================================================
__global__ __launch_bounds__(512)
void regulator_kernel(const float* __restrict__ dur, float* __restrict__ dmaskf,
                      int* __restrict__ idxbuf, float* __restrict__ out_dmask,
                      float* __restrict__ out_dlen)
{
  int b = blockIdx.x, tid = threadIdx.x;
  __shared__ int cum[256];
  __shared__ int len_s;
  if (tid < 256) cum[tid] = (int)rintf(dur[b * 256 + tid] / 0.0265f);
  __syncthreads();
  if (tid == 0) {
    int acc = 0;
    for (int i = 0; i < 256; i++) { acc += cum[i]; cum[i] = acc; }
    int len = acc < 400 ? acc : 400;
    len_s = len;
    out_dlen[b] = (float)len;
  }
  __syncthreads();
  if (tid < 400) {
    int p = tid;
    int lo = 0, hi = 256;
    while (lo < hi) { int mid = (lo + hi) >> 1; if (cum[mid] <= p) lo = mid + 1; else hi = mid; }
    int idx = lo < 255 ? lo : 255;
    idxbuf[b * 400 + p] = idx;
    float mk = (p < len_s) ? 1.f : 0.f;
    dmaskf[b * 400 + p] = mk;
    out_dmask[b * 400 + p] = mk;
  }
}

__global__ __launch_bounds__(128)
void build_y_kernel(const __hip_bfloat16* __restrict__ encb, const int* __restrict__ idxbuf,
                    const float* __restrict__ dmaskf, const float* __restrict__ pe,
                    __hip_bfloat16* __restrict__ yb)
{
  int blk = blockIdx.x; int b = blk / 400, p = blk % 400;
  float mk = dmaskf[b * 400 + p];
  int idx = idxbuf[b * 400 + p];
  size_t orowp = ((size_t)b * 402 + 1 + p) * 384;
  size_t srow = ((size_t)b * 258 + 1 + idx) * 384;
  for (int c = threadIdx.x; c < 384; c += 128) {
    float v = (mk > 0.f) ? (__bfloat162float(encb[srow + c]) + pe[(size_t)p * 384 + c]) : 40.f;
    yb[orowp + c] = __float2bfloat16(v);
  }
}

// =================================================================
// Orchestration
// =================================================================
extern "C" void kernel_launch(void* const* d_in, const int* in_sizes, int n_in,
                              void* d_out, int out_size, void* d_ws, size_t ws_size,
                              hipStream_t stream)
{
  (void)in_sizes; (void)n_in; (void)out_size; (void)ws_size;
  float* outF = (float*)d_out;

  const int*   inputs  = (const int*)d_in[0];
  const float* dur_tgt = (const float*)d_in[1];
  const float* emb     = (const float*)d_in[2];
  const float* e_qkv_w = (const float*)d_in[3];
  const float* e_qkv_b = (const float*)d_in[4];
  const float* e_o_w   = (const float*)d_in[5];
  const float* e_ln1g  = (const float*)d_in[6];
  const float* e_ln1b  = (const float*)d_in[7];
  const float* e_c1w   = (const float*)d_in[8];
  const float* e_c1b   = (const float*)d_in[9];
  const float* e_c2w   = (const float*)d_in[10];
  const float* e_c2b   = (const float*)d_in[11];
  const float* e_ln2g  = (const float*)d_in[12];
  const float* e_ln2b  = (const float*)d_in[13];
  const float* dc_qkv_w = (const float*)d_in[14];
  const float* dc_qkv_b = (const float*)d_in[15];
  const float* dc_o_w   = (const float*)d_in[16];
  const float* dc_ln1g  = (const float*)d_in[17];
  const float* dc_ln1b  = (const float*)d_in[18];
  const float* dc_c1w   = (const float*)d_in[19];
  const float* dc_c1b   = (const float*)d_in[20];
  const float* dc_c2w   = (const float*)d_in[21];
  const float* dc_c2b   = (const float*)d_in[22];
  const float* dc_ln2g  = (const float*)d_in[23];
  const float* dc_ln2b  = (const float*)d_in[24];
  const float* dp_c1w = (const float*)d_in[25];
  const float* dp_c1b = (const float*)d_in[26];
  const float* dp_ln1g = (const float*)d_in[27];
  const float* dp_ln1b = (const float*)d_in[28];
  const float* dp_c2w = (const float*)d_in[29];
  const float* dp_c2b = (const float*)d_in[30];
  const float* dp_ln2g = (const float*)d_in[31];
  const float* dp_ln2b = (const float*)d_in[32];
  const float* dp_fcw = (const float*)d_in[33];
  const float* dp_fcb = (const float*)d_in[34];
  const float* proj_w = (const float*)d_in[35];
  const float* proj_b = (const float*)d_in[36];

  char* ws = (char*)d_ws;
  size_t off = 0;
  auto alloc = [&](size_t bytes) -> char* {
    char* p = ws + off;
    off += (bytes + 255) & ~(size_t)255;
    return p;
  };

  __hip_bfloat16* qkvwt_e = (__hip_bfloat16*)alloc((size_t)6 * 256 * 384 * 2);
  __hip_bfloat16* qkvwt_d = (__hip_bfloat16*)alloc((size_t)6 * 256 * 384 * 2);
  __hip_bfloat16* owt_e   = (__hip_bfloat16*)alloc((size_t)6 * 384 * 64 * 2);
  __hip_bfloat16* owt_d   = (__hip_bfloat16*)alloc((size_t)6 * 384 * 64 * 2);
  __hip_bfloat16* c1wt_e  = (__hip_bfloat16*)alloc((size_t)6 * 3 * 1536 * 384 * 2);
  __hip_bfloat16* c1wt_d  = (__hip_bfloat16*)alloc((size_t)6 * 3 * 1536 * 384 * 2);
  __hip_bfloat16* c2wt_e  = (__hip_bfloat16*)alloc((size_t)6 * 3 * 384 * 1536 * 2);
  __hip_bfloat16* c2wt_d  = (__hip_bfloat16*)alloc((size_t)6 * 3 * 384 * 1536 * 2);
  __hip_bfloat16* dpc1wt  = (__hip_bfloat16*)alloc((size_t)3 * 256 * 384 * 2);
  __hip_bfloat16* dpc2wt  = (__hip_bfloat16*)alloc((size_t)3 * 256 * 256 * 2);
  __hip_bfloat16* projwt  = (__hip_bfloat16*)alloc((size_t)128 * 384 * 2);
  float* pe_e   = (float*)alloc((size_t)256 * 384 * 4);
  float* pe_d   = (float*)alloc((size_t)400 * 384 * 4);
  float* maskf_e = (float*)alloc((size_t)32 * 256 * 4);
  float* maskf_d = (float*)alloc((size_t)32 * 400 * 4);
  int*   idxbuf  = (int*)alloc((size_t)32 * 400 * 4);
  __hip_bfloat16* h_enc_bf = (__hip_bfloat16*)alloc((size_t)32 * 258 * 384 * 2);
  __hip_bfloat16* h_dec_bf = (__hip_bfloat16*)alloc((size_t)32 * 402 * 384 * 2);
  __hip_bfloat16* qkvbuf = (__hip_bfloat16*)alloc((size_t)32 * 402 * 192 * 2);
  __hip_bfloat16* vecbuf = (__hip_bfloat16*)alloc((size_t)32 * 402 * 64 * 2);
  __hip_bfloat16* tmp384 = (__hip_bfloat16*)alloc((size_t)32 * 402 * 384 * 2);
  __hip_bfloat16* cbuf   = (__hip_bfloat16*)alloc((size_t)32 * 402 * 1536 * 2);
  __hip_bfloat16* dp1b   = (__hip_bfloat16*)alloc((size_t)32 * 258 * 256 * 2);
  __hip_bfloat16* dp2b   = (__hip_bfloat16*)alloc((size_t)32 * 258 * 256 * 2);

  // ---- weight conversion ----
  transpose_cvt<<<dim3(12, 8, 6), dim3(32, 8), 0, stream>>>(e_qkv_w, qkvwt_e, 384, 192, 256);
  transpose_cvt<<<dim3(12, 8, 6), dim3(32, 8), 0, stream>>>(dc_qkv_w, qkvwt_d, 384, 192, 256);
  transpose_cvt<<<dim3(2, 12, 6), dim3(32, 8), 0, stream>>>(e_o_w, owt_e, 64, 384, 384);
  transpose_cvt<<<dim3(2, 12, 6), dim3(32, 8), 0, stream>>>(dc_o_w, owt_d, 64, 384, 384);
  transpose_cvt<<<dim3(12, 4, 1), dim3(32, 8), 0, stream>>>(proj_w, projwt, 384, 80, 128);
  {
    long long tot = 6LL * 3 * 1536 * 384;
    int blocks = (int)((tot + 255) / 256);
    conv_cvt<<<blocks, 256, 0, stream>>>(e_c1w, c1wt_e, 1536, 384, tot);
    conv_cvt<<<blocks, 256, 0, stream>>>(dc_c1w, c1wt_d, 1536, 384, tot);
    conv_cvt<<<blocks, 256, 0, stream>>>(e_c2w, c2wt_e, 384, 1536, tot);
    conv_cvt<<<blocks, 256, 0, stream>>>(dc_c2w, c2wt_d, 384, 1536, tot);
  }
  { long long tot = 3LL * 256 * 384; conv_cvt<<<(int)((tot + 255) / 256), 256, 0, stream>>>(dp_c1w, dpc1wt, 256, 384, tot); }
  { long long tot = 3LL * 256 * 256; conv_cvt<<<(int)((tot + 255) / 256), 256, 0, stream>>>(dp_c2w, dpc2wt, 256, 256, tot); }

  pe_kernel<<<(256 * 192 + 255) / 256, 256, 0, stream>>>(pe_e, 256);
  pe_kernel<<<(400 * 192 + 255) / 256, 256, 0, stream>>>(pe_d, 400);

  embed_kernel<<<32 * 256, 128, 0, stream>>>(inputs, emb, pe_e, maskf_e, h_enc_bf);
  zero_guards<<<64, 256, 0, stream>>>(h_enc_bf, 256, 384);
  zero_guards<<<64, 256, 0, stream>>>(cbuf, 256, 1536);

  // ---- encoder ----
  for (int l = 0; l < 6; ++l) {
    gemm_tn<64, 128, 3, 1, 384, false, false, true><<<dim3(128, 2), 256, 0, stream>>>(
        h_enc_bf, qkvwt_e + (size_t)l * 256 * 384, e_qkv_b + l * 192, qkvbuf,
        192, 192, 256, 256);
    fattn_kernel<<<dim3(4, 32), 256, 0, stream>>>(qkvbuf, maskf_e, vecbuf, 256, 4);
    gemm_tn<64, 128, 3, 1, 64, false, false, true><<<dim3(128, 3), 256, 0, stream>>>(
        vecbuf, owt_e + (size_t)l * 384 * 64, nullptr, tmp384,
        384, 384, 256, 384);
    ln_kernel<384, true, true><<<2048, 256, 0, stream>>>(
        tmp384, h_enc_bf, e_ln1g + l * 384, e_ln1b + l * 384, maskf_e, h_enc_bf, 256);
    gemm_tn<128, 128, 2, 3, 384, true, false, true><<<dim3(64, 12), 256, 0, stream>>>(
        h_enc_bf, c1wt_e + (size_t)l * 3 * 1536 * 384, e_c1b + l * 1536, cbuf,
        1536, 1536, 256, 1536);
    gemm_tn<64, 128, 3, 3, 1536, false, false, true><<<dim3(128, 3), 256, 0, stream>>>(
        cbuf, c2wt_e + (size_t)l * 3 * 384 * 1536, e_c2b + l * 384, tmp384,
        384, 384, 256, 384);
    ln_kernel<384, true, true><<<2048, 256, 0, stream>>>(
        tmp384, h_enc_bf, e_ln2g + l * 384, e_ln2b + l * 384, maskf_e, h_enc_bf, 256);
  }

  // ---- duration predictor ----
  zero_guards<<<64, 256, 0, stream>>>(dp1b, 256, 256);
  gemm_tn<64, 128, 3, 3, 384, true, false, true><<<dim3(128, 2), 256, 0, stream>>>(
      h_enc_bf, dpc1wt, dp_c1b, dp1b, 256, 256, 256, 256);
  ln_kernel<256, false, false><<<2048, 256, 0, stream>>>(
      dp1b, nullptr, dp_ln1g, dp_ln1b, nullptr, dp1b, 256);
  gemm_tn<64, 128, 3, 3, 256, true, false, true><<<dim3(128, 2), 256, 0, stream>>>(
      dp1b, dpc2wt, dp_c2b, dp2b, 256, 256, 256, 256);
  ln_kernel<256, false, false><<<2048, 256, 0, stream>>>(
      dp2b, nullptr, dp_ln2g, dp_ln2b, nullptr, dp2b, 256);
  dpfc_kernel<<<32 * 256, 64, 0, stream>>>(
      dp2b, dp_fcw, dp_fcb, maskf_e, outF + OFF_LOGDUR, outF + OFF_DUR);

  // ---- length regulator ----
  regulator_kernel<<<32, 512, 0, stream>>>(dur_tgt, maskf_d, idxbuf,
                                           outF + OFF_DMASK, outF + OFF_DLEN);
  zero_guards<<<64, 256, 0, stream>>>(h_dec_bf, 400, 384);
  zero_guards<<<64, 256, 0, stream>>>(cbuf, 400, 1536);
  build_y_kernel<<<32 * 400, 128, 0, stream>>>(h_enc_bf, idxbuf, maskf_d, pe_d, h_dec_bf);

  // ---- decoder ----
  for (int l = 0; l < 6; ++l) {
    gemm_tn<64, 128, 3, 1, 384, false, false, true><<<dim3(200, 2), 256, 0, stream>>>(
        h_dec_bf, qkvwt_d + (size_t)l * 256 * 384, dc_qkv_b + l * 192, qkvbuf,
        192, 192, 400, 256);
    fattn_kernel<<<dim3(7, 32), 256, 0, stream>>>(qkvbuf, maskf_d, vecbuf, 400, 7);
    gemm_tn<64, 128, 3, 1, 64, false, false, true><<<dim3(200, 3), 256, 0, stream>>>(
        vecbuf, owt_d + (size_t)l * 384 * 64, nullptr, tmp384,
        384, 384, 400, 384);
    ln_kernel<384, true, true><<<3200, 256, 0, stream>>>(
        tmp384, h_dec_bf, dc_ln1g + l * 384, dc_ln1b + l * 384, maskf_d, h_dec_bf, 400);
    gemm_tn<128, 128, 2, 3, 384, true, false, true><<<dim3(100, 12), 256, 0, stream>>>(
        h_dec_bf, c1wt_d + (size_t)l * 3 * 1536 * 384, dc_c1b + l * 1536, cbuf,
        1536, 1536, 400, 1536);
    gemm_tn<64, 128, 3, 3, 1536, false, false, true><<<dim3(200, 3), 256, 0, stream>>>(
        cbuf, c2wt_d + (size_t)l * 3 * 384 * 1536, dc_c2b + l * 384, tmp384,
        384, 384, 400, 384);
    ln_kernel<384, true, true><<<3200, 256, 0, stream>>>(
        tmp384, h_dec_bf, dc_ln2g + l * 384, dc_ln2b + l * 384, maskf_d, h_dec_bf, 400);
  }

  // ---- mel projection ----
  gemm_tn<64, 128, 3, 1, 384, false, true, false><<<dim3(200, 1), 256, 0, stream>>>(
      h_dec_bf, projwt, proj_b, outF + OFF_MEL, 80, 80, 400, 128);
}

// Round 14
// 2120.748 us; speedup vs baseline: 1.0536x; 1.0136x over previous
//
#include <hip/hip_runtime.h>
#include <hip/hip_bf16.h>
#include <stdint.h>

typedef __attribute__((ext_vector_type(8))) short bf16x8;   // 8 bf16 in 4 VGPRs (MFMA A/B operand)
typedef __attribute__((ext_vector_type(4))) float f32x4;    // MFMA C/D operand
typedef __attribute__((ext_vector_type(4))) unsigned int u32x4; // native 16B vec

// ---------------- model constants ----------------
static constexpr int BB = 32, SS = 256, DD = 384;
static constexpr int TDEC = 400;
static constexpr int NMELC = 80;

// d_out offsets (floats), return order: mel, dec_mask, dur_pred, log_dur_pred, dec_lens
static constexpr size_t OFF_MEL    = 0;
static constexpr size_t OFF_DMASK  = (size_t)BB * TDEC * NMELC;   // 1,024,000
static constexpr size_t OFF_DUR    = OFF_DMASK + (size_t)BB * TDEC;
static constexpr size_t OFF_LOGDUR = OFF_DUR + (size_t)BB * SS;
static constexpr size_t OFF_DLEN   = OFF_LOGDUR + (size_t)BB * SS;

// async global->LDS, 16B per lane (dest must be wave-uniform base + lane*16)
__device__ __forceinline__ void gld16(void* lds, const void* g) {
  __builtin_amdgcn_global_load_lds(
      (const __attribute__((address_space(1))) void*)g,
      (__attribute__((address_space(3))) void*)lds, 16, 0, 0);
}

// =================================================================
// Weight conversion
// =================================================================

// src: [L][R][C] f32  ->  dst: [L][Cpad][R] bf16 (transposed; zeros for c >= C)
__global__ __launch_bounds__(256)
void transpose_cvt(const float* __restrict__ src, __hip_bfloat16* __restrict__ dst,
                   int R, int C, int Cpad)
{
  __shared__ float tile[32][33];
  int l = blockIdx.z;
  src += (size_t)l * R * C;
  dst += (size_t)l * Cpad * R;
  int r0 = blockIdx.x * 32, c0 = blockIdx.y * 32;
  int tx = threadIdx.x, ty = threadIdx.y;
  for (int i = ty; i < 32; i += 8) {
    int c = c0 + tx;
    tile[i][tx] = (c < C) ? src[(size_t)(r0 + i) * C + c] : 0.f;
  }
  __syncthreads();
  for (int i = ty; i < 32; i += 8) {
    dst[(size_t)(c0 + i) * R + (r0 + tx)] = __float2bfloat16(tile[tx][i]);
  }
}

// src: [L][Cout][Cin][3] f32  ->  dst: [L][3][Cout][Cin] bf16
__global__ __launch_bounds__(256)
void conv_cvt(const float* __restrict__ src, __hip_bfloat16* __restrict__ dst,
              int Cout, int Cin, long long total)
{
  long long i = (long long)blockIdx.x * 256 + threadIdx.x;
  if (i >= total) return;
  int ci = (int)(i % Cin);
  long long t1 = i / Cin;
  int co = (int)(t1 % Cout);
  long long t2 = t1 / Cout;
  int tap = (int)(t2 % 3);
  int l = (int)(t2 / 3);
  dst[i] = __float2bfloat16(src[(((size_t)l * Cout + co) * Cin + ci) * 3 + tap]);
}

// =================================================================
// Positional embedding / embedding
// =================================================================

__global__ __launch_bounds__(256)
void pe_kernel(float* __restrict__ pe, int T)
{
  int i = blockIdx.x * 256 + threadIdx.x;
  if (i >= T * 192) return;
  int t = i / 192, j = i % 192;
  float inv = expf(-(float)j * (9.210340371976184f / 192.f));
  float s = (float)t * inv;
  pe[(size_t)t * 384 + j]       = sinf(s);
  pe[(size_t)t * 384 + 192 + j] = cosf(s);
}

__global__ __launch_bounds__(128)
void embed_kernel(const int* __restrict__ inputs, const float* __restrict__ emb,
                  const float* __restrict__ pe, float* __restrict__ maskf,
                  __hip_bfloat16* __restrict__ xb)
{
  int blk = blockIdx.x; int b = blk / SS, t = blk % SS;
  int tok = inputs[b * SS + t];
  float mk = (tok != 0) ? 1.f : 0.f;
  if (threadIdx.x == 0) maskf[b * SS + t] = mk;
  size_t prow = ((size_t)b * (SS + 2) + 1 + t) * 384;
  for (int c = threadIdx.x; c < 384; c += 128) {
    float v = emb[(size_t)tok * 384 + c] + pe[(size_t)t * 384 + c] * mk;
    xb[prow + c] = __float2bfloat16(v);
  }
}

__global__ __launch_bounds__(256)
void zero_guards(__hip_bfloat16* __restrict__ buf, int T, int C)
{
  int b = blockIdx.x >> 1, which = blockIdx.x & 1;
  size_t row = ((size_t)b * (T + 2) + (which ? (T + 1) : 0)) * (size_t)C;
  for (int c = threadIdx.x; c < C; c += 256) buf[row + c] = __float2bfloat16(0.f);
}

// =================================================================
// GEMM: C[M,N] = act( sum_tap A[m + tap - NTAPS/2, :] @ B_tap + bias )
// A: bf16, padded rows (B, T+2, K), guard rows zero. B: bf16 [NTAPS][Npad][K].
// TM x TN tile, 4 waves 2x2; wave (TM/2)x(TN/2); 16x16x32 fragments.
// Depth-DEPTH pipeline over SYNC INTERVALS; counted vmcnt; R8 tail.
// DUAL=true: BK=64 per interval (two 32-K chunks per buffer, ONE barrier)
//   -> halves the per-step sync overhead (144 -> 72 intervals for c2).
// STEP ORDER: ks-outer, TAP-INNER (A fetched ~once; R12-verified).
// LDS chunk swizzle (conflicts~0).
// Block->tile map: per-XCD contiguous logical chunk (n-fast, bijective m204).
// Epilogue: bf16 C staged in LDS -> coalesced 16B row stores.
// =================================================================
template<int TM, int TN, int DEPTH, int NTAPS, int KV, bool DUAL,
         bool RELU, bool OUTF32, bool CPAD>
__global__ __launch_bounds__(256)
void gemm_tn(const __hip_bfloat16* __restrict__ A,
             const __hip_bfloat16* __restrict__ Bw,
             const float* __restrict__ bias,
             void* __restrict__ Cout_,
             int N, int ldc, int T, int Npad)
{
  constexpr int KS = KV >> 5;          // 32-K steps per tap
  constexpr int NSTEP = NTAPS * KS;    // total 32-K steps (even for all our shapes)
  constexpr int NI = DUAL ? NSTEP / 2 : NSTEP;   // sync intervals
  constexpr int DEP = (DEPTH < NI) ? DEPTH : NI;
  constexpr int NBUF = DEP + 1;
  constexpr int ABYTES = TM * 64;      // A bytes per 32-K chunk
  constexpr int BBYTES = TN * 64;      // B bytes per 32-K chunk
  constexpr int HALF = ABYTES + BBYTES;
  constexpr int BUFB = DUAL ? 2 * HALF : HALF;
  constexpr int MI_N = TM / 32;        // m-fragments per wave
  constexpr int NI_N = TN / 32;        // n-fragments per wave
  constexpr int OPS1 = (TM == 128 ? 2 : 1) + (TN == 128 ? 2 : 1);  // gld16 per chunk
  constexpr int OPS = DUAL ? 2 * OPS1 : OPS1;                       // gld16 per STAGE
  __shared__ __align__(16) char SH[NBUF * BUFB];

  const int tid = threadIdx.x;
  const int lane = tid & 63;
  const int w = tid >> 6;
  const int wm = w >> 1, wn = w & 1;

  // ---- per-XCD contiguous chunk mapping (bijective, m204; n-fast) ----
  const int GN = gridDim.y;
  const int NB = gridDim.x * GN;
  const int f = blockIdx.y * gridDim.x + blockIdx.x;
  const int qq = NB >> 3, rr8 = NB & 7;
  const int xcd = f & 7, pos = f >> 3;
  const int st = (xcd < rr8) ? xcd * (qq + 1) : rr8 * (qq + 1) + (xcd - rr8) * qq;
  const int L = st + pos;
  const int m0 = (L / GN) * TM;
  const int n0 = (L % GN) * TN;

  const int ar = tid >> 2;
  const int q = tid & 3;
  const int qsw = q ^ ((ar >> 1) & 3);         // pre-swizzled source chunk
  const int g0 = m0 + ar, g1 = g0 + 64;
  const char* sA0 = (const char*)A + (((size_t)(g0 + 2 * (g0 / T) + 1 - NTAPS / 2)) * KV + qsw * 8) * 2;
  const char* sA1 = (const char*)A + (((size_t)(g1 + 2 * (g1 / T) + 1 - NTAPS / 2)) * KV + qsw * 8) * 2;
  const char* sB0 = (const char*)Bw + ((size_t)(n0 + ar) * KV + qsw * 8) * 2;
  const char* sB1 = (const char*)Bw + ((size_t)(n0 + ar + 64) * KV + qsw * 8) * 2;

  const int woff = ar * 64 + q * 16;   // LDS byte offset (linear, tid*16)
  int tap_s = 0;

  const size_t AROW = (size_t)KV * 2;             // one A row (== tap shift)
  const size_t BPAN = (size_t)Npad * KV * 2;      // one B tap panel

  auto ADV = [&]() {
    // tap-inner: next tap = +1 A row, +1 B panel; wrap -> next 32-K chunk
    sA0 += AROW; sA1 += AROW; sB0 += BPAN; sB1 += BPAN;
    if (++tap_s == NTAPS) {
      tap_s = 0;
      sA0 -= NTAPS * AROW - 64; sA1 -= NTAPS * AROW - 64;
      sB0 -= NTAPS * BPAN - 64; sB1 -= NTAPS * BPAN - 64;
    }
  };
  auto STAGE1 = [&](char* base) {
    gld16(base + woff, sA0);
    if (TM == 128) gld16(base + 4096 + woff, sA1);
    gld16(base + ABYTES + woff, sB0);
    if (TN == 128) gld16(base + ABYTES + 4096 + woff, sB1);
    ADV();
  };
  auto STAGE = [&](int buf) {
    char* base = SH + buf * BUFB;
    STAGE1(base);
    if (DUAL) STAGE1(base + HALF);
  };

  f32x4 zero = {0.f, 0.f, 0.f, 0.f};
  f32x4 acc[MI_N][NI_N];
#pragma unroll
  for (int i = 0; i < MI_N; i++)
#pragma unroll
    for (int j = 0; j < NI_N; j++) acc[i][j] = zero;

  const int rl = lane & 15;
  const int hi4 = lane >> 4;
  const int kb2 = (hi4 ^ ((rl >> 1) & 3)) * 16;   // swizzled read slot (bytes)

  auto COMPUTE = [&](const char* base) {
    const char* Ab = base;
    const char* Bb = base + ABYTES;
    bf16x8 af[MI_N], bfr[NI_N];
#pragma unroll
    for (int mi = 0; mi < MI_N; mi++)
      af[mi] = *(const bf16x8*)(Ab + (wm * (TM / 2) + mi * 16 + rl) * 64 + kb2);
#pragma unroll
    for (int ni = 0; ni < NI_N; ni++)
      bfr[ni] = *(const bf16x8*)(Bb + (wn * (TN / 2) + ni * 16 + rl) * 64 + kb2);
#pragma unroll
    for (int mi = 0; mi < MI_N; mi++)
#pragma unroll
      for (int ni = 0; ni < NI_N; ni++)
        acc[mi][ni] = __builtin_amdgcn_mfma_f32_16x16x32_bf16(af[mi], bfr[ni], acc[mi][ni], 0, 0, 0);
  };

  // ---- prologue: fill DEP buffers ----
#pragma unroll
  for (int i = 0; i < DEP; ++i) STAGE(i);
  if constexpr (DEP == NI) {
    asm volatile("s_waitcnt vmcnt(0)" ::: "memory");
  } else {
    asm volatile("s_waitcnt vmcnt(%0)" :: "i"((DEP - 1) * OPS) : "memory");
  }
  __builtin_amdgcn_s_barrier();
  __builtin_amdgcn_sched_barrier(0);

  int cur = 0;
  for (int i = 0; i < NI; ++i) {
    if (i + DEP < NI) {
      int nb = cur + DEP; if (nb >= NBUF) nb -= NBUF;
      STAGE(nb);
    }
    const char* base = SH + cur * BUFB;
    COMPUTE(base);
    if (DUAL) COMPUTE(base + HALF);
    if (i + 1 < NI) {
      if (i + DEP < NI) {
        asm volatile("s_waitcnt vmcnt(%0)" :: "i"((DEP - 1) * OPS) : "memory");
      } else {
        asm volatile("s_waitcnt vmcnt(0)" ::: "memory");  // tail drain
      }
      __builtin_amdgcn_s_barrier();
      __builtin_amdgcn_sched_barrier(0);
    }
    cur = cur + 1; if (cur >= NBUF) cur -= NBUF;
  }

  // epilogue. C/D layout col=lane&15, row=(lane>>4)*4+j  [m89-verified]
  const int rj = hi4 * 4;
  if (!OUTF32) {
    // stage bf16 C-tile in LDS, then coalesced 16B row stores
    __syncthreads();                 // all waves done with K-loop LDS
    ushort* S = (ushort*)SH;         // [TM][TN] bf16
#pragma unroll
    for (int mi = 0; mi < MI_N; mi++) {
#pragma unroll
      for (int ni = 0; ni < NI_N; ni++) {
        int lc = wn * (TN / 2) + ni * 16 + rl;
        float bv = bias ? bias[n0 + lc] : 0.f;
#pragma unroll
        for (int j = 0; j < 4; j++) {
          float v = acc[mi][ni][j] + bv;
          if (RELU) v = fmaxf(v, 0.f);
          __hip_bfloat16 hb = __float2bfloat16(v);
          S[(wm * (TM / 2) + mi * 16 + rj + j) * TN + lc] = *(ushort*)&hb;
        }
      }
    }
    __syncthreads();
    constexpr int TPR = TN / 8;       // threads per row (16B each)
    constexpr int RPP = 256 / TPR;    // rows per pass
    const int tr = tid / TPR;
    const int tc = (tid % TPR) * 8;
#pragma unroll
    for (int pass = 0; pass < TM / RPP; ++pass) {
      int lr = pass * RPP + tr;
      int gcol = n0 + tc;
      if (gcol < N) {
        int r = m0 + lr;
        size_t orow = CPAD ? ((size_t)r + 2 * (r / T) + 1) : (size_t)r;
        *(u32x4*)((__hip_bfloat16*)Cout_ + orow * ldc + gcol) = *(const u32x4*)&S[lr * TN + tc];
      }
    }
  } else {
#pragma unroll
    for (int mi = 0; mi < MI_N; mi++) {
#pragma unroll
      for (int ni = 0; ni < NI_N; ni++) {
        int col = n0 + wn * (TN / 2) + ni * 16 + rl;
        if (col < N) {
          float bv = bias ? bias[col] : 0.f;
#pragma unroll
          for (int j = 0; j < 4; j++) {
            int r = m0 + wm * (TM / 2) + mi * 16 + rj + j;
            float v = acc[mi][ni][j] + bv;
            if (RELU) v = fmaxf(v, 0.f);
            size_t orow = CPAD ? ((size_t)r + 2 * (r / T) + 1) : (size_t)r;
            ((float*)Cout_)[orow * ldc + col] = v;
          }
        }
      }
    }
  }
}

// =================================================================
// Fused flash attention: 1 head, d=64. Block = (b, 64-query tile), 4 waves.
// =================================================================
__global__ __launch_bounds__(256)
void fattn_kernel(const __hip_bfloat16* __restrict__ qkv, const float* __restrict__ maskf,
                  __hip_bfloat16* __restrict__ vec, int T, int NT)
{
  __shared__ __align__(16) ushort VT[64][456];   // V^T: [d][key]
  __shared__ __align__(16) ushort Pl[4][16][72]; // per-wave P tile
  __shared__ float MS[448];                      // 0=ok, -1e9=masked, -1e38=pad

  const int tid = threadIdx.x;
  const int b = blockIdx.y;
  const int TP = T + 2;
  const int KTOT = NT * 64;
  const char* bptr = (const char*)qkv + ((size_t)b * TP + 1) * 384;

  for (int k = tid; k < KTOT; k += 256)
    MS[k] = (k < T) ? ((maskf[b * T + k] > 0.f) ? 0.f : -1e9f) : -1e38f;
  for (int i = tid; i < KTOT * 8; i += 256) {
    int k = i >> 3, seg = i & 7;
    int kr = (k < T) ? k : T - 1;
    uint4 u = *(const uint4*)(bptr + (size_t)kr * 384 + 256 + seg * 16);
    const ushort* e = (const ushort*)&u;
#pragma unroll
    for (int j = 0; j < 8; ++j) VT[seg * 8 + j][k] = e[j];
  }
  __syncthreads();

  const int w = tid >> 6, lane = tid & 63;
  const int lo = lane & 15, hi = lane >> 4;
  const int q0 = blockIdx.x * 64 + w * 16;
  const int qc = min(q0 + lo, T - 1);

  bf16x8 afr[2];
#pragma unroll
  for (int ks = 0; ks < 2; ++ks)
    afr[ks] = *(const bf16x8*)(bptr + (size_t)qc * 384 + ks * 64 + hi * 16);

  f32x4 Oacc[4];
  f32x4 z = {0.f, 0.f, 0.f, 0.f};
#pragma unroll
  for (int df = 0; df < 4; ++df) Oacc[df] = z;
  float mrun[4], lrun[4];
#pragma unroll
  for (int j = 0; j < 4; ++j) { mrun[j] = -3e38f; lrun[j] = 0.f; }

  for (int kt = 0; kt < NT; ++kt) {
    const int kb = kt * 64;
    f32x4 S[4];
#pragma unroll
    for (int f = 0; f < 4; ++f) S[f] = z;
#pragma unroll
    for (int ks = 0; ks < 2; ++ks) {
#pragma unroll
      for (int f = 0; f < 4; ++f) {
        int krc = min(kb + f * 16 + lo, T - 1);
        bf16x8 bfr = *(const bf16x8*)(bptr + (size_t)krc * 384 + 128 + ks * 64 + hi * 16);
        S[f] = __builtin_amdgcn_mfma_f32_16x16x32_bf16(afr[ks], bfr, S[f], 0, 0, 0);
      }
    }
    float sv[4][4];
#pragma unroll
    for (int f = 0; f < 4; ++f) {
      float msel = MS[kb + f * 16 + lo];
#pragma unroll
      for (int j = 0; j < 4; ++j) {
        float x = S[f][j] * 0.125f;
        sv[f][j] = (msel == 0.f) ? x : msel;
      }
    }
    float scale[4];
#pragma unroll
    for (int j = 0; j < 4; ++j) {
      float m4 = fmaxf(fmaxf(sv[0][j], sv[1][j]), fmaxf(sv[2][j], sv[3][j]));
#pragma unroll
      for (int msk = 1; msk < 16; msk <<= 1) m4 = fmaxf(m4, __shfl_xor(m4, msk));
      float mnew = fmaxf(mrun[j], m4);
      scale[j] = __expf(mrun[j] - mnew);
      mrun[j] = mnew;
    }
    float pv[4][4], ps[4] = {0.f, 0.f, 0.f, 0.f};
#pragma unroll
    for (int f = 0; f < 4; ++f)
#pragma unroll
      for (int j = 0; j < 4; ++j) {
        float p = __expf(sv[f][j] - mrun[j]);
        pv[f][j] = p; ps[j] += p;
      }
#pragma unroll
    for (int j = 0; j < 4; ++j) {
#pragma unroll
      for (int msk = 1; msk < 16; msk <<= 1) ps[j] += __shfl_xor(ps[j], msk);
      lrun[j] = lrun[j] * scale[j] + ps[j];
#pragma unroll
      for (int df = 0; df < 4; ++df) Oacc[df][j] *= scale[j];
    }
#pragma unroll
    for (int f = 0; f < 4; ++f)
#pragma unroll
      for (int j = 0; j < 4; ++j) {
        __hip_bfloat16 hb = __float2bfloat16(pv[f][j]);
        Pl[w][hi * 4 + j][f * 16 + lo] = *(ushort*)&hb;
      }
#pragma unroll
    for (int ks = 0; ks < 2; ++ks) {
      bf16x8 pa = *(const bf16x8*)((const char*)&Pl[w][lo][0] + ks * 64 + hi * 16);
#pragma unroll
      for (int df = 0; df < 4; ++df) {
        bf16x8 vfr = *(const bf16x8*)((const char*)&VT[df * 16 + lo][0] + kb * 2 + ks * 64 + hi * 16);
        Oacc[df] = __builtin_amdgcn_mfma_f32_16x16x32_bf16(pa, vfr, Oacc[df], 0, 0, 0);
      }
    }
  }

  float inv[4];
#pragma unroll
  for (int j = 0; j < 4; ++j) inv[j] = 1.f / lrun[j];
#pragma unroll
  for (int df = 0; df < 4; ++df)
#pragma unroll
    for (int j = 0; j < 4; ++j) {
      int qq = q0 + hi * 4 + j;
      if (qq < T) {
        __hip_bfloat16 hb = __float2bfloat16(Oacc[df][j] * inv[j]);
        *(ushort*)((char*)vec + ((size_t)b * TP + 1 + qq) * 128 + (df * 16 + lo) * 2) = *(ushort*)&hb;
      }
    }
}

// =================================================================
// LayerNorm (bf16 residual stream): out = LN(xin [+ resin]) * g + b [* mask]
// =================================================================
template<int C, bool HASRES, bool HASMASK>
__global__ __launch_bounds__(256)
void ln_kernel(const __hip_bfloat16* __restrict__ xin, const __hip_bfloat16* __restrict__ resin,
               const float* __restrict__ g, const float* __restrict__ bb,
               const float* __restrict__ maskf,
               __hip_bfloat16* __restrict__ outb, int T)
{
  constexpr int NU = C / 128;              // uint chunks per lane
  const int row = blockIdx.x * 4 + (threadIdx.x >> 6);
  const int lane = threadIdx.x & 63;
  const int b = row / T, t = row - b * T;
  const size_t prow = ((size_t)b * (T + 2) + 1 + t) * C;
  const uint* xu = (const uint*)(xin + prow);
  const uint* ru = (const uint*)(resin + prow);
  float v[2 * NU];
  float s1 = 0.f, s2 = 0.f;
#pragma unroll
  for (int k = 0; k < NU; ++k) {
    uint ux = xu[lane + 64 * k];
    uint xl = ux << 16, xh = ux & 0xffff0000u;
    float lo = *(float*)&xl, hi = *(float*)&xh;
    if (HASRES) {
      uint ur = ru[lane + 64 * k];
      uint rl2 = ur << 16, rh = ur & 0xffff0000u;
      lo += *(float*)&rl2; hi += *(float*)&rh;
    }
    v[2 * k] = lo; v[2 * k + 1] = hi;
    s1 += lo + hi; s2 += lo * lo + hi * hi;
  }
#pragma unroll
  for (int o = 32; o > 0; o >>= 1) { s1 += __shfl_xor(s1, o); s2 += __shfl_xor(s2, o); }
  float mu = s1 / C;
  float var = s2 / C - mu * mu;
  float rstd = rsqrtf(fmaxf(var, 0.f) + 1e-5f);
  float mk = HASMASK ? maskf[row] : 1.f;
  uint* ou = (uint*)(outb + prow);
#pragma unroll
  for (int k = 0; k < NU; ++k) {
    int c = (lane + 64 * k) * 2;
    float2 gv = *(const float2*)(g + c);
    float2 bv = *(const float2*)(bb + c);
    float lo = ((v[2 * k]     - mu) * rstd * gv.x + bv.x) * mk;
    float hi = ((v[2 * k + 1] - mu) * rstd * gv.y + bv.y) * mk;
    __hip_bfloat16 hl = __float2bfloat16(lo), hh = __float2bfloat16(hi);
    ou[lane + 64 * k] = (uint)(*(ushort*)&hl) | ((uint)(*(ushort*)&hh) << 16);
  }
}

// =================================================================
// Duration predictor FC + exp/clip
// =================================================================
__global__ __launch_bounds__(64)
void dpfc_kernel(const __hip_bfloat16* __restrict__ dp2, const float* __restrict__ fcw,
                 const float* __restrict__ fcb, const float* __restrict__ maskf,
                 float* __restrict__ logdur, float* __restrict__ durpred)
{
  int blk = blockIdx.x; int b = blk / SS, t = blk % SS;
  size_t prow = ((size_t)b * (SS + 2) + 1 + t) * 256;
  int lane = threadIdx.x;
  float a = 0.f;
  for (int c = lane; c < 256; c += 64) a += __bfloat162float(dp2[prow + c]) * fcw[c];
  for (int o = 32; o > 0; o >>= 1) a += __shfl_down(a, o);
  if (lane == 0) {
    float ld = (a + fcb[0]) * maskf[b * SS + t];
    logdur[b * SS + t] = ld;
    durpred[b * SS + t] = fminf(fmaxf(expf(ld) - 1.f, 0.f), 75.f);
  }
}

// =================================================================
// Length regulator
// =================================================================
__global__ __launch_bounds__(512)
void regulator_kernel(const float* __restrict__ dur, float* __restrict__ dmaskf,
                      int* __restrict__ idxbuf, float* __restrict__ out_dmask,
                      float* __restrict__ out_dlen)
{
  int b = blockIdx.x, tid = threadIdx.x;
  __shared__ int cum[256];
  __shared__ int len_s;
  if (tid < 256) cum[tid] = (int)rintf(dur[b * 256 + tid] / 0.0265f);
  __syncthreads();
  if (tid == 0) {
    int acc = 0;
    for (int i = 0; i < 256; i++) { acc += cum[i]; cum[i] = acc; }
    int len = acc < 400 ? acc : 400;
    len_s = len;
    out_dlen[b] = (float)len;
  }
  __syncthreads();
  if (tid < 400) {
    int p = tid;
    int lo = 0, hi = 256;
    while (lo < hi) { int mid = (lo + hi) >> 1; if (cum[mid] <= p) lo = mid + 1; else hi = mid; }
    int idx = lo < 255 ? lo : 255;
    idxbuf[b * 400 + p] = idx;
    float mk = (p < len_s) ? 1.f : 0.f;
    dmaskf[b * 400 + p] = mk;
    out_dmask[b * 400 + p] = mk;
  }
}

__global__ __launch_bounds__(128)
void build_y_kernel(const __hip_bfloat16* __restrict__ encb, const int* __restrict__ idxbuf,
                    const float* __restrict__ dmaskf, const float* __restrict__ pe,
                    __hip_bfloat16* __restrict__ yb)
{
  int blk = blockIdx.x; int b = blk / 400, p = blk % 400;
  float mk = dmaskf[b * 400 + p];
  int idx = idxbuf[b * 400 + p];
  size_t orowp = ((size_t)b * 402 + 1 + p) * 384;
  size_t srow = ((size_t)b * 258 + 1 + idx) * 384;
  for (int c = threadIdx.x; c < 384; c += 128) {
    float v = (mk > 0.f) ? (__bfloat162float(encb[srow + c]) + pe[(size_t)p * 384 + c]) : 40.f;
    yb[orowp + c] = __float2bfloat16(v);
  }
}

// =================================================================
// Orchestration
// =================================================================
extern "C" void kernel_launch(void* const* d_in, const int* in_sizes, int n_in,
                              void* d_out, int out_size, void* d_ws, size_t ws_size,
                              hipStream_t stream)
{
  (void)in_sizes; (void)n_in; (void)out_size; (void)ws_size;
  float* outF = (float*)d_out;

  const int*   inputs  = (const int*)d_in[0];
  const float* dur_tgt = (const float*)d_in[1];
  const float* emb     = (const float*)d_in[2];
  const float* e_qkv_w = (const float*)d_in[3];
  const float* e_qkv_b = (const float*)d_in[4];
  const float* e_o_w   = (const float*)d_in[5];
  const float* e_ln1g  = (const float*)d_in[6];
  const float* e_ln1b  = (const float*)d_in[7];
  const float* e_c1w   = (const float*)d_in[8];
  const float* e_c1b   = (const float*)d_in[9];
  const float* e_c2w   = (const float*)d_in[10];
  const float* e_c2b   = (const float*)d_in[11];
  const float* e_ln2g  = (const float*)d_in[12];
  const float* e_ln2b  = (const float*)d_in[13];
  const float* dc_qkv_w = (const float*)d_in[14];
  const float* dc_qkv_b = (const float*)d_in[15];
  const float* dc_o_w   = (const float*)d_in[16];
  const float* dc_ln1g  = (const float*)d_in[17];
  const float* dc_ln1b  = (const float*)d_in[18];
  const float* dc_c1w   = (const float*)d_in[19];
  const float* dc_c1b   = (const float*)d_in[20];
  const float* dc_c2w   = (const float*)d_in[21];
  const float* dc_c2b   = (const float*)d_in[22];
  const float* dc_ln2g  = (const float*)d_in[23];
  const float* dc_ln2b  = (const float*)d_in[24];
  const float* dp_c1w = (const float*)d_in[25];
  const float* dp_c1b = (const float*)d_in[26];
  const float* dp_ln1g = (const float*)d_in[27];
  const float* dp_ln1b = (const float*)d_in[28];
  const float* dp_c2w = (const float*)d_in[29];
  const float* dp_c2b = (const float*)d_in[30];
  const float* dp_ln2g = (const float*)d_in[31];
  const float* dp_ln2b = (const float*)d_in[32];
  const float* dp_fcw = (const float*)d_in[33];
  const float* dp_fcb = (const float*)d_in[34];
  const float* proj_w = (const float*)d_in[35];
  const float* proj_b = (const float*)d_in[36];

  char* ws = (char*)d_ws;
  size_t off = 0;
  auto alloc = [&](size_t bytes) -> char* {
    char* p = ws + off;
    off += (bytes + 255) & ~(size_t)255;
    return p;
  };

  __hip_bfloat16* qkvwt_e = (__hip_bfloat16*)alloc((size_t)6 * 256 * 384 * 2);
  __hip_bfloat16* qkvwt_d = (__hip_bfloat16*)alloc((size_t)6 * 256 * 384 * 2);
  __hip_bfloat16* owt_e   = (__hip_bfloat16*)alloc((size_t)6 * 384 * 64 * 2);
  __hip_bfloat16* owt_d   = (__hip_bfloat16*)alloc((size_t)6 * 384 * 64 * 2);
  __hip_bfloat16* c1wt_e  = (__hip_bfloat16*)alloc((size_t)6 * 3 * 1536 * 384 * 2);
  __hip_bfloat16* c1wt_d  = (__hip_bfloat16*)alloc((size_t)6 * 3 * 1536 * 384 * 2);
  __hip_bfloat16* c2wt_e  = (__hip_bfloat16*)alloc((size_t)6 * 3 * 384 * 1536 * 2);
  __hip_bfloat16* c2wt_d  = (__hip_bfloat16*)alloc((size_t)6 * 3 * 384 * 1536 * 2);
  __hip_bfloat16* dpc1wt  = (__hip_bfloat16*)alloc((size_t)3 * 256 * 384 * 2);
  __hip_bfloat16* dpc2wt  = (__hip_bfloat16*)alloc((size_t)3 * 256 * 256 * 2);
  __hip_bfloat16* projwt  = (__hip_bfloat16*)alloc((size_t)128 * 384 * 2);
  float* pe_e   = (float*)alloc((size_t)256 * 384 * 4);
  float* pe_d   = (float*)alloc((size_t)400 * 384 * 4);
  float* maskf_e = (float*)alloc((size_t)32 * 256 * 4);
  float* maskf_d = (float*)alloc((size_t)32 * 400 * 4);
  int*   idxbuf  = (int*)alloc((size_t)32 * 400 * 4);
  __hip_bfloat16* h_enc_bf = (__hip_bfloat16*)alloc((size_t)32 * 258 * 384 * 2);
  __hip_bfloat16* h_dec_bf = (__hip_bfloat16*)alloc((size_t)32 * 402 * 384 * 2);
  __hip_bfloat16* qkvbuf = (__hip_bfloat16*)alloc((size_t)32 * 402 * 192 * 2);
  __hip_bfloat16* vecbuf = (__hip_bfloat16*)alloc((size_t)32 * 402 * 64 * 2);
  __hip_bfloat16* tmp384 = (__hip_bfloat16*)alloc((size_t)32 * 402 * 384 * 2);
  __hip_bfloat16* cbuf   = (__hip_bfloat16*)alloc((size_t)32 * 402 * 1536 * 2);
  __hip_bfloat16* dp1b   = (__hip_bfloat16*)alloc((size_t)32 * 258 * 256 * 2);
  __hip_bfloat16* dp2b   = (__hip_bfloat16*)alloc((size_t)32 * 258 * 256 * 2);

  // ---- weight conversion ----
  transpose_cvt<<<dim3(12, 8, 6), dim3(32, 8), 0, stream>>>(e_qkv_w, qkvwt_e, 384, 192, 256);
  transpose_cvt<<<dim3(12, 8, 6), dim3(32, 8), 0, stream>>>(dc_qkv_w, qkvwt_d, 384, 192, 256);
  transpose_cvt<<<dim3(2, 12, 6), dim3(32, 8), 0, stream>>>(e_o_w, owt_e, 64, 384, 384);
  transpose_cvt<<<dim3(2, 12, 6), dim3(32, 8), 0, stream>>>(dc_o_w, owt_d, 64, 384, 384);
  transpose_cvt<<<dim3(12, 4, 1), dim3(32, 8), 0, stream>>>(proj_w, projwt, 384, 80, 128);
  {
    long long tot = 6LL * 3 * 1536 * 384;
    int blocks = (int)((tot + 255) / 256);
    conv_cvt<<<blocks, 256, 0, stream>>>(e_c1w, c1wt_e, 1536, 384, tot);
    conv_cvt<<<blocks, 256, 0, stream>>>(dc_c1w, c1wt_d, 1536, 384, tot);
    conv_cvt<<<blocks, 256, 0, stream>>>(e_c2w, c2wt_e, 384, 1536, tot);
    conv_cvt<<<blocks, 256, 0, stream>>>(dc_c2w, c2wt_d, 384, 1536, tot);
  }
  { long long tot = 3LL * 256 * 384; conv_cvt<<<(int)((tot + 255) / 256), 256, 0, stream>>>(dp_c1w, dpc1wt, 256, 384, tot); }
  { long long tot = 3LL * 256 * 256; conv_cvt<<<(int)((tot + 255) / 256), 256, 0, stream>>>(dp_c2w, dpc2wt, 256, 256, tot); }

  pe_kernel<<<(256 * 192 + 255) / 256, 256, 0, stream>>>(pe_e, 256);
  pe_kernel<<<(400 * 192 + 255) / 256, 256, 0, stream>>>(pe_d, 400);

  embed_kernel<<<32 * 256, 128, 0, stream>>>(inputs, emb, pe_e, maskf_e, h_enc_bf);
  zero_guards<<<64, 256, 0, stream>>>(h_enc_bf, 256, 384);
  zero_guards<<<64, 256, 0, stream>>>(cbuf, 256, 1536);

  // ---- encoder ----
  for (int l = 0; l < 6; ++l) {
    gemm_tn<64, 128, 2, 1, 384, false, false, false, true><<<dim3(128, 2), 256, 0, stream>>>(
        h_enc_bf, qkvwt_e + (size_t)l * 256 * 384, e_qkv_b + l * 192, qkvbuf,
        192, 192, 256, 256);
    fattn_kernel<<<dim3(4, 32), 256, 0, stream>>>(qkvbuf, maskf_e, vecbuf, 256, 4);
    gemm_tn<64, 128, 2, 1, 64, false, false, false, true><<<dim3(128, 3), 256, 0, stream>>>(
        vecbuf, owt_e + (size_t)l * 384 * 64, nullptr, tmp384,
        384, 384, 256, 384);
    ln_kernel<384, true, true><<<2048, 256, 0, stream>>>(
        tmp384, h_enc_bf, e_ln1g + l * 384, e_ln1b + l * 384, maskf_e, h_enc_bf, 256);
    gemm_tn<128, 128, 2, 3, 384, false, true, false, true><<<dim3(64, 12), 256, 0, stream>>>(
        h_enc_bf, c1wt_e + (size_t)l * 3 * 1536 * 384, e_c1b + l * 1536, cbuf,
        1536, 1536, 256, 1536);
    gemm_tn<64, 128, 2, 3, 1536, true, false, false, true><<<dim3(128, 3), 256, 0, stream>>>(
        cbuf, c2wt_e + (size_t)l * 3 * 384 * 1536, e_c2b + l * 384, tmp384,
        384, 384, 256, 384);
    ln_kernel<384, true, true><<<2048, 256, 0, stream>>>(
        tmp384, h_enc_bf, e_ln2g + l * 384, e_ln2b + l * 384, maskf_e, h_enc_bf, 256);
  }

  // ---- duration predictor ----
  zero_guards<<<64, 256, 0, stream>>>(dp1b, 256, 256);
  gemm_tn<64, 128, 2, 3, 384, false, true, false, true><<<dim3(128, 2), 256, 0, stream>>>(
      h_enc_bf, dpc1wt, dp_c1b, dp1b, 256, 256, 256, 256);
  ln_kernel<256, false, false><<<2048, 256, 0, stream>>>(
      dp1b, nullptr, dp_ln1g, dp_ln1b, nullptr, dp1b, 256);
  gemm_tn<64, 128, 2, 3, 256, false, true, false, true><<<dim3(128, 2), 256, 0, stream>>>(
      dp1b, dpc2wt, dp_c2b, dp2b, 256, 256, 256, 256);
  ln_kernel<256, false, false><<<2048, 256, 0, stream>>>(
      dp2b, nullptr, dp_ln2g, dp_ln2b, nullptr, dp2b, 256);
  dpfc_kernel<<<32 * 256, 64, 0, stream>>>(
      dp2b, dp_fcw, dp_fcb, maskf_e, outF + OFF_LOGDUR, outF + OFF_DUR);

  // ---- length regulator ----
  regulator_kernel<<<32, 512, 0, stream>>>(dur_tgt, maskf_d, idxbuf,
                                           outF + OFF_DMASK, outF + OFF_DLEN);
  zero_guards<<<64, 256, 0, stream>>>(h_dec_bf, 400, 384);
  zero_guards<<<64, 256, 0, stream>>>(cbuf, 400, 1536);
  build_y_kernel<<<32 * 400, 128, 0, stream>>>(h_enc_bf, idxbuf, maskf_d, pe_d, h_dec_bf);

  // ---- decoder ----
  for (int l = 0; l < 6; ++l) {
    gemm_tn<64, 128, 2, 1, 384, false, false, false, true><<<dim3(200, 2), 256, 0, stream>>>(
        h_dec_bf, qkvwt_d + (size_t)l * 256 * 384, dc_qkv_b + l * 192, qkvbuf,
        192, 192, 400, 256);
    fattn_kernel<<<dim3(7, 32), 256, 0, stream>>>(qkvbuf, maskf_d, vecbuf, 400, 7);
    gemm_tn<64, 128, 2, 1, 64, false, false, false, true><<<dim3(200, 3), 256, 0, stream>>>(
        vecbuf, owt_d + (size_t)l * 384 * 64, nullptr, tmp384,
        384, 384, 400, 384);
    ln_kernel<384, true, true><<<3200, 256, 0, stream>>>(
        tmp384, h_dec_bf, dc_ln1g + l * 384, dc_ln1b + l * 384, maskf_d, h_dec_bf, 400);
    gemm_tn<128, 128, 2, 3, 384, false, true, false, true><<<dim3(100, 12), 256, 0, stream>>>(
        h_dec_bf, c1wt_d + (size_t)l * 3 * 1536 * 384, dc_c1b + l * 1536, cbuf,
        1536, 1536, 400, 1536);
    gemm_tn<64, 128, 2, 3, 1536, true, false, false, true><<<dim3(200, 3), 256, 0, stream>>>(
        cbuf, c2wt_d + (size_t)l * 3 * 384 * 1536, dc_c2b + l * 384, tmp384,
        384, 384, 400, 384);
    ln_kernel<384, true, true><<<3200, 256, 0, stream>>>(
        tmp384, h_dec_bf, dc_ln2g + l * 384, dc_ln2b + l * 384, maskf_d, h_dec_bf, 400);
  }

  // ---- mel projection ----
  gemm_tn<64, 128, 2, 1, 384, false, false, true, false><<<dim3(200, 1), 256, 0, stream>>>(
      h_dec_bf, projwt, proj_b, outF + OFF_MEL, 80, 80, 400, 128);
}

// Round 16
// 2060.627 us; speedup vs baseline: 1.0843x; 1.0292x over previous
//
#include <hip/hip_runtime.h>
#include <hip/hip_bf16.h>
#include <stdint.h>

typedef __attribute__((ext_vector_type(8))) short bf16x8;   // 8 bf16 in 4 VGPRs (MFMA A/B operand)
typedef __attribute__((ext_vector_type(4))) float f32x4;    // MFMA C/D operand
typedef __attribute__((ext_vector_type(4))) unsigned int u32x4; // native 16B vec

// ---------------- model constants ----------------
static constexpr int BB = 32, SS = 256, DD = 384;
static constexpr int TDEC = 400;
static constexpr int NMELC = 80;

// d_out offsets (floats), return order: mel, dec_mask, dur_pred, log_dur_pred, dec_lens
static constexpr size_t OFF_MEL    = 0;
static constexpr size_t OFF_DMASK  = (size_t)BB * TDEC * NMELC;   // 1,024,000
static constexpr size_t OFF_DUR    = OFF_DMASK + (size_t)BB * TDEC;
static constexpr size_t OFF_LOGDUR = OFF_DUR + (size_t)BB * SS;
static constexpr size_t OFF_DLEN   = OFF_LOGDUR + (size_t)BB * SS;

// async global->LDS, 16B per lane (dest must be wave-uniform base + lane*16)
__device__ __forceinline__ void gld16(void* lds, const void* g) {
  __builtin_amdgcn_global_load_lds(
      (const __attribute__((address_space(1))) void*)g,
      (__attribute__((address_space(3))) void*)lds, 16, 0, 0);
}

// =================================================================
// Weight conversion
// =================================================================

// src: [L][R][C] f32  ->  dst: [L][Cpad][R] bf16 (transposed; zeros for c >= C)
__global__ __launch_bounds__(256)
void transpose_cvt(const float* __restrict__ src, __hip_bfloat16* __restrict__ dst,
                   int R, int C, int Cpad)
{
  __shared__ float tile[32][33];
  int l = blockIdx.z;
  src += (size_t)l * R * C;
  dst += (size_t)l * Cpad * R;
  int r0 = blockIdx.x * 32, c0 = blockIdx.y * 32;
  int tx = threadIdx.x, ty = threadIdx.y;
  for (int i = ty; i < 32; i += 8) {
    int c = c0 + tx;
    tile[i][tx] = (c < C) ? src[(size_t)(r0 + i) * C + c] : 0.f;
  }
  __syncthreads();
  for (int i = ty; i < 32; i += 8) {
    dst[(size_t)(c0 + i) * R + (r0 + tx)] = __float2bfloat16(tile[tx][i]);
  }
}

// src: [L][Cout][Cin][3] f32  ->  dst: [L][3][Cout][Cin] bf16
__global__ __launch_bounds__(256)
void conv_cvt(const float* __restrict__ src, __hip_bfloat16* __restrict__ dst,
              int Cout, int Cin, long long total)
{
  long long i = (long long)blockIdx.x * 256 + threadIdx.x;
  if (i >= total) return;
  int ci = (int)(i % Cin);
  long long t1 = i / Cin;
  int co = (int)(t1 % Cout);
  long long t2 = t1 / Cout;
  int tap = (int)(t2 % 3);
  int l = (int)(t2 / 3);
  dst[i] = __float2bfloat16(src[(((size_t)l * Cout + co) * Cin + ci) * 3 + tap]);
}

// =================================================================
// Positional embedding / embedding
// =================================================================

__global__ __launch_bounds__(256)
void pe_kernel(float* __restrict__ pe, int T)
{
  int i = blockIdx.x * 256 + threadIdx.x;
  if (i >= T * 192) return;
  int t = i / 192, j = i % 192;
  float inv = expf(-(float)j * (9.210340371976184f / 192.f));
  float s = (float)t * inv;
  pe[(size_t)t * 384 + j]       = sinf(s);
  pe[(size_t)t * 384 + 192 + j] = cosf(s);
}

__global__ __launch_bounds__(128)
void embed_kernel(const int* __restrict__ inputs, const float* __restrict__ emb,
                  const float* __restrict__ pe, float* __restrict__ maskf,
                  __hip_bfloat16* __restrict__ xb)
{
  int blk = blockIdx.x; int b = blk / SS, t = blk % SS;
  int tok = inputs[b * SS + t];
  float mk = (tok != 0) ? 1.f : 0.f;
  if (threadIdx.x == 0) maskf[b * SS + t] = mk;
  size_t prow = ((size_t)b * (SS + 2) + 1 + t) * 384;
  for (int c = threadIdx.x; c < 384; c += 128) {
    float v = emb[(size_t)tok * 384 + c] + pe[(size_t)t * 384 + c] * mk;
    xb[prow + c] = __float2bfloat16(v);
  }
}

__global__ __launch_bounds__(256)
void zero_guards(__hip_bfloat16* __restrict__ buf, int T, int C)
{
  int b = blockIdx.x >> 1, which = blockIdx.x & 1;
  size_t row = ((size_t)b * (T + 2) + (which ? (T + 1) : 0)) * (size_t)C;
  for (int c = threadIdx.x; c < C; c += 256) buf[row + c] = __float2bfloat16(0.f);
}

// =================================================================
// gemm_ws: BARRIER-FREE wave-split-K conv GEMM (for c2: M large, N=384).
// Tile 64x64 per block; 4 waves each compute the FULL tile over an
// interleaved quarter of the K chunks (chunk idx === wave (mod 4),
// tap-inner order). Each wave has PRIVATE double-buffered LDS (2x8KB)
// and self-paces with s_waitcnt vmcnt(8) — NO s_barrier in the K loop.
// 8 independent wave pipelines per CU (2 blocks resident) hide latency.
// Ends: __syncthreads + 4-way f32 reduce via LDS + bias(+ReLU) + bf16 store.
// Npad = rows per B tap panel (384 for c2!).
// =================================================================
template<int NTAPS, int KV, bool RELU>
__global__ __launch_bounds__(256)
void gemm_ws(const __hip_bfloat16* __restrict__ A,
             const __hip_bfloat16* __restrict__ Bw,
             const float* __restrict__ bias,
             __hip_bfloat16* __restrict__ Cout_,
             int N, int ldc, int T, int Npad)
{
  constexpr int NSTEP = NTAPS * (KV >> 5);
  static_assert(NSTEP % 4 == 0, "K chunks must split by 4 waves");
  constexpr int NC = NSTEP / 4;
  __shared__ __align__(16) char SH[65536];   // 4 waves x 2 bufs x 8KB; reused for reduce

  const int tid = threadIdx.x;
  const int lane = tid & 63;
  const int w = tid >> 6;

  // ---- per-XCD contiguous chunk mapping (bijective, m204; n-fast) ----
  const int GN = gridDim.y;
  const int NB = gridDim.x * GN;
  const int f = blockIdx.y * gridDim.x + blockIdx.x;
  const int qq = NB >> 3, rr8 = NB & 7;
  const int xcd = f & 7, pos = f >> 3;
  const int st = (xcd < rr8) ? xcd * (qq + 1) : rr8 * (qq + 1) + (xcd - rr8) * qq;
  const int L = st + pos;
  const int m0 = (L / GN) * 64;
  const int n0 = (L % GN) * 64;

  // staging lane mapping: call r covers rows r*16 + (lane>>2), 16B slot lane&3
  const int l4 = lane >> 2, q = lane & 3;
  const int qsw = q ^ ((l4 >> 1) & 3);     // pre-swizzled source slot
  const char* baseA[4];
  const char* baseB[4];
#pragma unroll
  for (int r = 0; r < 4; ++r) {
    int grow = m0 + r * 16 + l4;
    baseA[r] = (const char*)A + (((size_t)(grow + 2 * (grow / T) + 1 - NTAPS / 2)) * KV + qsw * 8) * 2;
    int nrow = n0 + r * 16 + l4;
    baseB[r] = (const char*)Bw + ((size_t)nrow * KV + qsw * 8) * 2;
  }
  const size_t AROW = (size_t)KV * 2;
  const size_t BPAN = (size_t)Npad * KV * 2;

  char* myb = SH + w * 16384;
  const int lds_l = lane * 16;

  auto STAGE = [&](int buf, int cidx) {
    int tap = cidx % NTAPS, ks = cidx / NTAPS;
    size_t aoff = (size_t)tap * AROW + (size_t)ks * 64;
    size_t boff = (size_t)tap * BPAN + (size_t)ks * 64;
    char* d = myb + buf * 8192;
#pragma unroll
    for (int r = 0; r < 4; ++r) gld16(d + r * 1024 + lds_l, baseA[r] + aoff);
#pragma unroll
    for (int r = 0; r < 4; ++r) gld16(d + 4096 + r * 1024 + lds_l, baseB[r] + boff);
  };

  f32x4 zero = {0.f, 0.f, 0.f, 0.f};
  f32x4 acc[4][4];
#pragma unroll
  for (int i = 0; i < 4; i++)
#pragma unroll
    for (int j = 0; j < 4; j++) acc[i][j] = zero;

  const int rl = lane & 15;
  const int hi4 = lane >> 4;
  const int kb2 = (hi4 ^ ((rl >> 1) & 3)) * 16;
  const int rj = hi4 * 4;

  auto COMPUTE = [&](int buf) {
    const char* Ab = myb + buf * 8192;
    const char* Bb = Ab + 4096;
    bf16x8 af[4], bfr[4];
#pragma unroll
    for (int mi = 0; mi < 4; mi++)
      af[mi] = *(const bf16x8*)(Ab + (mi * 16 + rl) * 64 + kb2);
#pragma unroll
    for (int ni = 0; ni < 4; ni++)
      bfr[ni] = *(const bf16x8*)(Bb + (ni * 16 + rl) * 64 + kb2);
#pragma unroll
    for (int mi = 0; mi < 4; mi++)
#pragma unroll
      for (int ni = 0; ni < 4; ni++)
        acc[mi][ni] = __builtin_amdgcn_mfma_f32_16x16x32_bf16(af[mi], bfr[ni], acc[mi][ni], 0, 0, 0);
  };

  // ---- barrier-free K loop (self-paced per wave) ----
  int cidx = w;
  STAGE(0, cidx); cidx += 4;
  if (NC > 1) { STAGE(1, cidx); cidx += 4; }
  for (int c = 0; c < NC; ++c) {
    if (c + 1 < NC) asm volatile("s_waitcnt vmcnt(8)" ::: "memory");
    else            asm volatile("s_waitcnt vmcnt(0)" ::: "memory");
    __builtin_amdgcn_sched_barrier(0);
    COMPUTE(c & 1);
    if (c + 2 < NC) { STAGE(c & 1, cidx); cidx += 4; }
  }

  // ---- cross-wave reduce + epilogue ----
  __syncthreads();                 // all waves done with staged LDS
  float* P = (float*)SH;           // [4][64][64] f32 partials
#pragma unroll
  for (int mi = 0; mi < 4; ++mi)
#pragma unroll
    for (int ni = 0; ni < 4; ++ni)
#pragma unroll
      for (int j = 0; j < 4; ++j)
        P[w * 4096 + (mi * 16 + rj + j) * 64 + ni * 16 + rl] = acc[mi][ni][j];
  __syncthreads();
#pragma unroll
  for (int p = 0; p < 4; ++p) {
    int idx = p * 1024 + tid * 4;
    f32x4 s = *(const f32x4*)(P + idx);
    s += *(const f32x4*)(P + 4096 + idx);
    s += *(const f32x4*)(P + 8192 + idx);
    s += *(const f32x4*)(P + 12288 + idx);
    int row = idx >> 6, col = idx & 63;
    f32x4 bv = *(const f32x4*)(bias + n0 + col);
    s += bv;
    ushort4 h;
#pragma unroll
    for (int e = 0; e < 4; ++e) {
      float v = s[e];
      if (RELU) v = fmaxf(v, 0.f);
      __hip_bfloat16 hb = __float2bfloat16(v);
      ((ushort*)&h)[e] = *(ushort*)&hb;
    }
    int m = m0 + row;
    size_t orow = (size_t)m + 2 * (m / T) + 1;
    *(ushort4*)(Cout_ + orow * ldc + n0 + col) = h;
  }
}

// =================================================================
// GEMM: C[M,N] = act( sum_tap A[m + tap - NTAPS/2, :] @ B_tap + bias )
// (R14 structure: barriered pipeline, used for qkv/o/c1/dp/proj)
// =================================================================
template<int TM, int TN, int DEPTH, int NTAPS, int KV, bool DUAL,
         bool RELU, bool OUTF32, bool CPAD>
__global__ __launch_bounds__(256)
void gemm_tn(const __hip_bfloat16* __restrict__ A,
             const __hip_bfloat16* __restrict__ Bw,
             const float* __restrict__ bias,
             void* __restrict__ Cout_,
             int N, int ldc, int T, int Npad)
{
  constexpr int KS = KV >> 5;
  constexpr int NSTEP = NTAPS * KS;
  constexpr int NI = DUAL ? NSTEP / 2 : NSTEP;
  constexpr int DEP = (DEPTH < NI) ? DEPTH : NI;
  constexpr int NBUF = DEP + 1;
  constexpr int ABYTES = TM * 64;
  constexpr int BBYTES = TN * 64;
  constexpr int HALF = ABYTES + BBYTES;
  constexpr int BUFB = DUAL ? 2 * HALF : HALF;
  constexpr int MI_N = TM / 32;
  constexpr int NI_N = TN / 32;
  constexpr int OPS1 = (TM == 128 ? 2 : 1) + (TN == 128 ? 2 : 1);
  constexpr int OPS = DUAL ? 2 * OPS1 : OPS1;
  __shared__ __align__(16) char SH[NBUF * BUFB];

  const int tid = threadIdx.x;
  const int lane = tid & 63;
  const int w = tid >> 6;
  const int wm = w >> 1, wn = w & 1;

  const int GN = gridDim.y;
  const int NB = gridDim.x * GN;
  const int f = blockIdx.y * gridDim.x + blockIdx.x;
  const int qq = NB >> 3, rr8 = NB & 7;
  const int xcd = f & 7, pos = f >> 3;
  const int st = (xcd < rr8) ? xcd * (qq + 1) : rr8 * (qq + 1) + (xcd - rr8) * qq;
  const int L = st + pos;
  const int m0 = (L / GN) * TM;
  const int n0 = (L % GN) * TN;

  const int ar = tid >> 2;
  const int q = tid & 3;
  const int qsw = q ^ ((ar >> 1) & 3);
  const int g0 = m0 + ar, g1 = g0 + 64;
  const char* sA0 = (const char*)A + (((size_t)(g0 + 2 * (g0 / T) + 1 - NTAPS / 2)) * KV + qsw * 8) * 2;
  const char* sA1 = (const char*)A + (((size_t)(g1 + 2 * (g1 / T) + 1 - NTAPS / 2)) * KV + qsw * 8) * 2;
  const char* sB0 = (const char*)Bw + ((size_t)(n0 + ar) * KV + qsw * 8) * 2;
  const char* sB1 = (const char*)Bw + ((size_t)(n0 + ar + 64) * KV + qsw * 8) * 2;

  const int woff = ar * 64 + q * 16;
  int tap_s = 0;

  const size_t AROW = (size_t)KV * 2;
  const size_t BPAN = (size_t)Npad * KV * 2;

  auto ADV = [&]() {
    sA0 += AROW; sA1 += AROW; sB0 += BPAN; sB1 += BPAN;
    if (++tap_s == NTAPS) {
      tap_s = 0;
      sA0 -= NTAPS * AROW - 64; sA1 -= NTAPS * AROW - 64;
      sB0 -= NTAPS * BPAN - 64; sB1 -= NTAPS * BPAN - 64;
    }
  };
  auto STAGE1 = [&](char* base) {
    gld16(base + woff, sA0);
    if (TM == 128) gld16(base + 4096 + woff, sA1);
    gld16(base + ABYTES + woff, sB0);
    if (TN == 128) gld16(base + ABYTES + 4096 + woff, sB1);
    ADV();
  };
  auto STAGE = [&](int buf) {
    char* base = SH + buf * BUFB;
    STAGE1(base);
    if (DUAL) STAGE1(base + HALF);
  };

  f32x4 zero = {0.f, 0.f, 0.f, 0.f};
  f32x4 acc[MI_N][NI_N];
#pragma unroll
  for (int i = 0; i < MI_N; i++)
#pragma unroll
    for (int j = 0; j < NI_N; j++) acc[i][j] = zero;

  const int rl = lane & 15;
  const int hi4 = lane >> 4;
  const int kb2 = (hi4 ^ ((rl >> 1) & 3)) * 16;

  auto COMPUTE = [&](const char* base) {
    const char* Ab = base;
    const char* Bb = base + ABYTES;
    bf16x8 af[MI_N], bfr[NI_N];
#pragma unroll
    for (int mi = 0; mi < MI_N; mi++)
      af[mi] = *(const bf16x8*)(Ab + (wm * (TM / 2) + mi * 16 + rl) * 64 + kb2);
#pragma unroll
    for (int ni = 0; ni < NI_N; ni++)
      bfr[ni] = *(const bf16x8*)(Bb + (wn * (TN / 2) + ni * 16 + rl) * 64 + kb2);
#pragma unroll
    for (int mi = 0; mi < MI_N; mi++)
#pragma unroll
      for (int ni = 0; ni < NI_N; ni++)
        acc[mi][ni] = __builtin_amdgcn_mfma_f32_16x16x32_bf16(af[mi], bfr[ni], acc[mi][ni], 0, 0, 0);
  };

#pragma unroll
  for (int i = 0; i < DEP; ++i) STAGE(i);
  if constexpr (DEP == NI) {
    asm volatile("s_waitcnt vmcnt(0)" ::: "memory");
  } else {
    asm volatile("s_waitcnt vmcnt(%0)" :: "i"((DEP - 1) * OPS) : "memory");
  }
  __builtin_amdgcn_s_barrier();
  __builtin_amdgcn_sched_barrier(0);

  int cur = 0;
  for (int i = 0; i < NI; ++i) {
    if (i + DEP < NI) {
      int nb = cur + DEP; if (nb >= NBUF) nb -= NBUF;
      STAGE(nb);
    }
    const char* base = SH + cur * BUFB;
    COMPUTE(base);
    if (DUAL) COMPUTE(base + HALF);
    if (i + 1 < NI) {
      if (i + DEP < NI) {
        asm volatile("s_waitcnt vmcnt(%0)" :: "i"((DEP - 1) * OPS) : "memory");
      } else {
        asm volatile("s_waitcnt vmcnt(0)" ::: "memory");
      }
      __builtin_amdgcn_s_barrier();
      __builtin_amdgcn_sched_barrier(0);
    }
    cur = cur + 1; if (cur >= NBUF) cur -= NBUF;
  }

  const int rj = hi4 * 4;
  if (!OUTF32) {
    __syncthreads();
    ushort* S = (ushort*)SH;
#pragma unroll
    for (int mi = 0; mi < MI_N; mi++) {
#pragma unroll
      for (int ni = 0; ni < NI_N; ni++) {
        int lc = wn * (TN / 2) + ni * 16 + rl;
        float bv = bias ? bias[n0 + lc] : 0.f;
#pragma unroll
        for (int j = 0; j < 4; j++) {
          float v = acc[mi][ni][j] + bv;
          if (RELU) v = fmaxf(v, 0.f);
          __hip_bfloat16 hb = __float2bfloat16(v);
          S[(wm * (TM / 2) + mi * 16 + rj + j) * TN + lc] = *(ushort*)&hb;
        }
      }
    }
    __syncthreads();
    constexpr int TPR = TN / 8;
    constexpr int RPP = 256 / TPR;
    const int tr = tid / TPR;
    const int tc = (tid % TPR) * 8;
#pragma unroll
    for (int pass = 0; pass < TM / RPP; ++pass) {
      int lr = pass * RPP + tr;
      int gcol = n0 + tc;
      if (gcol < N) {
        int r = m0 + lr;
        size_t orow = CPAD ? ((size_t)r + 2 * (r / T) + 1) : (size_t)r;
        *(u32x4*)((__hip_bfloat16*)Cout_ + orow * ldc + gcol) = *(const u32x4*)&S[lr * TN + tc];
      }
    }
  } else {
#pragma unroll
    for (int mi = 0; mi < MI_N; mi++) {
#pragma unroll
      for (int ni = 0; ni < NI_N; ni++) {
        int col = n0 + wn * (TN / 2) + ni * 16 + rl;
        if (col < N) {
          float bv = bias ? bias[col] : 0.f;
#pragma unroll
          for (int j = 0; j < 4; j++) {
            int r = m0 + wm * (TM / 2) + mi * 16 + rj + j;
            float v = acc[mi][ni][j] + bv;
            if (RELU) v = fmaxf(v, 0.f);
            size_t orow = CPAD ? ((size_t)r + 2 * (r / T) + 1) : (size_t)r;
            ((float*)Cout_)[orow * ldc + col] = v;
          }
        }
      }
    }
  }
}

// =================================================================
// Fused flash attention: 1 head, d=64. Block = (b, 64-query tile), 4 waves.
// =================================================================
__global__ __launch_bounds__(256)
void fattn_kernel(const __hip_bfloat16* __restrict__ qkv, const float* __restrict__ maskf,
                  __hip_bfloat16* __restrict__ vec, int T, int NT)
{
  __shared__ __align__(16) ushort VT[64][456];   // V^T: [d][key]
  __shared__ __align__(16) ushort Pl[4][16][72]; // per-wave P tile
  __shared__ float MS[448];                      // 0=ok, -1e9=masked, -1e38=pad

  const int tid = threadIdx.x;
  const int b = blockIdx.y;
  const int TP = T + 2;
  const int KTOT = NT * 64;
  const char* bptr = (const char*)qkv + ((size_t)b * TP + 1) * 384;

  for (int k = tid; k < KTOT; k += 256)
    MS[k] = (k < T) ? ((maskf[b * T + k] > 0.f) ? 0.f : -1e9f) : -1e38f;
  for (int i = tid; i < KTOT * 8; i += 256) {
    int k = i >> 3, seg = i & 7;
    int kr = (k < T) ? k : T - 1;
    uint4 u = *(const uint4*)(bptr + (size_t)kr * 384 + 256 + seg * 16);
    const ushort* e = (const ushort*)&u;
#pragma unroll
    for (int j = 0; j < 8; ++j) VT[seg * 8 + j][k] = e[j];
  }
  __syncthreads();

  const int w = tid >> 6, lane = tid & 63;
  const int lo = lane & 15, hi = lane >> 4;
  const int q0 = blockIdx.x * 64 + w * 16;
  const int qc = min(q0 + lo, T - 1);

  bf16x8 afr[2];
#pragma unroll
  for (int ks = 0; ks < 2; ++ks)
    afr[ks] = *(const bf16x8*)(bptr + (size_t)qc * 384 + ks * 64 + hi * 16);

  f32x4 Oacc[4];
  f32x4 z = {0.f, 0.f, 0.f, 0.f};
#pragma unroll
  for (int df = 0; df < 4; ++df) Oacc[df] = z;
  float mrun[4], lrun[4];
#pragma unroll
  for (int j = 0; j < 4; ++j) { mrun[j] = -3e38f; lrun[j] = 0.f; }

  for (int kt = 0; kt < NT; ++kt) {
    const int kb = kt * 64;
    f32x4 S[4];
#pragma unroll
    for (int f = 0; f < 4; ++f) S[f] = z;
#pragma unroll
    for (int ks = 0; ks < 2; ++ks) {
#pragma unroll
      for (int f = 0; f < 4; ++f) {
        int krc = min(kb + f * 16 + lo, T - 1);
        bf16x8 bfr = *(const bf16x8*)(bptr + (size_t)krc * 384 + 128 + ks * 64 + hi * 16);
        S[f] = __builtin_amdgcn_mfma_f32_16x16x32_bf16(afr[ks], bfr, S[f], 0, 0, 0);
      }
    }
    float sv[4][4];
#pragma unroll
    for (int f = 0; f < 4; ++f) {
      float msel = MS[kb + f * 16 + lo];
#pragma unroll
      for (int j = 0; j < 4; ++j) {
        float x = S[f][j] * 0.125f;
        sv[f][j] = (msel == 0.f) ? x : msel;
      }
    }
    float scale[4];
#pragma unroll
    for (int j = 0; j < 4; ++j) {
      float m4 = fmaxf(fmaxf(sv[0][j], sv[1][j]), fmaxf(sv[2][j], sv[3][j]));
#pragma unroll
      for (int msk = 1; msk < 16; msk <<= 1) m4 = fmaxf(m4, __shfl_xor(m4, msk));
      float mnew = fmaxf(mrun[j], m4);
      scale[j] = __expf(mrun[j] - mnew);
      mrun[j] = mnew;
    }
    float pv[4][4], ps[4] = {0.f, 0.f, 0.f, 0.f};
#pragma unroll
    for (int f = 0; f < 4; ++f)
#pragma unroll
      for (int j = 0; j < 4; ++j) {
        float p = __expf(sv[f][j] - mrun[j]);
        pv[f][j] = p; ps[j] += p;
      }
#pragma unroll
    for (int j = 0; j < 4; ++j) {
#pragma unroll
      for (int msk = 1; msk < 16; msk <<= 1) ps[j] += __shfl_xor(ps[j], msk);
      lrun[j] = lrun[j] * scale[j] + ps[j];
#pragma unroll
      for (int df = 0; df < 4; ++df) Oacc[df][j] *= scale[j];
    }
#pragma unroll
    for (int f = 0; f < 4; ++f)
#pragma unroll
      for (int j = 0; j < 4; ++j) {
        __hip_bfloat16 hb = __float2bfloat16(pv[f][j]);
        Pl[w][hi * 4 + j][f * 16 + lo] = *(ushort*)&hb;
      }
#pragma unroll
    for (int ks = 0; ks < 2; ++ks) {
      bf16x8 pa = *(const bf16x8*)((const char*)&Pl[w][lo][0] + ks * 64 + hi * 16);
#pragma unroll
      for (int df = 0; df < 4; ++df) {
        bf16x8 vfr = *(const bf16x8*)((const char*)&VT[df * 16 + lo][0] + kb * 2 + ks * 64 + hi * 16);
        Oacc[df] = __builtin_amdgcn_mfma_f32_16x16x32_bf16(pa, vfr, Oacc[df], 0, 0, 0);
      }
    }
  }

  float inv[4];
#pragma unroll
  for (int j = 0; j < 4; ++j) inv[j] = 1.f / lrun[j];
#pragma unroll
  for (int df = 0; df < 4; ++df)
#pragma unroll
    for (int j = 0; j < 4; ++j) {
      int qq = q0 + hi * 4 + j;
      if (qq < T) {
        __hip_bfloat16 hb = __float2bfloat16(Oacc[df][j] * inv[j]);
        *(ushort*)((char*)vec + ((size_t)b * TP + 1 + qq) * 128 + (df * 16 + lo) * 2) = *(ushort*)&hb;
      }
    }
}

// =================================================================
// LayerNorm (bf16 residual stream): out = LN(xin [+ resin]) * g + b [* mask]
// =================================================================
template<int C, bool HASRES, bool HASMASK>
__global__ __launch_bounds__(256)
void ln_kernel(const __hip_bfloat16* __restrict__ xin, const __hip_bfloat16* __restrict__ resin,
               const float* __restrict__ g, const float* __restrict__ bb,
               const float* __restrict__ maskf,
               __hip_bfloat16* __restrict__ outb, int T)
{
  constexpr int NU = C / 128;              // uint chunks per lane
  const int row = blockIdx.x * 4 + (threadIdx.x >> 6);
  const int lane = threadIdx.x & 63;
  const int b = row / T, t = row - b * T;
  const size_t prow = ((size_t)b * (T + 2) + 1 + t) * C;
  const uint* xu = (const uint*)(xin + prow);
  const uint* ru = (const uint*)(resin + prow);
  float v[2 * NU];
  float s1 = 0.f, s2 = 0.f;
#pragma unroll
  for (int k = 0; k < NU; ++k) {
    uint ux = xu[lane + 64 * k];
    uint xl = ux << 16, xh = ux & 0xffff0000u;
    float lo = *(float*)&xl, hi = *(float*)&xh;
    if (HASRES) {
      uint ur = ru[lane + 64 * k];
      uint rl2 = ur << 16, rh = ur & 0xffff0000u;
      lo += *(float*)&rl2; hi += *(float*)&rh;
    }
    v[2 * k] = lo; v[2 * k + 1] = hi;
    s1 += lo + hi; s2 += lo * lo + hi * hi;
  }
#pragma unroll
  for (int o = 32; o > 0; o >>= 1) { s1 += __shfl_xor(s1, o); s2 += __shfl_xor(s2, o); }
  float mu = s1 / C;
  float var = s2 / C - mu * mu;
  float rstd = rsqrtf(fmaxf(var, 0.f) + 1e-5f);
  float mk = HASMASK ? maskf[row] : 1.f;
  uint* ou = (uint*)(outb + prow);
#pragma unroll
  for (int k = 0; k < NU; ++k) {
    int c = (lane + 64 * k) * 2;
    float2 gv = *(const float2*)(g + c);
    float2 bv = *(const float2*)(bb + c);
    float lo = ((v[2 * k]     - mu) * rstd * gv.x + bv.x) * mk;
    float hi = ((v[2 * k + 1] - mu) * rstd * gv.y + bv.y) * mk;
    __hip_bfloat16 hl = __float2bfloat16(lo), hh = __float2bfloat16(hi);
    ou[lane + 64 * k] = (uint)(*(ushort*)&hl) | ((uint)(*(ushort*)&hh) << 16);
  }
}

// =================================================================
// Duration predictor FC + exp/clip
// =================================================================
__global__ __launch_bounds__(64)
void dpfc_kernel(const __hip_bfloat16* __restrict__ dp2, const float* __restrict__ fcw,
                 const float* __restrict__ fcb, const float* __restrict__ maskf,
                 float* __restrict__ logdur, float* __restrict__ durpred)
{
  int blk = blockIdx.x; int b = blk / SS, t = blk % SS;
  size_t prow = ((size_t)b * (SS + 2) + 1 + t) * 256;
  int lane = threadIdx.x;
  float a = 0.f;
  for (int c = lane; c < 256; c += 64) a += __bfloat162float(dp2[prow + c]) * fcw[c];
  for (int o = 32; o > 0; o >>= 1) a += __shfl_down(a, o);
  if (lane == 0) {
    float ld = (a + fcb[0]) * maskf[b * SS + t];
    logdur[b * SS + t] = ld;
    durpred[b * SS + t] = fminf(fmaxf(expf(ld) - 1.f, 0.f), 75.f);
  }
}

// =================================================================
// Length regulator
// =================================================================
__global__ __launch_bounds__(512)
void regulator_kernel(const float* __restrict__ dur, float* __restrict__ dmaskf,
                      int* __restrict__ idxbuf, float* __restrict__ out_dmask,
                      float* __restrict__ out_dlen)
{
  int b = blockIdx.x, tid = threadIdx.x;
  __shared__ int cum[256];
  __shared__ int len_s;
  if (tid < 256) cum[tid] = (int)rintf(dur[b * 256 + tid] / 0.0265f);
  __syncthreads();
  if (tid == 0) {
    int acc = 0;
    for (int i = 0; i < 256; i++) { acc += cum[i]; cum[i] = acc; }
    int len = acc < 400 ? acc : 400;
    len_s = len;
    out_dlen[b] = (float)len;
  }
  __syncthreads();
  if (tid < 400) {
    int p = tid;
    int lo = 0, hi = 256;
    while (lo < hi) { int mid = (lo + hi) >> 1; if (cum[mid] <= p) lo = mid + 1; else hi = mid; }
    int idx = lo < 255 ? lo : 255;
    idxbuf[b * 400 + p] = idx;
    float mk = (p < len_s) ? 1.f : 0.f;
    dmaskf[b * 400 + p] = mk;
    out_dmask[b * 400 + p] = mk;
  }
}

__global__ __launch_bounds__(128)
void build_y_kernel(const __hip_bfloat16* __restrict__ encb, const int* __restrict__ idxbuf,
                    const float* __restrict__ dmaskf, const float* __restrict__ pe,
                    __hip_bfloat16* __restrict__ yb)
{
  int blk = blockIdx.x; int b = blk / 400, p = blk % 400;
  float mk = dmaskf[b * 400 + p];
  int idx = idxbuf[b * 400 + p];
  size_t orowp = ((size_t)b * 402 + 1 + p) * 384;
  size_t srow = ((size_t)b * 258 + 1 + idx) * 384;
  for (int c = threadIdx.x; c < 384; c += 128) {
    float v = (mk > 0.f) ? (__bfloat162float(encb[srow + c]) + pe[(size_t)p * 384 + c]) : 40.f;
    yb[orowp + c] = __float2bfloat16(v);
  }
}

// =================================================================
// Orchestration
// =================================================================
extern "C" void kernel_launch(void* const* d_in, const int* in_sizes, int n_in,
                              void* d_out, int out_size, void* d_ws, size_t ws_size,
                              hipStream_t stream)
{
  (void)in_sizes; (void)n_in; (void)out_size; (void)ws_size;
  float* outF = (float*)d_out;

  const int*   inputs  = (const int*)d_in[0];
  const float* dur_tgt = (const float*)d_in[1];
  const float* emb     = (const float*)d_in[2];
  const float* e_qkv_w = (const float*)d_in[3];
  const float* e_qkv_b = (const float*)d_in[4];
  const float* e_o_w   = (const float*)d_in[5];
  const float* e_ln1g  = (const float*)d_in[6];
  const float* e_ln1b  = (const float*)d_in[7];
  const float* e_c1w   = (const float*)d_in[8];
  const float* e_c1b   = (const float*)d_in[9];
  const float* e_c2w   = (const float*)d_in[10];
  const float* e_c2b   = (const float*)d_in[11];
  const float* e_ln2g  = (const float*)d_in[12];
  const float* e_ln2b  = (const float*)d_in[13];
  const float* dc_qkv_w = (const float*)d_in[14];
  const float* dc_qkv_b = (const float*)d_in[15];
  const float* dc_o_w   = (const float*)d_in[16];
  const float* dc_ln1g  = (const float*)d_in[17];
  const float* dc_ln1b  = (const float*)d_in[18];
  const float* dc_c1w   = (const float*)d_in[19];
  const float* dc_c1b   = (const float*)d_in[20];
  const float* dc_c2w   = (const float*)d_in[21];
  const float* dc_c2b   = (const float*)d_in[22];
  const float* dc_ln2g  = (const float*)d_in[23];
  const float* dc_ln2b  = (const float*)d_in[24];
  const float* dp_c1w = (const float*)d_in[25];
  const float* dp_c1b = (const float*)d_in[26];
  const float* dp_ln1g = (const float*)d_in[27];
  const float* dp_ln1b = (const float*)d_in[28];
  const float* dp_c2w = (const float*)d_in[29];
  const float* dp_c2b = (const float*)d_in[30];
  const float* dp_ln2g = (const float*)d_in[31];
  const float* dp_ln2b = (const float*)d_in[32];
  const float* dp_fcw = (const float*)d_in[33];
  const float* dp_fcb = (const float*)d_in[34];
  const float* proj_w = (const float*)d_in[35];
  const float* proj_b = (const float*)d_in[36];

  char* ws = (char*)d_ws;
  size_t off = 0;
  auto alloc = [&](size_t bytes) -> char* {
    char* p = ws + off;
    off += (bytes + 255) & ~(size_t)255;
    return p;
  };

  __hip_bfloat16* qkvwt_e = (__hip_bfloat16*)alloc((size_t)6 * 256 * 384 * 2);
  __hip_bfloat16* qkvwt_d = (__hip_bfloat16*)alloc((size_t)6 * 256 * 384 * 2);
  __hip_bfloat16* owt_e   = (__hip_bfloat16*)alloc((size_t)6 * 384 * 64 * 2);
  __hip_bfloat16* owt_d   = (__hip_bfloat16*)alloc((size_t)6 * 384 * 64 * 2);
  __hip_bfloat16* c1wt_e  = (__hip_bfloat16*)alloc((size_t)6 * 3 * 1536 * 384 * 2);
  __hip_bfloat16* c1wt_d  = (__hip_bfloat16*)alloc((size_t)6 * 3 * 1536 * 384 * 2);
  __hip_bfloat16* c2wt_e  = (__hip_bfloat16*)alloc((size_t)6 * 3 * 384 * 1536 * 2);
  __hip_bfloat16* c2wt_d  = (__hip_bfloat16*)alloc((size_t)6 * 3 * 384 * 1536 * 2);
  __hip_bfloat16* dpc1wt  = (__hip_bfloat16*)alloc((size_t)3 * 256 * 384 * 2);
  __hip_bfloat16* dpc2wt  = (__hip_bfloat16*)alloc((size_t)3 * 256 * 256 * 2);
  __hip_bfloat16* projwt  = (__hip_bfloat16*)alloc((size_t)128 * 384 * 2);
  float* pe_e   = (float*)alloc((size_t)256 * 384 * 4);
  float* pe_d   = (float*)alloc((size_t)400 * 384 * 4);
  float* maskf_e = (float*)alloc((size_t)32 * 256 * 4);
  float* maskf_d = (float*)alloc((size_t)32 * 400 * 4);
  int*   idxbuf  = (int*)alloc((size_t)32 * 400 * 4);
  __hip_bfloat16* h_enc_bf = (__hip_bfloat16*)alloc((size_t)32 * 258 * 384 * 2);
  __hip_bfloat16* h_dec_bf = (__hip_bfloat16*)alloc((size_t)32 * 402 * 384 * 2);
  __hip_bfloat16* qkvbuf = (__hip_bfloat16*)alloc((size_t)32 * 402 * 192 * 2);
  __hip_bfloat16* vecbuf = (__hip_bfloat16*)alloc((size_t)32 * 402 * 64 * 2);
  __hip_bfloat16* tmp384 = (__hip_bfloat16*)alloc((size_t)32 * 402 * 384 * 2);
  __hip_bfloat16* cbuf   = (__hip_bfloat16*)alloc((size_t)32 * 402 * 1536 * 2);
  __hip_bfloat16* dp1b   = (__hip_bfloat16*)alloc((size_t)32 * 258 * 256 * 2);
  __hip_bfloat16* dp2b   = (__hip_bfloat16*)alloc((size_t)32 * 258 * 256 * 2);

  // ---- weight conversion ----
  transpose_cvt<<<dim3(12, 8, 6), dim3(32, 8), 0, stream>>>(e_qkv_w, qkvwt_e, 384, 192, 256);
  transpose_cvt<<<dim3(12, 8, 6), dim3(32, 8), 0, stream>>>(dc_qkv_w, qkvwt_d, 384, 192, 256);
  transpose_cvt<<<dim3(2, 12, 6), dim3(32, 8), 0, stream>>>(e_o_w, owt_e, 64, 384, 384);
  transpose_cvt<<<dim3(2, 12, 6), dim3(32, 8), 0, stream>>>(dc_o_w, owt_d, 64, 384, 384);
  transpose_cvt<<<dim3(12, 4, 1), dim3(32, 8), 0, stream>>>(proj_w, projwt, 384, 80, 128);
  {
    long long tot = 6LL * 3 * 1536 * 384;
    int blocks = (int)((tot + 255) / 256);
    conv_cvt<<<blocks, 256, 0, stream>>>(e_c1w, c1wt_e, 1536, 384, tot);
    conv_cvt<<<blocks, 256, 0, stream>>>(dc_c1w, c1wt_d, 1536, 384, tot);
    conv_cvt<<<blocks, 256, 0, stream>>>(e_c2w, c2wt_e, 384, 1536, tot);
    conv_cvt<<<blocks, 256, 0, stream>>>(dc_c2w, c2wt_d, 384, 1536, tot);
  }
  { long long tot = 3LL * 256 * 384; conv_cvt<<<(int)((tot + 255) / 256), 256, 0, stream>>>(dp_c1w, dpc1wt, 256, 384, tot); }
  { long long tot = 3LL * 256 * 256; conv_cvt<<<(int)((tot + 255) / 256), 256, 0, stream>>>(dp_c2w, dpc2wt, 256, 256, tot); }

  pe_kernel<<<(256 * 192 + 255) / 256, 256, 0, stream>>>(pe_e, 256);
  pe_kernel<<<(400 * 192 + 255) / 256, 256, 0, stream>>>(pe_d, 400);

  embed_kernel<<<32 * 256, 128, 0, stream>>>(inputs, emb, pe_e, maskf_e, h_enc_bf);
  zero_guards<<<64, 256, 0, stream>>>(h_enc_bf, 256, 384);
  zero_guards<<<64, 256, 0, stream>>>(cbuf, 256, 1536);

  // ---- encoder ----
  for (int l = 0; l < 6; ++l) {
    gemm_tn<64, 128, 2, 1, 384, false, false, false, true><<<dim3(128, 2), 256, 0, stream>>>(
        h_enc_bf, qkvwt_e + (size_t)l * 256 * 384, e_qkv_b + l * 192, qkvbuf,
        192, 192, 256, 256);
    fattn_kernel<<<dim3(4, 32), 256, 0, stream>>>(qkvbuf, maskf_e, vecbuf, 256, 4);
    gemm_tn<64, 128, 2, 1, 64, false, false, false, true><<<dim3(128, 3), 256, 0, stream>>>(
        vecbuf, owt_e + (size_t)l * 384 * 64, nullptr, tmp384,
        384, 384, 256, 384);
    ln_kernel<384, true, true><<<2048, 256, 0, stream>>>(
        tmp384, h_enc_bf, e_ln1g + l * 384, e_ln1b + l * 384, maskf_e, h_enc_bf, 256);
    gemm_tn<128, 128, 2, 3, 384, false, true, false, true><<<dim3(64, 12), 256, 0, stream>>>(
        h_enc_bf, c1wt_e + (size_t)l * 3 * 1536 * 384, e_c1b + l * 1536, cbuf,
        1536, 1536, 256, 1536);
    gemm_ws<3, 1536, false><<<dim3(128, 6), 256, 0, stream>>>(
        cbuf, c2wt_e + (size_t)l * 3 * 384 * 1536, e_c2b + l * 384, tmp384,
        384, 384, 256, 384);
    ln_kernel<384, true, true><<<2048, 256, 0, stream>>>(
        tmp384, h_enc_bf, e_ln2g + l * 384, e_ln2b + l * 384, maskf_e, h_enc_bf, 256);
  }

  // ---- duration predictor ----
  zero_guards<<<64, 256, 0, stream>>>(dp1b, 256, 256);
  gemm_tn<64, 128, 2, 3, 384, false, true, false, true><<<dim3(128, 2), 256, 0, stream>>>(
      h_enc_bf, dpc1wt, dp_c1b, dp1b, 256, 256, 256, 256);
  ln_kernel<256, false, false><<<2048, 256, 0, stream>>>(
      dp1b, nullptr, dp_ln1g, dp_ln1b, nullptr, dp1b, 256);
  gemm_tn<64, 128, 2, 3, 256, false, true, false, true><<<dim3(128, 2), 256, 0, stream>>>(
      dp1b, dpc2wt, dp_c2b, dp2b, 256, 256, 256, 256);
  ln_kernel<256, false, false><<<2048, 256, 0, stream>>>(
      dp2b, nullptr, dp_ln2g, dp_ln2b, nullptr, dp2b, 256);
  dpfc_kernel<<<32 * 256, 64, 0, stream>>>(
      dp2b, dp_fcw, dp_fcb, maskf_e, outF + OFF_LOGDUR, outF + OFF_DUR);

  // ---- length regulator ----
  regulator_kernel<<<32, 512, 0, stream>>>(dur_tgt, maskf_d, idxbuf,
                                           outF + OFF_DMASK, outF + OFF_DLEN);
  zero_guards<<<64, 256, 0, stream>>>(h_dec_bf, 400, 384);
  zero_guards<<<64, 256, 0, stream>>>(cbuf, 400, 1536);
  build_y_kernel<<<32 * 400, 128, 0, stream>>>(h_enc_bf, idxbuf, maskf_d, pe_d, h_dec_bf);

  // ---- decoder ----
  for (int l = 0; l < 6; ++l) {
    gemm_tn<64, 128, 2, 1, 384, false, false, false, true><<<dim3(200, 2), 256, 0, stream>>>(
        h_dec_bf, qkvwt_d + (size_t)l * 256 * 384, dc_qkv_b + l * 192, qkvbuf,
        192, 192, 400, 256);
    fattn_kernel<<<dim3(7, 32), 256, 0, stream>>>(qkvbuf, maskf_d, vecbuf, 400, 7);
    gemm_tn<64, 128, 2, 1, 64, false, false, false, true><<<dim3(200, 3), 256, 0, stream>>>(
        vecbuf, owt_d + (size_t)l * 384 * 64, nullptr, tmp384,
        384, 384, 400, 384);
    ln_kernel<384, true, true><<<3200, 256, 0, stream>>>(
        tmp384, h_dec_bf, dc_ln1g + l * 384, dc_ln1b + l * 384, maskf_d, h_dec_bf, 400);
    gemm_tn<128, 128, 2, 3, 384, false, true, false, true><<<dim3(100, 12), 256, 0, stream>>>(
        h_dec_bf, c1wt_d + (size_t)l * 3 * 1536 * 384, dc_c1b + l * 1536, cbuf,
        1536, 1536, 400, 1536);
    gemm_ws<3, 1536, false><<<dim3(200, 6), 256, 0, stream>>>(
        cbuf, c2wt_d + (size_t)l * 3 * 384 * 1536, dc_c2b + l * 384, tmp384,
        384, 384, 400, 384);
    ln_kernel<384, true, true><<<3200, 256, 0, stream>>>(
        tmp384, h_dec_bf, dc_ln2g + l * 384, dc_ln2b + l * 384, maskf_d, h_dec_bf, 400);
  }

  // ---- mel projection ----
  gemm_tn<64, 128, 2, 1, 384, false, false, true, false><<<dim3(200, 1), 256, 0, stream>>>(
      h_dec_bf, projwt, proj_b, outF + OFF_MEL, 80, 80, 400, 128);
}